// Round 2
// baseline (1723.121 us; speedup 1.0000x reference)
//
#include <hip/hip_runtime.h>
#include <hip/hip_bf16.h>

#define B_ 8
#define C_ 64
#define N_ 4096
#define K_ 20
#define EPS_ 1e-5f
#define SLOPE_ 0.2f

__device__ __forceinline__ float lrelu(float x) { return x >= 0.f ? x : SLOPE_ * x; }

// ---------------------------------------------------------------------------
// Kernel A: per-point transforms yA = wA@x, dd = (wB-wA)@x, xx = |x|^2
// grid 512 (B * N/64), block 256
// ---------------------------------------------------------------------------
__global__ void __launch_bounds__(256) k_pre(const float* __restrict__ x,
                                             const float* __restrict__ wk1,
                                             float* __restrict__ yA,
                                             float* __restrict__ dd,
                                             float* __restrict__ xx) {
    __shared__ float w[64][128];
    __shared__ float xs[64][64];
    int t = threadIdx.x;
    int blk = blockIdx.x;
    int b = blk >> 6;
    int n0 = (blk & 63) << 6;

    // load w_k1 (64x128 f32) -> LDS
    for (int i = 0; i < 8; ++i) {
        int j = i * 256 + t;                 // float4 index, 2048 total
        float4 v = ((const float4*)wk1)[j];
        int o = j >> 5;                      // 32 float4 per 128-col row
        int c4 = (j & 31) << 2;
        w[o][c4 + 0] = v.x; w[o][c4 + 1] = v.y;
        w[o][c4 + 2] = v.z; w[o][c4 + 3] = v.w;
    }
    // load x tile (64 ch x 64 pts)
    const float* xb = x + (size_t)b * C_ * N_;
    for (int i = 0; i < 4; ++i) {
        int j = i * 256 + t;                 // float4 index, 1024 total
        int c = j >> 4;
        int p4 = (j & 15) << 2;
        float4 v = *(const float4*)(xb + c * N_ + n0 + p4);
        xs[c][p4 + 0] = v.x; xs[c][p4 + 1] = v.y;
        xs[c][p4 + 2] = v.z; xs[c][p4 + 3] = v.w;
    }
    __syncthreads();

    if (t < 64) {
        float s = 0.f;
        for (int c = 0; c < 64; ++c) { float xv = xs[c][t]; s += xv * xv; }
        xx[b * N_ + n0 + t] = s;
    }

    int p = t & 63, og = t >> 6;
    for (int oi = 0; oi < 16; ++oi) {
        int o = og * 16 + oi;
        float sA = 0.f, sB = 0.f;
        for (int c = 0; c < 64; ++c) {
            float xv = xs[c][p];
            sA += w[o][c] * xv;
            sB += w[o][64 + c] * xv;
        }
        size_t base = ((size_t)(b * N_ + n0 + p)) * 64 + o;
        yA[base] = sA;
        dd[base] = sB - sA;  // (wB - wA) @ x
    }
}

// ---------------------------------------------------------------------------
// Kernel B: top-20 neighbor indices by score = 2*dot(x_n,x_m) - |x_m|^2
// grid 512 (B * N/64 rows), block 256. 64x64 Gram chunks, per-row top-k in LDS.
// ---------------------------------------------------------------------------
__global__ void __launch_bounds__(256) k_topk(const float* __restrict__ x,
                                              const float* __restrict__ xx,
                                              int* __restrict__ idxg) {
    __shared__ float xn[64][64];   // [c][row-point]
    __shared__ float xm[64][64];   // [c][col-point]
    __shared__ float sc[64][68];   // padded scores
    __shared__ float tv[64][K_];
    __shared__ int   ti[64][K_];
    int t = threadIdx.x;
    int blk = blockIdx.x;
    int b = blk >> 6;
    int n0 = (blk & 63) << 6;
    const float* xb = x + (size_t)b * C_ * N_;

    for (int i = 0; i < 4; ++i) {
        int j = i * 256 + t;
        int c = j >> 4;
        int p4 = (j & 15) << 2;
        float4 v = *(const float4*)(xb + c * N_ + n0 + p4);
        xn[c][p4 + 0] = v.x; xn[c][p4 + 1] = v.y;
        xn[c][p4 + 2] = v.z; xn[c][p4 + 3] = v.w;
    }
    if (t < 64) {
        for (int k = 0; k < K_; ++k) { tv[t][k] = -3.0e38f; ti[t][k] = 0; }
    }
    __syncthreads();

    int tr = t >> 4, tc = t & 15;
    const float* xxb = xx + b * N_;

    for (int mc = 0; mc < 64; ++mc) {
        int m0 = mc << 6;
        for (int i = 0; i < 4; ++i) {
            int j = i * 256 + t;
            int c = j >> 4;
            int p4 = (j & 15) << 2;
            float4 v = *(const float4*)(xb + c * N_ + m0 + p4);
            xm[c][p4 + 0] = v.x; xm[c][p4 + 1] = v.y;
            xm[c][p4 + 2] = v.z; xm[c][p4 + 3] = v.w;
        }
        __syncthreads();

        float acc[4][4] = {};
        for (int c = 0; c < 64; ++c) {
            float4 a4 = *(const float4*)&xn[c][tr << 2];
            float4 b4 = *(const float4*)&xm[c][tc << 2];
            float av[4] = {a4.x, a4.y, a4.z, a4.w};
            float bv[4] = {b4.x, b4.y, b4.z, b4.w};
            for (int jj = 0; jj < 4; ++jj)
                for (int ii = 0; ii < 4; ++ii)
                    acc[jj][ii] += av[jj] * bv[ii];
        }
        for (int ii = 0; ii < 4; ++ii) {
            float xv = xxb[m0 + (tc << 2) + ii];
            for (int jj = 0; jj < 4; ++jj)
                sc[(tr << 2) + jj][(tc << 2) + ii] = 2.f * acc[jj][ii] - xv;
        }
        __syncthreads();

        if (t < 64) {
            float mn = tv[t][K_ - 1];
            for (int j = 0; j < 64; ++j) {
                float v = sc[t][j];
                if (v > mn) {
                    int pos = K_ - 1;
                    while (pos > 0 && tv[t][pos - 1] < v) {
                        tv[t][pos] = tv[t][pos - 1];
                        ti[t][pos] = ti[t][pos - 1];
                        --pos;
                    }
                    tv[t][pos] = v;
                    ti[t][pos] = m0 + j;
                    mn = tv[t][K_ - 1];
                }
            }
        }
        __syncthreads();
    }

    if (t < 64) {
        int n = n0 + t;
        for (int k = 0; k < K_; ++k)
            idxg[((size_t)(b * N_ + n)) * K_ + k] = ti[t][k];
    }
}

// ---------------------------------------------------------------------------
// Kernel C1: gather + BN1/lrelu -> conv_k2 -> max_k -> BN2/lrelu -> ht[b][o][n]
// grid 4096 (B * N/8), block 256 (8 points/block, 32 threads/point)
// ---------------------------------------------------------------------------
__global__ void __launch_bounds__(256) k_edge(const float* __restrict__ yA,
                                              const float* __restrict__ dd,
                                              const int* __restrict__ idxg,
                                              const float* __restrict__ wk2,
                                              const float* __restrict__ g1,
                                              const float* __restrict__ bb1,
                                              const float* __restrict__ mm1,
                                              const float* __restrict__ vv1,
                                              const float* __restrict__ g2,
                                              const float* __restrict__ bb2,
                                              const float* __restrict__ mm2,
                                              const float* __restrict__ vv2,
                                              float* __restrict__ ht) {
    __shared__ float wt[64][68];        // wt[in][out] = wk2[out][in]
    __shared__ float tmf[8 * 1412];     // t-matrix: [pt]*1412 + o*22 + k (bank-spread)
    __shared__ float ddl[8][64];
    __shared__ float s1c[64], t1c[64], s2c[64], t2c[64];
    __shared__ int   il[8][K_];
    __shared__ float hl[8][64];
    int t = threadIdx.x;
    int blk = blockIdx.x;
    int b = blk >> 9;
    int n0 = (blk & 511) << 3;

    for (int i = 0; i < 16; ++i) {
        int j = i * 256 + t;
        int oo = j >> 6, ic = j & 63;     // j = oo*64 + ic
        wt[ic][oo] = wk2[j];
    }
    if (t < 64) {
        float g = g1[t], be = bb1[t], m = mm1[t], v = vv1[t];
        float s = g * rsqrtf(v + EPS_);
        s1c[t] = s; t1c[t] = be - m * s;
        g = g2[t]; be = bb2[t]; m = mm2[t]; v = vv2[t];
        s = g * rsqrtf(v + EPS_);
        s2c[t] = s; t2c[t] = be - m * s;
    }
    size_t pbase = (size_t)(b * N_ + n0);
    for (int i = t; i < 512; i += 256) {
        int pt = i >> 6, o = i & 63;
        ddl[pt][o] = dd[(pbase + pt) * 64 + o];
    }
    if (t < 8 * K_) {
        int pt = t / K_, k = t % K_;
        il[pt][k] = idxg[(pbase + pt) * K_ + k];
    }
    __syncthreads();

    // gather phase: conv_k1 output = yA[m] + dd[n], then BN1 + lrelu
    const float* yAb = yA + (size_t)(b * N_) * 64;
    for (int i = 0; i < 10; ++i) {
        int j = i * 256 + t;                 // 2560 float4 items
        int pt = j / 320;
        int r = j - pt * 320;
        int k = r >> 4;
        int f = r & 15;
        int m = il[pt][k];
        float4 y4 = *(const float4*)(yAb + (size_t)m * 64 + (f << 2));
        float vals[4] = {y4.x, y4.y, y4.z, y4.w};
        int o = f << 2;
        for (int cdx = 0; cdx < 4; ++cdx) {
            int oc = o + cdx;
            float v = vals[cdx] + ddl[pt][oc];
            v = lrelu(s1c[oc] * v + t1c[oc]);
            tmf[pt * 1412 + oc * 22 + k] = v;
        }
    }
    __syncthreads();

    // conv_k2 (64x64) over k=20 + max over k
    int pt = t >> 5, u = t & 31;
    int o2_0 = (u & 7) << 3;
    int k0 = (u >> 3) * 5;
    float acc[8][5];
    for (int i = 0; i < 8; ++i)
        for (int q = 0; q < 5; ++q) acc[i][q] = 0.f;
    const float* tmp_ = &tmf[pt * 1412];
    for (int o = 0; o < 64; ++o) {
        float4 w0 = *(const float4*)&wt[o][o2_0];
        float4 w1v = *(const float4*)&wt[o][o2_0 + 4];
        float wv[8] = {w0.x, w0.y, w0.z, w0.w, w1v.x, w1v.y, w1v.z, w1v.w};
        float tvv[5];
        for (int q = 0; q < 5; ++q) tvv[q] = tmp_[o * 22 + k0 + q];
        for (int i = 0; i < 8; ++i)
            for (int q = 0; q < 5; ++q)
                acc[i][q] += wv[i] * tvv[q];
    }
    for (int i = 0; i < 8; ++i) {
        float pm = acc[i][0];
        for (int q = 1; q < 5; ++q) pm = fmaxf(pm, acc[i][q]);
        pm = fmaxf(pm, __shfl_xor(pm, 8));
        pm = fmaxf(pm, __shfl_xor(pm, 16));
        if ((u >> 3) == 0) {
            int o2 = o2_0 + i;
            hl[pt][o2] = lrelu(s2c[o2] * pm + t2c[o2]);
        }
    }
    __syncthreads();

    // write ht transposed [b][o][n] for coalesced head kernel
    float* htb = ht + (size_t)b * 64 * N_;
    for (int i = t; i < 512; i += 256) {
        int o = i >> 3, pt2 = i & 7;
        htb[o * N_ + n0 + pt2] = hl[pt2][o];
    }
}

// ---------------------------------------------------------------------------
// Kernel C2: MLP head 64 -> 256 -> 128 -> 1 per point, 64 points per block
// grid 512, block 256
// ---------------------------------------------------------------------------
__global__ void __launch_bounds__(256) k_head(const float* __restrict__ ht,
                                              const float* __restrict__ w1,
                                              const float* __restrict__ g1,
                                              const float* __restrict__ bb1,
                                              const float* __restrict__ mm1,
                                              const float* __restrict__ vv1,
                                              const float* __restrict__ w2,
                                              const float* __restrict__ g2,
                                              const float* __restrict__ bb2,
                                              const float* __restrict__ mm2,
                                              const float* __restrict__ vv2,
                                              const float* __restrict__ w3,
                                              const float* __restrict__ b3,
                                              float* __restrict__ out) {
    __shared__ float hbuf[64][64];   // [o][pt]
    __shared__ float a1[256][64];    // [row][pt]
    __shared__ float a2[128][64];
    __shared__ float sA[256], tA[256], sB[128], tB[128];
    int t = threadIdx.x;
    int blk = blockIdx.x;
    int b = blk >> 6;
    int n0 = (blk & 63) << 6;
    const float* htb = ht + (size_t)b * 64 * N_;

    for (int i = 0; i < 16; ++i) {
        int j = i * 256 + t;
        int o = j >> 6, pt = j & 63;
        hbuf[o][pt] = htb[o * N_ + n0 + pt];
    }
    {
        float g = g1[t], be = bb1[t], m = mm1[t], v = vv1[t];
        float s = g * rsqrtf(v + EPS_);
        sA[t] = s; tA[t] = be - m * s;
    }
    if (t < 128) {
        float g = g2[t], be = bb2[t], m = mm2[t], v = vv2[t];
        float s = g * rsqrtf(v + EPS_);
        sB[t] = s; tB[t] = be - m * s;
    }
    __syncthreads();

    int ptg = t & 15, rg = t >> 4;
    int pt4 = ptg << 2;

    // stage A: a1 = lrelu(BN(W1 @ h)), 256 rows, K=64
    for (int ib = 0; ib < 4; ++ib) {
        int r0 = (rg << 4) + (ib << 2);
        float acc[4][4] = {};
        for (int o4 = 0; o4 < 16; ++o4) {
            float hf[4][4];
            for (int c = 0; c < 4; ++c) {
                float4 q = *(const float4*)&hbuf[(o4 << 2) + c][pt4];
                hf[c][0] = q.x; hf[c][1] = q.y; hf[c][2] = q.z; hf[c][3] = q.w;
            }
            for (int j = 0; j < 4; ++j) {
                float4 wv4 = *(const float4*)(w1 + (r0 + j) * 64 + (o4 << 2));
                float wv[4] = {wv4.x, wv4.y, wv4.z, wv4.w};
                for (int c = 0; c < 4; ++c)
                    for (int pp = 0; pp < 4; ++pp)
                        acc[j][pp] += wv[c] * hf[c][pp];
            }
        }
        for (int j = 0; j < 4; ++j) {
            int r = r0 + j;
            float4 ov;
            ov.x = lrelu(sA[r] * acc[j][0] + tA[r]);
            ov.y = lrelu(sA[r] * acc[j][1] + tA[r]);
            ov.z = lrelu(sA[r] * acc[j][2] + tA[r]);
            ov.w = lrelu(sA[r] * acc[j][3] + tA[r]);
            *(float4*)&a1[r][pt4] = ov;
        }
    }
    __syncthreads();

    // stage B: a2 = lrelu(BN(W2 @ a1)), 128 rows, K=256
    for (int ib = 0; ib < 2; ++ib) {
        int r0 = (rg << 3) + (ib << 2);
        float acc[4][4] = {};
        for (int p4i = 0; p4i < 64; ++p4i) {
            float af[4][4];
            for (int c = 0; c < 4; ++c) {
                float4 q = *(const float4*)&a1[(p4i << 2) + c][pt4];
                af[c][0] = q.x; af[c][1] = q.y; af[c][2] = q.z; af[c][3] = q.w;
            }
            for (int j = 0; j < 4; ++j) {
                float4 wv4 = *(const float4*)(w2 + (r0 + j) * 256 + (p4i << 2));
                float wv[4] = {wv4.x, wv4.y, wv4.z, wv4.w};
                for (int c = 0; c < 4; ++c)
                    for (int pp = 0; pp < 4; ++pp)
                        acc[j][pp] += wv[c] * af[c][pp];
            }
        }
        for (int j = 0; j < 4; ++j) {
            int r = r0 + j;
            float4 ov;
            ov.x = lrelu(sB[r] * acc[j][0] + tB[r]);
            ov.y = lrelu(sB[r] * acc[j][1] + tB[r]);
            ov.z = lrelu(sB[r] * acc[j][2] + tB[r]);
            ov.w = lrelu(sB[r] * acc[j][3] + tB[r]);
            *(float4*)&a2[r][pt4] = ov;
        }
    }
    __syncthreads();

    // stage C: out = w3 . a2 + b3
    if (t < 64) {
        float accv = 0.f;
        for (int q = 0; q < 128; ++q) accv += w3[q] * a2[q][t];
        accv += b3[0];
        out[b * N_ + n0 + t] = accv;
    }
}

// ---------------------------------------------------------------------------
extern "C" void kernel_launch(void* const* d_in, const int* in_sizes, int n_in,
                              void* d_out, int out_size, void* d_ws, size_t ws_size,
                              hipStream_t stream) {
    (void)in_sizes; (void)n_in; (void)out_size; (void)ws_size;
    const float* x    = (const float*)d_in[0];
    const float* wk1  = (const float*)d_in[1];
    const float* gk1  = (const float*)d_in[2];
    const float* bk1  = (const float*)d_in[3];
    const float* mk1  = (const float*)d_in[4];
    const float* vk1  = (const float*)d_in[5];
    const float* wk2  = (const float*)d_in[6];
    const float* gk2  = (const float*)d_in[7];
    const float* bk2  = (const float*)d_in[8];
    const float* mk2  = (const float*)d_in[9];
    const float* vk2  = (const float*)d_in[10];
    const float* w1   = (const float*)d_in[11];
    const float* g1   = (const float*)d_in[12];
    const float* b1   = (const float*)d_in[13];
    const float* m1   = (const float*)d_in[14];
    const float* v1   = (const float*)d_in[15];
    const float* w2   = (const float*)d_in[16];
    const float* g2   = (const float*)d_in[17];
    const float* b2   = (const float*)d_in[18];
    const float* m2   = (const float*)d_in[19];
    const float* v2   = (const float*)d_in[20];
    const float* w3   = (const float*)d_in[21];
    const float* b3   = (const float*)d_in[22];

    char* ws = (char*)d_ws;
    float* yA  = (float*)(ws);                 //  8 MB  [(b*N+n)*64 + o]
    float* dd  = (float*)(ws + 8388608);       //  8 MB  same layout
    float* xx  = (float*)(ws + 16777216);      //  128 KB [b*N+n]
    int*   idx = (int*)  (ws + 16908288);      //  2.5 MB [(b*N+n)*20 + k]
    float* ht  = (float*)(ws + 19529728);      //  8 MB  [b][o][n]

    k_pre <<<B_ * (N_ / 64), 256, 0, stream>>>(x, wk1, yA, dd, xx);
    k_topk<<<B_ * (N_ / 64), 256, 0, stream>>>(x, xx, idx);
    k_edge<<<B_ * (N_ / 8),  256, 0, stream>>>(yA, dd, idx, wk2,
                                               gk1, bk1, mk1, vk1,
                                               gk2, bk2, mk2, vk2, ht);
    k_head<<<B_ * (N_ / 64), 256, 0, stream>>>(ht, w1, g1, b1, m1, v1,
                                               w2, g2, b2, m2, v2, w3, b3,
                                               (float*)d_out);
}

// Round 3
// 868.822 us; speedup vs baseline: 1.9833x; 1.9833x over previous
//
#include <hip/hip_runtime.h>
#include <hip/hip_bf16.h>

#define B_ 8
#define C_ 64
#define N_ 4096
#define K_ 20
#define EPS_ 1e-5f
#define SLOPE_ 0.2f

__device__ __forceinline__ float lrelu(float x) { return x >= 0.f ? x : SLOPE_ * x; }

// ---------------------------------------------------------------------------
// Kernel A: per-point transforms yA = wA@x, dd = (wB-wA)@x, xx = |x|^2
// grid 512 (B * N/64), block 256
// ---------------------------------------------------------------------------
__global__ void __launch_bounds__(256) k_pre(const float* __restrict__ x,
                                             const float* __restrict__ wk1,
                                             float* __restrict__ yA,
                                             float* __restrict__ dd,
                                             float* __restrict__ xx) {
    __shared__ float w[64][128];
    __shared__ float xs[64][64];
    int t = threadIdx.x;
    int blk = blockIdx.x;
    int b = blk >> 6;
    int n0 = (blk & 63) << 6;

    for (int i = 0; i < 8; ++i) {
        int j = i * 256 + t;
        float4 v = ((const float4*)wk1)[j];
        int o = j >> 5;
        int c4 = (j & 31) << 2;
        w[o][c4 + 0] = v.x; w[o][c4 + 1] = v.y;
        w[o][c4 + 2] = v.z; w[o][c4 + 3] = v.w;
    }
    const float* xb = x + (size_t)b * C_ * N_;
    for (int i = 0; i < 4; ++i) {
        int j = i * 256 + t;
        int c = j >> 4;
        int p4 = (j & 15) << 2;
        float4 v = *(const float4*)(xb + c * N_ + n0 + p4);
        xs[c][p4 + 0] = v.x; xs[c][p4 + 1] = v.y;
        xs[c][p4 + 2] = v.z; xs[c][p4 + 3] = v.w;
    }
    __syncthreads();

    if (t < 64) {
        float s = 0.f;
        for (int c = 0; c < 64; ++c) { float xv = xs[c][t]; s += xv * xv; }
        xx[b * N_ + n0 + t] = s;
    }

    int p = t & 63, og = t >> 6;
    for (int oi = 0; oi < 16; ++oi) {
        int o = og * 16 + oi;
        float sA = 0.f, sB = 0.f;
        for (int c = 0; c < 64; ++c) {
            float xv = xs[c][p];
            sA += w[o][c] * xv;
            sB += w[o][64 + c] * xv;
        }
        size_t base = ((size_t)(b * N_ + n0 + p)) * 64 + o;
        yA[base] = sA;
        dd[base] = sB - sA;
    }
}

// ---------------------------------------------------------------------------
// Kernel B: top-20 neighbors by score = 2*dot(x_n,x_m) - |x_m|^2
// grid 512 (B * N/64 rows), block 256 (4 waves x 16 rows).
// Gram in 64x64 chunks (4x4 register tile); selection via wave-distributed
// sorted top-20 in registers (lanes 0..19), ballot-filtered inserts.
// ---------------------------------------------------------------------------
__global__ void __launch_bounds__(256) k_topk(const float* __restrict__ x,
                                              const float* __restrict__ xx,
                                              int* __restrict__ idxg) {
    __shared__ float xn[64][64];      // [ch][row]
    __shared__ float xm[2][64][64];   // [buf][ch][cand]
    __shared__ float sc[64][68];      // [row][cand], padded
    int t = threadIdx.x;
    int lane = t & 63;
    int w = t >> 6;                   // wave 0..3
    int blk = blockIdx.x;
    int b = blk >> 6;
    int n0 = (blk & 63) << 6;
    const float* xb = x + (size_t)b * C_ * N_;
    const float* xxb = xx + b * N_;

    // stage xn (block's 64 rows) and xm[0] (chunk 0)
    for (int i = 0; i < 4; ++i) {
        int j = i * 256 + t;
        int c = j >> 4;
        int p4 = (j & 15) << 2;
        float4 v = *(const float4*)(xb + c * N_ + n0 + p4);
        xn[c][p4 + 0] = v.x; xn[c][p4 + 1] = v.y;
        xn[c][p4 + 2] = v.z; xn[c][p4 + 3] = v.w;
        float4 u = *(const float4*)(xb + c * N_ + p4);      // m0 = 0
        xm[0][c][p4 + 0] = u.x; xm[0][c][p4 + 1] = u.y;
        xm[0][c][p4 + 2] = u.z; xm[0][c][p4 + 3] = u.w;
    }

    // wave-distributed top-20 lists: lane i holds element i of each row's list
    float lv[16];
    int   li[16];
#pragma unroll
    for (int r = 0; r < 16; ++r) { lv[r] = -3.0e38f; li[r] = 0; }

    int tr = t >> 4, tc = t & 15;
    int p = 0;
    __syncthreads();

    for (int mc = 0; mc < 64; ++mc) {
        int m0 = mc << 6;
        // ---- Gram: sc[row][cand] for this chunk (identical math to before)
        float acc[4][4] = {};
        for (int c = 0; c < 64; ++c) {
            float4 a4 = *(const float4*)&xn[c][tr << 2];
            float4 b4 = *(const float4*)&xm[p][c][tc << 2];
            float av[4] = {a4.x, a4.y, a4.z, a4.w};
            float bv[4] = {b4.x, b4.y, b4.z, b4.w};
            for (int jj = 0; jj < 4; ++jj)
                for (int ii = 0; ii < 4; ++ii)
                    acc[jj][ii] += av[jj] * bv[ii];
        }
        for (int ii = 0; ii < 4; ++ii) {
            float xv = xxb[m0 + (tc << 2) + ii];
            for (int jj = 0; jj < 4; ++jj)
                sc[(tr << 2) + jj][(tc << 2) + ii] = 2.f * acc[jj][ii] - xv;
        }
        __syncthreads();   // sc ready; xm[p] consumed

        // ---- stage next chunk into xm[p^1] (overlaps selection below)
        if (mc + 1 < 64) {
            int m1 = (mc + 1) << 6;
            for (int i = 0; i < 4; ++i) {
                int j = i * 256 + t;
                int c = j >> 4;
                int p4 = (j & 15) << 2;
                float4 u = *(const float4*)(xb + c * N_ + m1 + p4);
                xm[p ^ 1][c][p4 + 0] = u.x; xm[p ^ 1][c][p4 + 1] = u.y;
                xm[p ^ 1][c][p4 + 2] = u.z; xm[p ^ 1][c][p4 + 3] = u.w;
            }
        }

        // ---- selection: each wave owns rows w*16 .. w*16+15
#pragma unroll
        for (int r = 0; r < 16; ++r) {
            int lrow = (w << 4) + r;
            float s = sc[lrow][lane];               // conflict-free
            float mnc = __shfl(lv[r], 19);
            unsigned long long mask = __ballot(s > mnc);
            while (mask) {
                int j = (int)__builtin_ctzll(mask);
                mask &= mask - 1;
                float sv = __shfl(s, j);
                if (sv > mnc) {                      // wave-uniform re-check
                    unsigned long long gt = __ballot(lane < 20 && lv[r] > sv);
                    int cpos = __popcll(gt);
                    float upv = __shfl_up(lv[r], 1);
                    int   upi = __shfl_up(li[r], 1);
                    if (lane >= cpos && lane < 20) {
                        lv[r] = (lane == cpos) ? sv : upv;
                        li[r] = (lane == cpos) ? (m0 + j) : upi;
                    }
                    mnc = __shfl(lv[r], 19);
                }
            }
        }
        __syncthreads();   // selection done (sc reusable), xm[p^1] landed
        p ^= 1;
    }

    // write out indices (set order is irrelevant downstream)
#pragma unroll
    for (int r = 0; r < 16; ++r) {
        int n = n0 + (w << 4) + r;
        if (lane < K_)
            idxg[((size_t)(b * N_ + n)) * K_ + lane] = li[r];
    }
}

// ---------------------------------------------------------------------------
// Kernel C1: gather + BN1/lrelu -> conv_k2 -> max_k -> BN2/lrelu -> ht[b][o][n]
// grid 4096 (B * N/8), block 256 (8 points/block, 32 threads/point)
// ---------------------------------------------------------------------------
__global__ void __launch_bounds__(256) k_edge(const float* __restrict__ yA,
                                              const float* __restrict__ dd,
                                              const int* __restrict__ idxg,
                                              const float* __restrict__ wk2,
                                              const float* __restrict__ g1,
                                              const float* __restrict__ bb1,
                                              const float* __restrict__ mm1,
                                              const float* __restrict__ vv1,
                                              const float* __restrict__ g2,
                                              const float* __restrict__ bb2,
                                              const float* __restrict__ mm2,
                                              const float* __restrict__ vv2,
                                              float* __restrict__ ht) {
    __shared__ float wt[64][68];
    __shared__ float tmf[8 * 1412];
    __shared__ float ddl[8][64];
    __shared__ float s1c[64], t1c[64], s2c[64], t2c[64];
    __shared__ int   il[8][K_];
    __shared__ float hl[8][64];
    int t = threadIdx.x;
    int blk = blockIdx.x;
    int b = blk >> 9;
    int n0 = (blk & 511) << 3;

    for (int i = 0; i < 16; ++i) {
        int j = i * 256 + t;
        int oo = j >> 6, ic = j & 63;
        wt[ic][oo] = wk2[j];
    }
    if (t < 64) {
        float g = g1[t], be = bb1[t], m = mm1[t], v = vv1[t];
        float s = g * rsqrtf(v + EPS_);
        s1c[t] = s; t1c[t] = be - m * s;
        g = g2[t]; be = bb2[t]; m = mm2[t]; v = vv2[t];
        s = g * rsqrtf(v + EPS_);
        s2c[t] = s; t2c[t] = be - m * s;
    }
    size_t pbase = (size_t)(b * N_ + n0);
    for (int i = t; i < 512; i += 256) {
        int pt = i >> 6, o = i & 63;
        ddl[pt][o] = dd[(pbase + pt) * 64 + o];
    }
    if (t < 8 * K_) {
        int pt = t / K_, k = t % K_;
        il[pt][k] = idxg[(pbase + pt) * K_ + k];
    }
    __syncthreads();

    const float* yAb = yA + (size_t)(b * N_) * 64;
    for (int i = 0; i < 10; ++i) {
        int j = i * 256 + t;
        int pt = j / 320;
        int r = j - pt * 320;
        int k = r >> 4;
        int f = r & 15;
        int m = il[pt][k];
        float4 y4 = *(const float4*)(yAb + (size_t)m * 64 + (f << 2));
        float vals[4] = {y4.x, y4.y, y4.z, y4.w};
        int o = f << 2;
        for (int cdx = 0; cdx < 4; ++cdx) {
            int oc = o + cdx;
            float v = vals[cdx] + ddl[pt][oc];
            v = lrelu(s1c[oc] * v + t1c[oc]);
            tmf[pt * 1412 + oc * 22 + k] = v;
        }
    }
    __syncthreads();

    int pt = t >> 5, u = t & 31;
    int o2_0 = (u & 7) << 3;
    int k0 = (u >> 3) * 5;
    float acc[8][5];
    for (int i = 0; i < 8; ++i)
        for (int q = 0; q < 5; ++q) acc[i][q] = 0.f;
    const float* tmp_ = &tmf[pt * 1412];
    for (int o = 0; o < 64; ++o) {
        float4 w0 = *(const float4*)&wt[o][o2_0];
        float4 w1v = *(const float4*)&wt[o][o2_0 + 4];
        float wv[8] = {w0.x, w0.y, w0.z, w0.w, w1v.x, w1v.y, w1v.z, w1v.w};
        float tvv[5];
        for (int q = 0; q < 5; ++q) tvv[q] = tmp_[o * 22 + k0 + q];
        for (int i = 0; i < 8; ++i)
            for (int q = 0; q < 5; ++q)
                acc[i][q] += wv[i] * tvv[q];
    }
    for (int i = 0; i < 8; ++i) {
        float pm = acc[i][0];
        for (int q = 1; q < 5; ++q) pm = fmaxf(pm, acc[i][q]);
        pm = fmaxf(pm, __shfl_xor(pm, 8));
        pm = fmaxf(pm, __shfl_xor(pm, 16));
        if ((u >> 3) == 0) {
            int o2 = o2_0 + i;
            hl[pt][o2] = lrelu(s2c[o2] * pm + t2c[o2]);
        }
    }
    __syncthreads();

    float* htb = ht + (size_t)b * 64 * N_;
    for (int i = t; i < 512; i += 256) {
        int o = i >> 3, pt2 = i & 7;
        htb[o * N_ + n0 + pt2] = hl[pt2][o];
    }
}

// ---------------------------------------------------------------------------
// Kernel C2: MLP head 64 -> 256 -> 128 -> 1 per point, 64 points per block
// grid 512, block 256
// ---------------------------------------------------------------------------
__global__ void __launch_bounds__(256) k_head(const float* __restrict__ ht,
                                              const float* __restrict__ w1,
                                              const float* __restrict__ g1,
                                              const float* __restrict__ bb1,
                                              const float* __restrict__ mm1,
                                              const float* __restrict__ vv1,
                                              const float* __restrict__ w2,
                                              const float* __restrict__ g2,
                                              const float* __restrict__ bb2,
                                              const float* __restrict__ mm2,
                                              const float* __restrict__ vv2,
                                              const float* __restrict__ w3,
                                              const float* __restrict__ b3,
                                              float* __restrict__ out) {
    __shared__ float hbuf[64][64];
    __shared__ float a1[256][64];
    __shared__ float a2[128][64];
    __shared__ float sA[256], tA[256], sB[128], tB[128];
    int t = threadIdx.x;
    int blk = blockIdx.x;
    int b = blk >> 6;
    int n0 = (blk & 63) << 6;
    const float* htb = ht + (size_t)b * 64 * N_;

    for (int i = 0; i < 16; ++i) {
        int j = i * 256 + t;
        int o = j >> 6, pt = j & 63;
        hbuf[o][pt] = htb[o * N_ + n0 + pt];
    }
    {
        float g = g1[t], be = bb1[t], m = mm1[t], v = vv1[t];
        float s = g * rsqrtf(v + EPS_);
        sA[t] = s; tA[t] = be - m * s;
    }
    if (t < 128) {
        float g = g2[t], be = bb2[t], m = mm2[t], v = vv2[t];
        float s = g * rsqrtf(v + EPS_);
        sB[t] = s; tB[t] = be - m * s;
    }
    __syncthreads();

    int ptg = t & 15, rg = t >> 4;
    int pt4 = ptg << 2;

    for (int ib = 0; ib < 4; ++ib) {
        int r0 = (rg << 4) + (ib << 2);
        float acc[4][4] = {};
        for (int o4 = 0; o4 < 16; ++o4) {
            float hf[4][4];
            for (int c = 0; c < 4; ++c) {
                float4 q = *(const float4*)&hbuf[(o4 << 2) + c][pt4];
                hf[c][0] = q.x; hf[c][1] = q.y; hf[c][2] = q.z; hf[c][3] = q.w;
            }
            for (int j = 0; j < 4; ++j) {
                float4 wv4 = *(const float4*)(w1 + (r0 + j) * 64 + (o4 << 2));
                float wv[4] = {wv4.x, wv4.y, wv4.z, wv4.w};
                for (int c = 0; c < 4; ++c)
                    for (int pp = 0; pp < 4; ++pp)
                        acc[j][pp] += wv[c] * hf[c][pp];
            }
        }
        for (int j = 0; j < 4; ++j) {
            int r = r0 + j;
            float4 ov;
            ov.x = lrelu(sA[r] * acc[j][0] + tA[r]);
            ov.y = lrelu(sA[r] * acc[j][1] + tA[r]);
            ov.z = lrelu(sA[r] * acc[j][2] + tA[r]);
            ov.w = lrelu(sA[r] * acc[j][3] + tA[r]);
            *(float4*)&a1[r][pt4] = ov;
        }
    }
    __syncthreads();

    for (int ib = 0; ib < 2; ++ib) {
        int r0 = (rg << 3) + (ib << 2);
        float acc[4][4] = {};
        for (int p4i = 0; p4i < 64; ++p4i) {
            float af[4][4];
            for (int c = 0; c < 4; ++c) {
                float4 q = *(const float4*)&a1[(p4i << 2) + c][pt4];
                af[c][0] = q.x; af[c][1] = q.y; af[c][2] = q.z; af[c][3] = q.w;
            }
            for (int j = 0; j < 4; ++j) {
                float4 wv4 = *(const float4*)(w2 + (r0 + j) * 256 + (p4i << 2));
                float wv[4] = {wv4.x, wv4.y, wv4.z, wv4.w};
                for (int c = 0; c < 4; ++c)
                    for (int pp = 0; pp < 4; ++pp)
                        acc[j][pp] += wv[c] * af[c][pp];
            }
        }
        for (int j = 0; j < 4; ++j) {
            int r = r0 + j;
            float4 ov;
            ov.x = lrelu(sB[r] * acc[j][0] + tB[r]);
            ov.y = lrelu(sB[r] * acc[j][1] + tB[r]);
            ov.z = lrelu(sB[r] * acc[j][2] + tB[r]);
            ov.w = lrelu(sB[r] * acc[j][3] + tB[r]);
            *(float4*)&a2[r][pt4] = ov;
        }
    }
    __syncthreads();

    if (t < 64) {
        float accv = 0.f;
        for (int q = 0; q < 128; ++q) accv += w3[q] * a2[q][t];
        accv += b3[0];
        out[b * N_ + n0 + t] = accv;
    }
}

// ---------------------------------------------------------------------------
extern "C" void kernel_launch(void* const* d_in, const int* in_sizes, int n_in,
                              void* d_out, int out_size, void* d_ws, size_t ws_size,
                              hipStream_t stream) {
    (void)in_sizes; (void)n_in; (void)out_size; (void)ws_size;
    const float* x    = (const float*)d_in[0];
    const float* wk1  = (const float*)d_in[1];
    const float* gk1  = (const float*)d_in[2];
    const float* bk1  = (const float*)d_in[3];
    const float* mk1  = (const float*)d_in[4];
    const float* vk1  = (const float*)d_in[5];
    const float* wk2  = (const float*)d_in[6];
    const float* gk2  = (const float*)d_in[7];
    const float* bk2  = (const float*)d_in[8];
    const float* mk2  = (const float*)d_in[9];
    const float* vk2  = (const float*)d_in[10];
    const float* w1   = (const float*)d_in[11];
    const float* g1   = (const float*)d_in[12];
    const float* b1   = (const float*)d_in[13];
    const float* m1   = (const float*)d_in[14];
    const float* v1   = (const float*)d_in[15];
    const float* w2   = (const float*)d_in[16];
    const float* g2   = (const float*)d_in[17];
    const float* b2   = (const float*)d_in[18];
    const float* m2   = (const float*)d_in[19];
    const float* v2   = (const float*)d_in[20];
    const float* w3   = (const float*)d_in[21];
    const float* b3   = (const float*)d_in[22];

    char* ws = (char*)d_ws;
    float* yA  = (float*)(ws);                 //  8 MB
    float* dd  = (float*)(ws + 8388608);       //  8 MB
    float* xx  = (float*)(ws + 16777216);      //  128 KB
    int*   idx = (int*)  (ws + 16908288);      //  2.5 MB
    float* ht  = (float*)(ws + 19529728);      //  8 MB

    k_pre <<<B_ * (N_ / 64), 256, 0, stream>>>(x, wk1, yA, dd, xx);
    k_topk<<<B_ * (N_ / 64), 256, 0, stream>>>(x, xx, idx);
    k_edge<<<B_ * (N_ / 8),  256, 0, stream>>>(yA, dd, idx, wk2,
                                               gk1, bk1, mk1, vk1,
                                               gk2, bk2, mk2, vk2, ht);
    k_head<<<B_ * (N_ / 64), 256, 0, stream>>>(ht, w1, g1, b1, m1, v1,
                                               w2, g2, b2, m2, v2, w3, b3,
                                               (float*)d_out);
}

// Round 4
// 712.940 us; speedup vs baseline: 2.4169x; 1.2186x over previous
//
#include <hip/hip_runtime.h>
#include <hip/hip_bf16.h>

#define B_ 8
#define C_ 64
#define N_ 4096
#define K_ 20
#define EPS_ 1e-5f
#define SLOPE_ 0.2f

typedef __attribute__((ext_vector_type(8))) short bf16x8;
typedef __attribute__((ext_vector_type(4))) float f32x4;

__device__ __forceinline__ float lrelu(float x) { return x >= 0.f ? x : SLOPE_ * x; }
__device__ __forceinline__ float bf2f(unsigned short u) {
    return __uint_as_float(((unsigned int)u) << 16);
}
__device__ __forceinline__ unsigned short f2bf(float f) {
    unsigned int u = __float_as_uint(f);
    return (unsigned short)((u + 0x7FFFu + ((u >> 16) & 1u)) >> 16);
}

// ---------------------------------------------------------------------------
// Kernel A: per-point transforms yA = wA@x, dd = (wB-wA)@x, xx = |x|^2
// ---------------------------------------------------------------------------
__global__ void __launch_bounds__(256) k_pre(const float* __restrict__ x,
                                             const float* __restrict__ wk1,
                                             float* __restrict__ yA,
                                             float* __restrict__ dd,
                                             float* __restrict__ xx) {
    __shared__ float w[64][128];
    __shared__ float xs[64][64];
    int t = threadIdx.x;
    int blk = blockIdx.x;
    int b = blk >> 6;
    int n0 = (blk & 63) << 6;

    for (int i = 0; i < 8; ++i) {
        int j = i * 256 + t;
        float4 v = ((const float4*)wk1)[j];
        int o = j >> 5;
        int c4 = (j & 31) << 2;
        w[o][c4 + 0] = v.x; w[o][c4 + 1] = v.y;
        w[o][c4 + 2] = v.z; w[o][c4 + 3] = v.w;
    }
    const float* xb = x + (size_t)b * C_ * N_;
    for (int i = 0; i < 4; ++i) {
        int j = i * 256 + t;
        int c = j >> 4;
        int p4 = (j & 15) << 2;
        float4 v = *(const float4*)(xb + c * N_ + n0 + p4);
        xs[c][p4 + 0] = v.x; xs[c][p4 + 1] = v.y;
        xs[c][p4 + 2] = v.z; xs[c][p4 + 3] = v.w;
    }
    __syncthreads();

    if (t < 64) {
        float s = 0.f;
        for (int c = 0; c < 64; ++c) { float xv = xs[c][t]; s += xv * xv; }
        xx[b * N_ + n0 + t] = s;
    }

    int p = t & 63, og = t >> 6;
    for (int oi = 0; oi < 16; ++oi) {
        int o = og * 16 + oi;
        float sA = 0.f, sB = 0.f;
        for (int c = 0; c < 64; ++c) {
            float xv = xs[c][p];
            sA += w[o][c] * xv;
            sB += w[o][64 + c] * xv;
        }
        size_t base = ((size_t)(b * N_ + n0 + p)) * 64 + o;
        yA[base] = sA;
        dd[base] = sB - sA;
    }
}

// ---------------------------------------------------------------------------
// Kernel B: top-20 neighbors by score = 2*dot(x_n,x_m) - |x_m|^2
// MFMA split-bf16 Gram (hi/lo, 4 cross terms = fp32-grade accuracy).
// grid 512 (B * N/64 rows), block 256 (4 waves x 16 rows, wave-local).
// ---------------------------------------------------------------------------
__global__ void __launch_bounds__(256) k_topk(const float* __restrict__ x,
                                              const float* __restrict__ xx,
                                              int* __restrict__ idxg) {
    __shared__ unsigned short xmh[2][64 * 64];  // [buf][cand][c] bf16 hi, 16B-unit XOR-swizzled
    __shared__ unsigned short xml[2][64 * 64];  // bf16 lo
    __shared__ float sc[64][68];                // [row][cand] scores
    int t = threadIdx.x;
    int lane = t & 63;
    int w = t >> 6;
    int blk = blockIdx.x;
    int b = blk >> 6;
    int n0 = (blk & 63) << 6;
    const float* xb = x + (size_t)b * C_ * N_;
    const float* xxb = xx + b * N_;

    // ---- A fragments: wave w owns rows n0 + w*16 .. +15 (built once).
    // mfma_f32_16x16x32_bf16 A-layout: lane holds m = lane&15, k = (lane>>4)*8 + j
    int arow = n0 + (w << 4) + (lane & 15);
    int k8 = (lane >> 4) << 3;
    bf16x8 ah[2], al[2];
#pragma unroll
    for (int kc = 0; kc < 2; ++kc) {
#pragma unroll
        for (int j = 0; j < 8; ++j) {
            float v = xb[(size_t)(kc * 32 + k8 + j) * N_ + arow];
            unsigned short h = f2bf(v);
            unsigned short l = f2bf(v - bf2f(h));
            ah[kc][j] = (short)h;
            al[kc][j] = (short)l;
        }
    }

    // ---- staging: fp32 global -> hi/lo bf16 LDS (swizzled 16B units)
    auto stage = [&](int p, int m0) {
#pragma unroll
        for (int rep = 0; rep < 2; ++rep) {
            int i = t + (rep << 8);        // 0..511
            int nl = i & 63;               // local cand
            int oct = i >> 6;              // c-octet 0..7
            bf16x8 hv, lv8;
#pragma unroll
            for (int j = 0; j < 8; ++j) {
                float v = xb[(size_t)(oct * 8 + j) * N_ + m0 + nl];
                unsigned short h = f2bf(v);
                hv[j] = (short)h;
                lv8[j] = (short)f2bf(v - bf2f(h));
            }
            int unit = oct ^ (nl & 7);
            *(bf16x8*)&xmh[p][nl * 64 + unit * 8] = hv;
            *(bf16x8*)&xml[p][nl * 64 + unit * 8] = lv8;
        }
    };

    float lv[16];
    int   li[16];
#pragma unroll
    for (int r = 0; r < 16; ++r) { lv[r] = -3.0e38f; li[r] = 0; }

    stage(0, 0);
    __syncthreads();
    int p = 0;

    for (int mc = 0; mc < 64; ++mc) {
        int m0 = mc << 6;
        // xx for this chunk's 4 cand tiles (L2-resident)
        float xxv[4];
#pragma unroll
        for (int ct = 0; ct < 4; ++ct)
            xxv[ct] = xxb[m0 + ct * 16 + (lane & 15)];

        // ---- MFMA Gram: 4 cand tiles x 2 K-chunks x 4 hi/lo cross terms
#pragma unroll
        for (int ct = 0; ct < 4; ++ct) {
            f32x4 acc = {0.f, 0.f, 0.f, 0.f};
            int n_ = ct * 16 + (lane & 15);
#pragma unroll
            for (int kc = 0; kc < 2; ++kc) {
                int unit = (kc * 4 + (lane >> 4)) ^ (n_ & 7);
                bf16x8 bh = *(const bf16x8*)&xmh[p][n_ * 64 + unit * 8];
                bf16x8 bl = *(const bf16x8*)&xml[p][n_ * 64 + unit * 8];
                acc = __builtin_amdgcn_mfma_f32_16x16x32_bf16(ah[kc], bh, acc, 0, 0, 0);
                acc = __builtin_amdgcn_mfma_f32_16x16x32_bf16(ah[kc], bl, acc, 0, 0, 0);
                acc = __builtin_amdgcn_mfma_f32_16x16x32_bf16(al[kc], bh, acc, 0, 0, 0);
                acc = __builtin_amdgcn_mfma_f32_16x16x32_bf16(al[kc], bl, acc, 0, 0, 0);
            }
            // D layout: col = lane&15, row = (lane>>4)*4 + r  (wave-local sc rows)
#pragma unroll
            for (int r = 0; r < 4; ++r)
                sc[(w << 4) + ((lane >> 4) << 2) + r][ct * 16 + (lane & 15)] =
                    2.f * acc[r] - xxv[ct];
        }

        // ---- stage next chunk (global latency overlaps selection below)
        if (mc + 1 < 64) stage(p ^ 1, (mc + 1) << 6);

        // ---- selection: wave w owns rows w*16..+15 (sc rows it just wrote)
#pragma unroll
        for (int r = 0; r < 16; ++r) {
            int lrow = (w << 4) + r;
            float s = sc[lrow][lane];
            float mnc = __shfl(lv[r], 19);
            unsigned long long mask = __ballot(s > mnc);
            while (mask) {
                int j = (int)__builtin_ctzll(mask);
                mask &= mask - 1;
                float sv = __shfl(s, j);
                if (sv > mnc) {
                    unsigned long long gt = __ballot(lane < 20 && lv[r] > sv);
                    int cpos = __popcll(gt);
                    float upv = __shfl_up(lv[r], 1);
                    int   upi = __shfl_up(li[r], 1);
                    if (lane >= cpos && lane < 20) {
                        lv[r] = (lane == cpos) ? sv : upv;
                        li[r] = (lane == cpos) ? (m0 + j) : upi;
                    }
                    mnc = __shfl(lv[r], 19);
                }
            }
        }
        __syncthreads();
        p ^= 1;
    }

#pragma unroll
    for (int r = 0; r < 16; ++r) {
        int n = n0 + (w << 4) + r;
        if (lane < K_)
            idxg[((size_t)(b * N_ + n)) * K_ + lane] = li[r];
    }
}

// ---------------------------------------------------------------------------
// Kernel C1: gather + BN1/lrelu -> conv_k2 -> max_k -> BN2/lrelu -> ht[b][o][n]
// ---------------------------------------------------------------------------
__global__ void __launch_bounds__(256) k_edge(const float* __restrict__ yA,
                                              const float* __restrict__ dd,
                                              const int* __restrict__ idxg,
                                              const float* __restrict__ wk2,
                                              const float* __restrict__ g1,
                                              const float* __restrict__ bb1,
                                              const float* __restrict__ mm1,
                                              const float* __restrict__ vv1,
                                              const float* __restrict__ g2,
                                              const float* __restrict__ bb2,
                                              const float* __restrict__ mm2,
                                              const float* __restrict__ vv2,
                                              float* __restrict__ ht) {
    __shared__ float wt[64][68];
    __shared__ float tmf[8 * 1412];
    __shared__ float ddl[8][64];
    __shared__ float s1c[64], t1c[64], s2c[64], t2c[64];
    __shared__ int   il[8][K_];
    __shared__ float hl[8][64];
    int t = threadIdx.x;
    int blk = blockIdx.x;
    int b = blk >> 9;
    int n0 = (blk & 511) << 3;

    for (int i = 0; i < 16; ++i) {
        int j = i * 256 + t;
        int oo = j >> 6, ic = j & 63;
        wt[ic][oo] = wk2[j];
    }
    if (t < 64) {
        float g = g1[t], be = bb1[t], m = mm1[t], v = vv1[t];
        float s = g * rsqrtf(v + EPS_);
        s1c[t] = s; t1c[t] = be - m * s;
        g = g2[t]; be = bb2[t]; m = mm2[t]; v = vv2[t];
        s = g * rsqrtf(v + EPS_);
        s2c[t] = s; t2c[t] = be - m * s;
    }
    size_t pbase = (size_t)(b * N_ + n0);
    for (int i = t; i < 512; i += 256) {
        int pt = i >> 6, o = i & 63;
        ddl[pt][o] = dd[(pbase + pt) * 64 + o];
    }
    if (t < 8 * K_) {
        int pt = t / K_, k = t % K_;
        il[pt][k] = idxg[(pbase + pt) * K_ + k];
    }
    __syncthreads();

    const float* yAb = yA + (size_t)(b * N_) * 64;
    for (int i = 0; i < 10; ++i) {
        int j = i * 256 + t;
        int pt = j / 320;
        int r = j - pt * 320;
        int k = r >> 4;
        int f = r & 15;
        int m = il[pt][k];
        float4 y4 = *(const float4*)(yAb + (size_t)m * 64 + (f << 2));
        float vals[4] = {y4.x, y4.y, y4.z, y4.w};
        int o = f << 2;
        for (int cdx = 0; cdx < 4; ++cdx) {
            int oc = o + cdx;
            float v = vals[cdx] + ddl[pt][oc];
            v = lrelu(s1c[oc] * v + t1c[oc]);
            tmf[pt * 1412 + oc * 22 + k] = v;
        }
    }
    __syncthreads();

    int pt = t >> 5, u = t & 31;
    int o2_0 = (u & 7) << 3;
    int k0 = (u >> 3) * 5;
    float acc[8][5];
    for (int i = 0; i < 8; ++i)
        for (int q = 0; q < 5; ++q) acc[i][q] = 0.f;
    const float* tmp_ = &tmf[pt * 1412];
    for (int o = 0; o < 64; ++o) {
        float4 w0 = *(const float4*)&wt[o][o2_0];
        float4 w1v = *(const float4*)&wt[o][o2_0 + 4];
        float wv[8] = {w0.x, w0.y, w0.z, w0.w, w1v.x, w1v.y, w1v.z, w1v.w};
        float tvv[5];
        for (int q = 0; q < 5; ++q) tvv[q] = tmp_[o * 22 + k0 + q];
        for (int i = 0; i < 8; ++i)
            for (int q = 0; q < 5; ++q)
                acc[i][q] += wv[i] * tvv[q];
    }
    for (int i = 0; i < 8; ++i) {
        float pm = acc[i][0];
        for (int q = 1; q < 5; ++q) pm = fmaxf(pm, acc[i][q]);
        pm = fmaxf(pm, __shfl_xor(pm, 8));
        pm = fmaxf(pm, __shfl_xor(pm, 16));
        if ((u >> 3) == 0) {
            int o2 = o2_0 + i;
            hl[pt][o2] = lrelu(s2c[o2] * pm + t2c[o2]);
        }
    }
    __syncthreads();

    float* htb = ht + (size_t)b * 64 * N_;
    for (int i = t; i < 512; i += 256) {
        int o = i >> 3, pt2 = i & 7;
        htb[o * N_ + n0 + pt2] = hl[pt2][o];
    }
}

// ---------------------------------------------------------------------------
// Kernel C2: MLP head 64 -> 256 -> 128 -> 1 per point, 64 points per block
// ---------------------------------------------------------------------------
__global__ void __launch_bounds__(256) k_head(const float* __restrict__ ht,
                                              const float* __restrict__ w1,
                                              const float* __restrict__ g1,
                                              const float* __restrict__ bb1,
                                              const float* __restrict__ mm1,
                                              const float* __restrict__ vv1,
                                              const float* __restrict__ w2,
                                              const float* __restrict__ g2,
                                              const float* __restrict__ bb2,
                                              const float* __restrict__ mm2,
                                              const float* __restrict__ vv2,
                                              const float* __restrict__ w3,
                                              const float* __restrict__ b3,
                                              float* __restrict__ out) {
    __shared__ float hbuf[64][64];
    __shared__ float a1[256][64];
    __shared__ float a2[128][64];
    __shared__ float sA[256], tA[256], sB[128], tB[128];
    int t = threadIdx.x;
    int blk = blockIdx.x;
    int b = blk >> 6;
    int n0 = (blk & 63) << 6;
    const float* htb = ht + (size_t)b * 64 * N_;

    for (int i = 0; i < 16; ++i) {
        int j = i * 256 + t;
        int o = j >> 6, pt = j & 63;
        hbuf[o][pt] = htb[o * N_ + n0 + pt];
    }
    {
        float g = g1[t], be = bb1[t], m = mm1[t], v = vv1[t];
        float s = g * rsqrtf(v + EPS_);
        sA[t] = s; tA[t] = be - m * s;
    }
    if (t < 128) {
        float g = g2[t], be = bb2[t], m = mm2[t], v = vv2[t];
        float s = g * rsqrtf(v + EPS_);
        sB[t] = s; tB[t] = be - m * s;
    }
    __syncthreads();

    int ptg = t & 15, rg = t >> 4;
    int pt4 = ptg << 2;

    for (int ib = 0; ib < 4; ++ib) {
        int r0 = (rg << 4) + (ib << 2);
        float acc[4][4] = {};
        for (int o4 = 0; o4 < 16; ++o4) {
            float hf[4][4];
            for (int c = 0; c < 4; ++c) {
                float4 q = *(const float4*)&hbuf[(o4 << 2) + c][pt4];
                hf[c][0] = q.x; hf[c][1] = q.y; hf[c][2] = q.z; hf[c][3] = q.w;
            }
            for (int j = 0; j < 4; ++j) {
                float4 wv4 = *(const float4*)(w1 + (r0 + j) * 64 + (o4 << 2));
                float wv[4] = {wv4.x, wv4.y, wv4.z, wv4.w};
                for (int c = 0; c < 4; ++c)
                    for (int pp = 0; pp < 4; ++pp)
                        acc[j][pp] += wv[c] * hf[c][pp];
            }
        }
        for (int j = 0; j < 4; ++j) {
            int r = r0 + j;
            float4 ov;
            ov.x = lrelu(sA[r] * acc[j][0] + tA[r]);
            ov.y = lrelu(sA[r] * acc[j][1] + tA[r]);
            ov.z = lrelu(sA[r] * acc[j][2] + tA[r]);
            ov.w = lrelu(sA[r] * acc[j][3] + tA[r]);
            *(float4*)&a1[r][pt4] = ov;
        }
    }
    __syncthreads();

    for (int ib = 0; ib < 2; ++ib) {
        int r0 = (rg << 3) + (ib << 2);
        float acc[4][4] = {};
        for (int p4i = 0; p4i < 64; ++p4i) {
            float af[4][4];
            for (int c = 0; c < 4; ++c) {
                float4 q = *(const float4*)&a1[(p4i << 2) + c][pt4];
                af[c][0] = q.x; af[c][1] = q.y; af[c][2] = q.z; af[c][3] = q.w;
            }
            for (int j = 0; j < 4; ++j) {
                float4 wv4 = *(const float4*)(w2 + (r0 + j) * 256 + (p4i << 2));
                float wv[4] = {wv4.x, wv4.y, wv4.z, wv4.w};
                for (int c = 0; c < 4; ++c)
                    for (int pp = 0; pp < 4; ++pp)
                        acc[j][pp] += wv[c] * af[c][pp];
            }
        }
        for (int j = 0; j < 4; ++j) {
            int r = r0 + j;
            float4 ov;
            ov.x = lrelu(sB[r] * acc[j][0] + tB[r]);
            ov.y = lrelu(sB[r] * acc[j][1] + tB[r]);
            ov.z = lrelu(sB[r] * acc[j][2] + tB[r]);
            ov.w = lrelu(sB[r] * acc[j][3] + tB[r]);
            *(float4*)&a2[r][pt4] = ov;
        }
    }
    __syncthreads();

    if (t < 64) {
        float accv = 0.f;
        for (int q = 0; q < 128; ++q) accv += w3[q] * a2[q][t];
        accv += b3[0];
        out[b * N_ + n0 + t] = accv;
    }
}

// ---------------------------------------------------------------------------
extern "C" void kernel_launch(void* const* d_in, const int* in_sizes, int n_in,
                              void* d_out, int out_size, void* d_ws, size_t ws_size,
                              hipStream_t stream) {
    (void)in_sizes; (void)n_in; (void)out_size; (void)ws_size;
    const float* x    = (const float*)d_in[0];
    const float* wk1  = (const float*)d_in[1];
    const float* gk1  = (const float*)d_in[2];
    const float* bk1  = (const float*)d_in[3];
    const float* mk1  = (const float*)d_in[4];
    const float* vk1  = (const float*)d_in[5];
    const float* wk2  = (const float*)d_in[6];
    const float* gk2  = (const float*)d_in[7];
    const float* bk2  = (const float*)d_in[8];
    const float* mk2  = (const float*)d_in[9];
    const float* vk2  = (const float*)d_in[10];
    const float* w1   = (const float*)d_in[11];
    const float* g1   = (const float*)d_in[12];
    const float* b1   = (const float*)d_in[13];
    const float* m1   = (const float*)d_in[14];
    const float* v1   = (const float*)d_in[15];
    const float* w2   = (const float*)d_in[16];
    const float* g2   = (const float*)d_in[17];
    const float* b2   = (const float*)d_in[18];
    const float* m2   = (const float*)d_in[19];
    const float* v2   = (const float*)d_in[20];
    const float* w3   = (const float*)d_in[21];
    const float* b3   = (const float*)d_in[22];

    char* ws = (char*)d_ws;
    float* yA  = (float*)(ws);                 //  8 MB
    float* dd  = (float*)(ws + 8388608);       //  8 MB
    float* xx  = (float*)(ws + 16777216);      //  128 KB
    int*   idx = (int*)  (ws + 16908288);      //  2.5 MB
    float* ht  = (float*)(ws + 19529728);      //  8 MB

    k_pre <<<B_ * (N_ / 64), 256, 0, stream>>>(x, wk1, yA, dd, xx);
    k_topk<<<B_ * (N_ / 64), 256, 0, stream>>>(x, xx, idx);
    k_edge<<<B_ * (N_ / 8),  256, 0, stream>>>(yA, dd, idx, wk2,
                                               gk1, bk1, mk1, vk1,
                                               gk2, bk2, mk2, vk2, ht);
    k_head<<<B_ * (N_ / 64), 256, 0, stream>>>(ht, w1, g1, b1, m1, v1,
                                               w2, g2, b2, m2, v2, w3, b3,
                                               (float*)d_out);
}

// Round 5
// 664.705 us; speedup vs baseline: 2.5923x; 1.0726x over previous
//
#include <hip/hip_runtime.h>
#include <hip/hip_bf16.h>

#define B_ 8
#define C_ 64
#define N_ 4096
#define K_ 20
#define EPS_ 1e-5f
#define SLOPE_ 0.2f

typedef __attribute__((ext_vector_type(8))) short bf16x8;
typedef __attribute__((ext_vector_type(4))) float f32x4;

__device__ __forceinline__ float lrelu(float x) { return x >= 0.f ? x : SLOPE_ * x; }
__device__ __forceinline__ float bf2f(unsigned short u) {
    return __uint_as_float(((unsigned int)u) << 16);
}
__device__ __forceinline__ unsigned short f2bf(float f) {
    unsigned int u = __float_as_uint(f);
    return (unsigned short)((u + 0x7FFFu + ((u >> 16) & 1u)) >> 16);
}

// ---------------------------------------------------------------------------
// Kernel A: yA = wA@x, dd = (wB-wA)@x, xx = |x|^2, and pre-split bf16 hi/lo
// chunk images xps[b][chunk] (swizzled, byte-identical to k_topk LDS layout).
// grid 512 (B * N/64), block 256
// ---------------------------------------------------------------------------
__global__ void __launch_bounds__(256) k_pre(const float* __restrict__ x,
                                             const float* __restrict__ wk1,
                                             float* __restrict__ yA,
                                             float* __restrict__ dd,
                                             float* __restrict__ xx,
                                             unsigned short* __restrict__ xps) {
    __shared__ float w[64][128];
    __shared__ float xs[64][64];
    int t = threadIdx.x;
    int blk = blockIdx.x;
    int b = blk >> 6;
    int n0 = (blk & 63) << 6;

    for (int i = 0; i < 8; ++i) {
        int j = i * 256 + t;
        float4 v = ((const float4*)wk1)[j];
        int o = j >> 5;
        int c4 = (j & 31) << 2;
        w[o][c4 + 0] = v.x; w[o][c4 + 1] = v.y;
        w[o][c4 + 2] = v.z; w[o][c4 + 3] = v.w;
    }
    const float* xb = x + (size_t)b * C_ * N_;
    for (int i = 0; i < 4; ++i) {
        int j = i * 256 + t;
        int c = j >> 4;
        int p4 = (j & 15) << 2;
        float4 v = *(const float4*)(xb + c * N_ + n0 + p4);
        xs[c][p4 + 0] = v.x; xs[c][p4 + 1] = v.y;
        xs[c][p4 + 2] = v.z; xs[c][p4 + 3] = v.w;
    }
    __syncthreads();

    if (t < 64) {
        float s = 0.f;
        for (int c = 0; c < 64; ++c) { float xv = xs[c][t]; s += xv * xv; }
        xx[b * N_ + n0 + t] = s;
    }

    // emit pre-split swizzled chunk image: hi[4096] | lo[4096] ushorts
    {
        unsigned short* xc = xps + ((size_t)(b * 64 + (blk & 63))) * 8192;
#pragma unroll
        for (int q = 0; q < 2; ++q) {
            int i = q * 256 + t;          // 0..511 units
            int nl = i >> 3, oct = i & 7;
            bf16x8 hv, lv8;
#pragma unroll
            for (int j = 0; j < 8; ++j) {
                float v = xs[oct * 8 + j][nl];
                unsigned short hh = f2bf(v);
                hv[j] = (short)hh;
                lv8[j] = (short)f2bf(v - bf2f(hh));
            }
            int unit = oct ^ (nl & 7);
            *(bf16x8*)&xc[nl * 64 + unit * 8] = hv;
            *(bf16x8*)&xc[4096 + nl * 64 + unit * 8] = lv8;
        }
    }

    int p = t & 63, og = t >> 6;
    for (int oi = 0; oi < 16; ++oi) {
        int o = og * 16 + oi;
        float sA = 0.f, sB = 0.f;
        for (int c = 0; c < 64; ++c) {
            float xv = xs[c][p];
            sA += w[o][c] * xv;
            sB += w[o][64 + c] * xv;
        }
        size_t base = ((size_t)(b * N_ + n0 + p)) * 64 + o;
        yA[base] = sA;
        dd[base] = sB - sA;
    }
}

// ---------------------------------------------------------------------------
// Kernel B: top-20 neighbors by score = 2*dot(x_n,x_m) - |x_m|^2
// grid 512 (B * N/64 rows), block 512 = 8 waves: (wr = row group of 16,
// wc = candidate half of 32). Wave-pair lists merged exactly at the end.
// ---------------------------------------------------------------------------
__global__ void __launch_bounds__(512) k_topk(const unsigned short* __restrict__ xps,
                                              const float* __restrict__ xx,
                                              int* __restrict__ idxg) {
    __shared__ unsigned short xs_[2][8192];   // [buf][hi 4096 | lo 4096]
    __shared__ float sc[64][68];              // [row][cand] scores (+merge scratch)
    int t = threadIdx.x;
    int lane = t & 63;
    int w = t >> 6;               // 0..7
    int wr = w >> 1;              // row group
    int wc = w & 1;               // cand half
    int h = lane >> 5;            // half within wave
    int c = lane & 31;            // pos within half
    int blk = blockIdx.x;
    int b = blk >> 6;
    int n0 = (blk & 63) << 6;
    int bc = b << 6;              // chunk base for this batch
    const float* xxb = xx + b * N_;

    // ---- A fragments from pre-split image of this block's own chunk
    const unsigned short* xcA = xps + ((size_t)(bc + (blk & 63))) * 8192;
    int anl = (wr << 4) + (lane & 15);
    bf16x8 ah[2], al[2];
#pragma unroll
    for (int kc = 0; kc < 2; ++kc) {
        int unit = (kc * 4 + (lane >> 4)) ^ (anl & 7);
        ah[kc] = *(const bf16x8*)&xcA[anl * 64 + unit * 8];
        al[kc] = *(const bf16x8*)&xcA[4096 + anl * 64 + unit * 8];
    }

    // ---- staging: linear 16 KB copy (pre-swizzled in global)
    auto stage = [&](int p, int mc) {
        const ulonglong2* src = (const ulonglong2*)(xps + ((size_t)(bc + mc)) * 8192);
        ulonglong2* dst = (ulonglong2*)&xs_[p][0];
        dst[t] = src[t];
        dst[t + 512] = src[t + 512];
    };

    float lv[8];
    int   li[8];
#pragma unroll
    for (int i = 0; i < 8; ++i) { lv[i] = -3.0e38f; li[i] = 0; }

    // one segmented (width-32) insert pass: each 32-lane half inserts the
    // ballot-passing candidates of its row into the lane-distributed list.
    auto ins = [&](float& lvr, int& lir, float s, int cid) {
        float mnc = __shfl(lvr, 19, 32);
        unsigned long long bal = __ballot(s > mnc);
        unsigned int mask0 = (unsigned int)bal;
        unsigned int mask1 = (unsigned int)(bal >> 32);
        while (mask0 | mask1) {
            bool act = h ? (mask1 != 0) : (mask0 != 0);
            int js = h ? (mask1 ? __builtin_ctz(mask1) : 0)
                       : (mask0 ? __builtin_ctz(mask0) : 0);
            mask0 &= mask0 - 1;
            mask1 &= mask1 - 1;
            float sv = __shfl(s, js, 32);
            int  siv = __shfl(cid, js, 32);
            bool doit = act && (sv > mnc);
            unsigned long long gt = __ballot((c < 20) && (lvr > sv));
            int cpos = h ? __popc((unsigned int)(gt >> 32)) : __popc((unsigned int)gt);
            float upv = __shfl_up(lvr, 1, 32);
            int   upi = __shfl_up(lir, 1, 32);
            if (doit && c >= cpos && c < 20) {
                lvr = (c == cpos) ? sv : upv;
                lir = (c == cpos) ? siv : upi;
            }
            mnc = __shfl(lvr, 19, 32);
        }
    };

    stage(0, 0);
    __syncthreads();
    int p = 0;

    for (int mc = 0; mc < 64; ++mc) {
        int m0 = mc << 6;

        // ---- MFMA Gram: this wave's cand half (2 tiles of 16)
#pragma unroll
        for (int ct = 0; ct < 2; ++ct) {
            f32x4 acc = {0.f, 0.f, 0.f, 0.f};
            int n_ = (wc << 5) + ct * 16 + (lane & 15);
            float xxv = xxb[m0 + n_];
#pragma unroll
            for (int kc = 0; kc < 2; ++kc) {
                int unit = (kc * 4 + (lane >> 4)) ^ (n_ & 7);
                bf16x8 bh = *(const bf16x8*)&xs_[p][n_ * 64 + unit * 8];
                bf16x8 bl = *(const bf16x8*)&xs_[p][4096 + n_ * 64 + unit * 8];
                acc = __builtin_amdgcn_mfma_f32_16x16x32_bf16(ah[kc], bh, acc, 0, 0, 0);
                acc = __builtin_amdgcn_mfma_f32_16x16x32_bf16(ah[kc], bl, acc, 0, 0, 0);
                acc = __builtin_amdgcn_mfma_f32_16x16x32_bf16(al[kc], bh, acc, 0, 0, 0);
                acc = __builtin_amdgcn_mfma_f32_16x16x32_bf16(al[kc], bl, acc, 0, 0, 0);
            }
#pragma unroll
            for (int r = 0; r < 4; ++r)
                sc[(wr << 4) + ((lane >> 4) << 2) + r][n_] = 2.f * acc[r] - xxv;
        }

        // ---- stage next chunk (overlaps selection)
        if (mc + 1 < 64) stage(p ^ 1, mc + 1);

        // ---- selection: 8 passes, 2 rows per pass (32-lane halves)
#pragma unroll
        for (int i = 0; i < 8; ++i) {
            int lrow = (wr << 4) + (i << 1) + h;
            float s = sc[lrow][(wc << 5) + c];
            int cid = m0 + (wc << 5) + c;
            ins(lv[i], li[i], s, cid);
        }
        __syncthreads();
        p ^= 1;
    }

    // ---- exact merge of wave-pair half-lists
    if (wc == 1) {
#pragma unroll
        for (int i = 0; i < 8; ++i) {
            int lrow = (wr << 4) + (i << 1) + h;
            if (c < 20) {
                sc[lrow][c] = lv[i];
                ((int*)&sc[lrow][20])[c] = li[i];
            }
        }
    }
    __syncthreads();
    if (wc == 0) {
#pragma unroll
        for (int i = 0; i < 8; ++i) {
            int lrow = (wr << 4) + (i << 1) + h;
            float s = (c < 20) ? sc[lrow][c] : -3.0e38f;
            int cid = (c < 20) ? ((int*)&sc[lrow][20])[c] : 0;
            ins(lv[i], li[i], s, cid);
        }
#pragma unroll
        for (int i = 0; i < 8; ++i) {
            int n = n0 + (wr << 4) + (i << 1) + h;
            if (c < K_)
                idxg[((size_t)(b * N_ + n)) * K_ + c] = li[i];
        }
    }
}

// ---------------------------------------------------------------------------
// Kernel C1: gather + BN1/lrelu -> conv_k2 -> max_k -> BN2/lrelu -> ht[b][o][n]
// ---------------------------------------------------------------------------
__global__ void __launch_bounds__(256) k_edge(const float* __restrict__ yA,
                                              const float* __restrict__ dd,
                                              const int* __restrict__ idxg,
                                              const float* __restrict__ wk2,
                                              const float* __restrict__ g1,
                                              const float* __restrict__ bb1,
                                              const float* __restrict__ mm1,
                                              const float* __restrict__ vv1,
                                              const float* __restrict__ g2,
                                              const float* __restrict__ bb2,
                                              const float* __restrict__ mm2,
                                              const float* __restrict__ vv2,
                                              float* __restrict__ ht) {
    __shared__ float wt[64][68];
    __shared__ float tmf[8 * 1412];
    __shared__ float ddl[8][64];
    __shared__ float s1c[64], t1c[64], s2c[64], t2c[64];
    __shared__ int   il[8][K_];
    __shared__ float hl[8][64];
    int t = threadIdx.x;
    int blk = blockIdx.x;
    int b = blk >> 9;
    int n0 = (blk & 511) << 3;

    for (int i = 0; i < 16; ++i) {
        int j = i * 256 + t;
        int oo = j >> 6, ic = j & 63;
        wt[ic][oo] = wk2[j];
    }
    if (t < 64) {
        float g = g1[t], be = bb1[t], m = mm1[t], v = vv1[t];
        float s = g * rsqrtf(v + EPS_);
        s1c[t] = s; t1c[t] = be - m * s;
        g = g2[t]; be = bb2[t]; m = mm2[t]; v = vv2[t];
        s = g * rsqrtf(v + EPS_);
        s2c[t] = s; t2c[t] = be - m * s;
    }
    size_t pbase = (size_t)(b * N_ + n0);
    for (int i = t; i < 512; i += 256) {
        int pt = i >> 6, o = i & 63;
        ddl[pt][o] = dd[(pbase + pt) * 64 + o];
    }
    if (t < 8 * K_) {
        int pt = t / K_, k = t % K_;
        il[pt][k] = idxg[(pbase + pt) * K_ + k];
    }
    __syncthreads();

    const float* yAb = yA + (size_t)(b * N_) * 64;
    for (int i = 0; i < 10; ++i) {
        int j = i * 256 + t;
        int pt = j / 320;
        int r = j - pt * 320;
        int k = r >> 4;
        int f = r & 15;
        int m = il[pt][k];
        float4 y4 = *(const float4*)(yAb + (size_t)m * 64 + (f << 2));
        float vals[4] = {y4.x, y4.y, y4.z, y4.w};
        int o = f << 2;
        for (int cdx = 0; cdx < 4; ++cdx) {
            int oc = o + cdx;
            float v = vals[cdx] + ddl[pt][oc];
            v = lrelu(s1c[oc] * v + t1c[oc]);
            tmf[pt * 1412 + oc * 22 + k] = v;
        }
    }
    __syncthreads();

    int pt = t >> 5, u = t & 31;
    int o2_0 = (u & 7) << 3;
    int k0 = (u >> 3) * 5;
    float acc[8][5];
    for (int i = 0; i < 8; ++i)
        for (int q = 0; q < 5; ++q) acc[i][q] = 0.f;
    const float* tmp_ = &tmf[pt * 1412];
    for (int o = 0; o < 64; ++o) {
        float4 w0 = *(const float4*)&wt[o][o2_0];
        float4 w1v = *(const float4*)&wt[o][o2_0 + 4];
        float wv[8] = {w0.x, w0.y, w0.z, w0.w, w1v.x, w1v.y, w1v.z, w1v.w};
        float tvv[5];
        for (int q = 0; q < 5; ++q) tvv[q] = tmp_[o * 22 + k0 + q];
        for (int i = 0; i < 8; ++i)
            for (int q = 0; q < 5; ++q)
                acc[i][q] += wv[i] * tvv[q];
    }
    for (int i = 0; i < 8; ++i) {
        float pm = acc[i][0];
        for (int q = 1; q < 5; ++q) pm = fmaxf(pm, acc[i][q]);
        pm = fmaxf(pm, __shfl_xor(pm, 8));
        pm = fmaxf(pm, __shfl_xor(pm, 16));
        if ((u >> 3) == 0) {
            int o2 = o2_0 + i;
            hl[pt][o2] = lrelu(s2c[o2] * pm + t2c[o2]);
        }
    }
    __syncthreads();

    float* htb = ht + (size_t)b * 64 * N_;
    for (int i = t; i < 512; i += 256) {
        int o = i >> 3, pt2 = i & 7;
        htb[o * N_ + n0 + pt2] = hl[pt2][o];
    }
}

// ---------------------------------------------------------------------------
// Kernel C2: MLP head 64 -> 256 -> 128 -> 1 per point, 64 points per block
// ---------------------------------------------------------------------------
__global__ void __launch_bounds__(256) k_head(const float* __restrict__ ht,
                                              const float* __restrict__ w1,
                                              const float* __restrict__ g1,
                                              const float* __restrict__ bb1,
                                              const float* __restrict__ mm1,
                                              const float* __restrict__ vv1,
                                              const float* __restrict__ w2,
                                              const float* __restrict__ g2,
                                              const float* __restrict__ bb2,
                                              const float* __restrict__ mm2,
                                              const float* __restrict__ vv2,
                                              const float* __restrict__ w3,
                                              const float* __restrict__ b3,
                                              float* __restrict__ out) {
    __shared__ float hbuf[64][64];
    __shared__ float a1[256][64];
    __shared__ float a2[128][64];
    __shared__ float sA[256], tA[256], sB[128], tB[128];
    int t = threadIdx.x;
    int blk = blockIdx.x;
    int b = blk >> 6;
    int n0 = (blk & 63) << 6;
    const float* htb = ht + (size_t)b * 64 * N_;

    for (int i = 0; i < 16; ++i) {
        int j = i * 256 + t;
        int o = j >> 6, pt = j & 63;
        hbuf[o][pt] = htb[o * N_ + n0 + pt];
    }
    {
        float g = g1[t], be = bb1[t], m = mm1[t], v = vv1[t];
        float s = g * rsqrtf(v + EPS_);
        sA[t] = s; tA[t] = be - m * s;
    }
    if (t < 128) {
        float g = g2[t], be = bb2[t], m = mm2[t], v = vv2[t];
        float s = g * rsqrtf(v + EPS_);
        sB[t] = s; tB[t] = be - m * s;
    }
    __syncthreads();

    int ptg = t & 15, rg = t >> 4;
    int pt4 = ptg << 2;

    for (int ib = 0; ib < 4; ++ib) {
        int r0 = (rg << 4) + (ib << 2);
        float acc[4][4] = {};
        for (int o4 = 0; o4 < 16; ++o4) {
            float hf[4][4];
            for (int c = 0; c < 4; ++c) {
                float4 q = *(const float4*)&hbuf[(o4 << 2) + c][pt4];
                hf[c][0] = q.x; hf[c][1] = q.y; hf[c][2] = q.z; hf[c][3] = q.w;
            }
            for (int j = 0; j < 4; ++j) {
                float4 wv4 = *(const float4*)(w1 + (r0 + j) * 64 + (o4 << 2));
                float wv[4] = {wv4.x, wv4.y, wv4.z, wv4.w};
                for (int c = 0; c < 4; ++c)
                    for (int pp = 0; pp < 4; ++pp)
                        acc[j][pp] += wv[c] * hf[c][pp];
            }
        }
        for (int j = 0; j < 4; ++j) {
            int r = r0 + j;
            float4 ov;
            ov.x = lrelu(sA[r] * acc[j][0] + tA[r]);
            ov.y = lrelu(sA[r] * acc[j][1] + tA[r]);
            ov.z = lrelu(sA[r] * acc[j][2] + tA[r]);
            ov.w = lrelu(sA[r] * acc[j][3] + tA[r]);
            *(float4*)&a1[r][pt4] = ov;
        }
    }
    __syncthreads();

    for (int ib = 0; ib < 2; ++ib) {
        int r0 = (rg << 3) + (ib << 2);
        float acc[4][4] = {};
        for (int p4i = 0; p4i < 64; ++p4i) {
            float af[4][4];
            for (int c = 0; c < 4; ++c) {
                float4 q = *(const float4*)&a1[(p4i << 2) + c][pt4];
                af[c][0] = q.x; af[c][1] = q.y; af[c][2] = q.z; af[c][3] = q.w;
            }
            for (int j = 0; j < 4; ++j) {
                float4 wv4 = *(const float4*)(w2 + (r0 + j) * 256 + (p4i << 2));
                float wv[4] = {wv4.x, wv4.y, wv4.z, wv4.w};
                for (int c = 0; c < 4; ++c)
                    for (int pp = 0; pp < 4; ++pp)
                        acc[j][pp] += wv[c] * af[c][pp];
            }
        }
        for (int j = 0; j < 4; ++j) {
            int r = r0 + j;
            float4 ov;
            ov.x = lrelu(sB[r] * acc[j][0] + tB[r]);
            ov.y = lrelu(sB[r] * acc[j][1] + tB[r]);
            ov.z = lrelu(sB[r] * acc[j][2] + tB[r]);
            ov.w = lrelu(sB[r] * acc[j][3] + tB[r]);
            *(float4*)&a2[r][pt4] = ov;
        }
    }
    __syncthreads();

    if (t < 64) {
        float accv = 0.f;
        for (int q = 0; q < 128; ++q) accv += w3[q] * a2[q][t];
        accv += b3[0];
        out[b * N_ + n0 + t] = accv;
    }
}

// ---------------------------------------------------------------------------
extern "C" void kernel_launch(void* const* d_in, const int* in_sizes, int n_in,
                              void* d_out, int out_size, void* d_ws, size_t ws_size,
                              hipStream_t stream) {
    (void)in_sizes; (void)n_in; (void)out_size; (void)ws_size;
    const float* x    = (const float*)d_in[0];
    const float* wk1  = (const float*)d_in[1];
    const float* gk1  = (const float*)d_in[2];
    const float* bk1  = (const float*)d_in[3];
    const float* mk1  = (const float*)d_in[4];
    const float* vk1  = (const float*)d_in[5];
    const float* wk2  = (const float*)d_in[6];
    const float* gk2  = (const float*)d_in[7];
    const float* bk2  = (const float*)d_in[8];
    const float* mk2  = (const float*)d_in[9];
    const float* vk2  = (const float*)d_in[10];
    const float* w1   = (const float*)d_in[11];
    const float* g1   = (const float*)d_in[12];
    const float* b1   = (const float*)d_in[13];
    const float* m1   = (const float*)d_in[14];
    const float* v1   = (const float*)d_in[15];
    const float* w2   = (const float*)d_in[16];
    const float* g2   = (const float*)d_in[17];
    const float* b2   = (const float*)d_in[18];
    const float* m2   = (const float*)d_in[19];
    const float* v2   = (const float*)d_in[20];
    const float* w3   = (const float*)d_in[21];
    const float* b3   = (const float*)d_in[22];

    char* ws = (char*)d_ws;
    float* yA  = (float*)(ws);                       //  8 MB
    float* dd  = (float*)(ws + 8388608);             //  8 MB
    float* xx  = (float*)(ws + 16777216);            //  128 KB
    int*   idx = (int*)  (ws + 16908288);            //  2.5 MB
    float* ht  = (float*)(ws + 19529728);            //  8 MB
    unsigned short* xps = (unsigned short*)(ws + 27918336);  // 8 MB split-bf16 images

    k_pre <<<B_ * (N_ / 64), 256, 0, stream>>>(x, wk1, yA, dd, xx, xps);
    k_topk<<<B_ * (N_ / 64), 512, 0, stream>>>(xps, xx, idx);
    k_edge<<<B_ * (N_ / 8),  256, 0, stream>>>(yA, dd, idx, wk2,
                                               gk1, bk1, mk1, vk1,
                                               gk2, bk2, mk2, vk2, ht);
    k_head<<<B_ * (N_ / 64), 256, 0, stream>>>(ht, w1, g1, b1, m1, v1,
                                               w2, g2, b2, m2, v2, w3, b3,
                                               (float*)d_out);
}

// Round 6
// 542.787 us; speedup vs baseline: 3.1746x; 1.2246x over previous
//
#include <hip/hip_runtime.h>
#include <hip/hip_bf16.h>

#define B_ 8
#define C_ 64
#define N_ 4096
#define K_ 20
#define EPS_ 1e-5f
#define SLOPE_ 0.2f

typedef __attribute__((ext_vector_type(8))) short bf16x8;
typedef __attribute__((ext_vector_type(4))) float f32x4;

__device__ __forceinline__ float lrelu(float x) { return x >= 0.f ? x : SLOPE_ * x; }
__device__ __forceinline__ float bf2f(unsigned short u) {
    return __uint_as_float(((unsigned int)u) << 16);
}
__device__ __forceinline__ unsigned short f2bf(float f) {
    unsigned int u = __float_as_uint(f);
    return (unsigned short)((u + 0x7FFFu + ((u >> 16) & 1u)) >> 16);
}

// ---------------------------------------------------------------------------
// Kernel A: yA = wA@x, dd = (wB-wA)@x, xx = |x|^2, and pre-split bf16 hi/lo
// chunk images xps[b][chunk] (swizzled, byte-identical to k_topk LDS layout).
// grid 512 (B * N/64), block 256
// ---------------------------------------------------------------------------
__global__ void __launch_bounds__(256) k_pre(const float* __restrict__ x,
                                             const float* __restrict__ wk1,
                                             float* __restrict__ yA,
                                             float* __restrict__ dd,
                                             float* __restrict__ xx,
                                             unsigned short* __restrict__ xps) {
    __shared__ float w[64][128];
    __shared__ float xs[64][64];
    int t = threadIdx.x;
    int blk = blockIdx.x;
    int b = blk >> 6;
    int n0 = (blk & 63) << 6;

    for (int i = 0; i < 8; ++i) {
        int j = i * 256 + t;
        float4 v = ((const float4*)wk1)[j];
        int o = j >> 5;
        int c4 = (j & 31) << 2;
        w[o][c4 + 0] = v.x; w[o][c4 + 1] = v.y;
        w[o][c4 + 2] = v.z; w[o][c4 + 3] = v.w;
    }
    const float* xb = x + (size_t)b * C_ * N_;
    for (int i = 0; i < 4; ++i) {
        int j = i * 256 + t;
        int c = j >> 4;
        int p4 = (j & 15) << 2;
        float4 v = *(const float4*)(xb + c * N_ + n0 + p4);
        xs[c][p4 + 0] = v.x; xs[c][p4 + 1] = v.y;
        xs[c][p4 + 2] = v.z; xs[c][p4 + 3] = v.w;
    }
    __syncthreads();

    if (t < 64) {
        float s = 0.f;
        for (int c = 0; c < 64; ++c) { float xv = xs[c][t]; s += xv * xv; }
        xx[b * N_ + n0 + t] = s;
    }

    // emit pre-split swizzled chunk image: hi[4096] | lo[4096] ushorts
    {
        unsigned short* xc = xps + ((size_t)(b * 64 + (blk & 63))) * 8192;
#pragma unroll
        for (int q = 0; q < 2; ++q) {
            int i = q * 256 + t;          // 0..511 units
            int nl = i >> 3, oct = i & 7;
            bf16x8 hv, lv8;
#pragma unroll
            for (int j = 0; j < 8; ++j) {
                float v = xs[oct * 8 + j][nl];
                unsigned short hh = f2bf(v);
                hv[j] = (short)hh;
                lv8[j] = (short)f2bf(v - bf2f(hh));
            }
            int unit = oct ^ (nl & 7);
            *(bf16x8*)&xc[nl * 64 + unit * 8] = hv;
            *(bf16x8*)&xc[4096 + nl * 64 + unit * 8] = lv8;
        }
    }

    int p = t & 63, og = t >> 6;
    for (int oi = 0; oi < 16; ++oi) {
        int o = og * 16 + oi;
        float sA = 0.f, sB = 0.f;
        for (int c = 0; c < 64; ++c) {
            float xv = xs[c][p];
            sA += w[o][c] * xv;
            sB += w[o][64 + c] * xv;
        }
        size_t base = ((size_t)(b * N_ + n0 + p)) * 64 + o;
        yA[base] = sA;
        dd[base] = sB - sA;
    }
}

// ---------------------------------------------------------------------------
// Kernel B: top-20 neighbors by score = 2*dot(x_n,x_m) - |x_m|^2
// grid 1024 (B * N/32), block 512 = 8 waves.
// Gram: wave (wr,wc) = (row 16-group, cand 16-quarter). Selection: wave w
// owns rows 4w..4w+3, full-width-64 register top-20 (proven machinery).
// ---------------------------------------------------------------------------
__global__ void __launch_bounds__(512) k_topk(const unsigned short* __restrict__ xps,
                                              const float* __restrict__ xx,
                                              int* __restrict__ idxg) {
    __shared__ unsigned short xs_[2][8192];   // [buf][hi 4096 | lo 4096]
    __shared__ float sc[32][68];              // [row][cand]
    int t = threadIdx.x;
    int lane = t & 63;
    int w = t >> 6;               // 0..7
    int wr = w >> 2;              // row group (16 rows)
    int wc = w & 3;               // cand quarter (16 cands)
    int blk = blockIdx.x;         // 0..1023
    int b = blk >> 7;
    int n0 = (blk & 127) << 5;    // 32-row block base
    int bc = b << 6;              // chunk base for this batch
    const float* xxb = xx + b * N_;

    // ---- A fragments from pre-split image of this block's home chunk
    const unsigned short* xcA = xps + ((size_t)(bc + ((blk & 127) >> 1))) * 8192;
    int anl = ((blk & 1) << 5) + (wr << 4) + (lane & 15);
    bf16x8 ah[2], al[2];
#pragma unroll
    for (int kc = 0; kc < 2; ++kc) {
        int unit = (kc * 4 + (lane >> 4)) ^ (anl & 7);
        ah[kc] = *(const bf16x8*)&xcA[anl * 64 + unit * 8];
        al[kc] = *(const bf16x8*)&xcA[4096 + anl * 64 + unit * 8];
    }

    // ---- staging: linear 16 KB copy (pre-swizzled in global)
    auto stage = [&](int p, int mc) {
        const ulonglong2* src = (const ulonglong2*)(xps + ((size_t)(bc + mc)) * 8192);
        ulonglong2* dst = (ulonglong2*)&xs_[p][0];
        dst[t] = src[t];
        dst[t + 512] = src[t + 512];
    };

    float lv[4];
    int   li[4];
#pragma unroll
    for (int i = 0; i < 4; ++i) { lv[i] = -3.0e38f; li[i] = 0; }

    // full-width-64 sorted insert (proven round-3/4 machinery)
    auto ins = [&](float& lvr, int& lir, float s, int m0) {
        float mnc = __shfl(lvr, 19);
        unsigned long long mask = __ballot(s > mnc);
        while (mask) {
            int j = (int)__builtin_ctzll(mask);
            mask &= mask - 1;
            float sv = __shfl(s, j);
            if (sv > mnc) {
                unsigned long long gt = __ballot(lane < 20 && lvr > sv);
                int cpos = __popcll(gt);
                float upv = __shfl_up(lvr, 1);
                int   upi = __shfl_up(lir, 1);
                if (lane >= cpos && lane < 20) {
                    lvr = (lane == cpos) ? sv : upv;
                    lir = (lane == cpos) ? (m0 + j) : upi;
                }
                mnc = __shfl(lvr, 19);
            }
        }
    };

    stage(0, 0);
    __syncthreads();
    int p = 0;

    for (int mc = 0; mc < 64; ++mc) {
        int m0 = mc << 6;

        // ---- MFMA Gram: rows wr*16..+15 x cands wc*16..+15
        {
            f32x4 acc = {0.f, 0.f, 0.f, 0.f};
            int n_ = (wc << 4) + (lane & 15);
            float xxv = xxb[m0 + n_];
#pragma unroll
            for (int kc = 0; kc < 2; ++kc) {
                int unit = (kc * 4 + (lane >> 4)) ^ (n_ & 7);
                bf16x8 bh = *(const bf16x8*)&xs_[p][n_ * 64 + unit * 8];
                bf16x8 bl = *(const bf16x8*)&xs_[p][4096 + n_ * 64 + unit * 8];
                acc = __builtin_amdgcn_mfma_f32_16x16x32_bf16(ah[kc], bh, acc, 0, 0, 0);
                acc = __builtin_amdgcn_mfma_f32_16x16x32_bf16(ah[kc], bl, acc, 0, 0, 0);
                acc = __builtin_amdgcn_mfma_f32_16x16x32_bf16(al[kc], bh, acc, 0, 0, 0);
                acc = __builtin_amdgcn_mfma_f32_16x16x32_bf16(al[kc], bl, acc, 0, 0, 0);
            }
#pragma unroll
            for (int r = 0; r < 4; ++r)
                sc[(wr << 4) + ((lane >> 4) << 2) + r][(wc << 4) + (lane & 15)] =
                    2.f * acc[r] - xxv;
        }

        // ---- stage next chunk (global latency overlaps barrier+selection)
        if (mc + 1 < 64) stage(p ^ 1, mc + 1);

        __syncthreads();   // sc complete across waves

        // ---- selection: wave w owns rows 4w..4w+3 over all 64 cands
#pragma unroll
        for (int i = 0; i < 4; ++i) {
            int lrow = (w << 2) + i;
            float s = sc[lrow][lane];
            ins(lv[i], li[i], s, m0);
        }
        __syncthreads();   // selection done; xs_[p^1] landed
        p ^= 1;
    }

#pragma unroll
    for (int i = 0; i < 4; ++i) {
        int n = n0 + (w << 2) + i;
        if (lane < K_)
            idxg[((size_t)(b * N_ + n)) * K_ + lane] = li[i];
    }
}

// ---------------------------------------------------------------------------
// Kernel C1: gather + BN1/lrelu -> conv_k2 -> max_k -> BN2/lrelu -> ht[b][o][n]
// ---------------------------------------------------------------------------
__global__ void __launch_bounds__(256) k_edge(const float* __restrict__ yA,
                                              const float* __restrict__ dd,
                                              const int* __restrict__ idxg,
                                              const float* __restrict__ wk2,
                                              const float* __restrict__ g1,
                                              const float* __restrict__ bb1,
                                              const float* __restrict__ mm1,
                                              const float* __restrict__ vv1,
                                              const float* __restrict__ g2,
                                              const float* __restrict__ bb2,
                                              const float* __restrict__ mm2,
                                              const float* __restrict__ vv2,
                                              float* __restrict__ ht) {
    __shared__ float wt[64][68];
    __shared__ float tmf[8 * 1412];
    __shared__ float ddl[8][64];
    __shared__ float s1c[64], t1c[64], s2c[64], t2c[64];
    __shared__ int   il[8][K_];
    __shared__ float hl[8][64];
    int t = threadIdx.x;
    int blk = blockIdx.x;
    int b = blk >> 9;
    int n0 = (blk & 511) << 3;

    for (int i = 0; i < 16; ++i) {
        int j = i * 256 + t;
        int oo = j >> 6, ic = j & 63;
        wt[ic][oo] = wk2[j];
    }
    if (t < 64) {
        float g = g1[t], be = bb1[t], m = mm1[t], v = vv1[t];
        float s = g * rsqrtf(v + EPS_);
        s1c[t] = s; t1c[t] = be - m * s;
        g = g2[t]; be = bb2[t]; m = mm2[t]; v = vv2[t];
        s = g * rsqrtf(v + EPS_);
        s2c[t] = s; t2c[t] = be - m * s;
    }
    size_t pbase = (size_t)(b * N_ + n0);
    for (int i = t; i < 512; i += 256) {
        int pt = i >> 6, o = i & 63;
        ddl[pt][o] = dd[(pbase + pt) * 64 + o];
    }
    if (t < 8 * K_) {
        int pt = t / K_, k = t % K_;
        il[pt][k] = idxg[(pbase + pt) * K_ + k];
    }
    __syncthreads();

    const float* yAb = yA + (size_t)(b * N_) * 64;
    for (int i = 0; i < 10; ++i) {
        int j = i * 256 + t;
        int pt = j / 320;
        int r = j - pt * 320;
        int k = r >> 4;
        int f = r & 15;
        int m = il[pt][k];
        float4 y4 = *(const float4*)(yAb + (size_t)m * 64 + (f << 2));
        float vals[4] = {y4.x, y4.y, y4.z, y4.w};
        int o = f << 2;
        for (int cdx = 0; cdx < 4; ++cdx) {
            int oc = o + cdx;
            float v = vals[cdx] + ddl[pt][oc];
            v = lrelu(s1c[oc] * v + t1c[oc]);
            tmf[pt * 1412 + oc * 22 + k] = v;
        }
    }
    __syncthreads();

    int pt = t >> 5, u = t & 31;
    int o2_0 = (u & 7) << 3;
    int k0 = (u >> 3) * 5;
    float acc[8][5];
    for (int i = 0; i < 8; ++i)
        for (int q = 0; q < 5; ++q) acc[i][q] = 0.f;
    const float* tmp_ = &tmf[pt * 1412];
    for (int o = 0; o < 64; ++o) {
        float4 w0 = *(const float4*)&wt[o][o2_0];
        float4 w1v = *(const float4*)&wt[o][o2_0 + 4];
        float wv[8] = {w0.x, w0.y, w0.z, w0.w, w1v.x, w1v.y, w1v.z, w1v.w};
        float tvv[5];
        for (int q = 0; q < 5; ++q) tvv[q] = tmp_[o * 22 + k0 + q];
        for (int i = 0; i < 8; ++i)
            for (int q = 0; q < 5; ++q)
                acc[i][q] += wv[i] * tvv[q];
    }
    for (int i = 0; i < 8; ++i) {
        float pm = acc[i][0];
        for (int q = 1; q < 5; ++q) pm = fmaxf(pm, acc[i][q]);
        pm = fmaxf(pm, __shfl_xor(pm, 8));
        pm = fmaxf(pm, __shfl_xor(pm, 16));
        if ((u >> 3) == 0) {
            int o2 = o2_0 + i;
            hl[pt][o2] = lrelu(s2c[o2] * pm + t2c[o2]);
        }
    }
    __syncthreads();

    float* htb = ht + (size_t)b * 64 * N_;
    for (int i = t; i < 512; i += 256) {
        int o = i >> 3, pt2 = i & 7;
        htb[o * N_ + n0 + pt2] = hl[pt2][o];
    }
}

// ---------------------------------------------------------------------------
// Kernel C2: MLP head 64 -> 256 -> 128 -> 1 per point, 64 points per block
// ---------------------------------------------------------------------------
__global__ void __launch_bounds__(256) k_head(const float* __restrict__ ht,
                                              const float* __restrict__ w1,
                                              const float* __restrict__ g1,
                                              const float* __restrict__ bb1,
                                              const float* __restrict__ mm1,
                                              const float* __restrict__ vv1,
                                              const float* __restrict__ w2,
                                              const float* __restrict__ g2,
                                              const float* __restrict__ bb2,
                                              const float* __restrict__ mm2,
                                              const float* __restrict__ vv2,
                                              const float* __restrict__ w3,
                                              const float* __restrict__ b3,
                                              float* __restrict__ out) {
    __shared__ float hbuf[64][64];
    __shared__ float a1[256][64];
    __shared__ float a2[128][64];
    __shared__ float sA[256], tA[256], sB[128], tB[128];
    int t = threadIdx.x;
    int blk = blockIdx.x;
    int b = blk >> 6;
    int n0 = (blk & 63) << 6;
    const float* htb = ht + (size_t)b * 64 * N_;

    for (int i = 0; i < 16; ++i) {
        int j = i * 256 + t;
        int o = j >> 6, pt = j & 63;
        hbuf[o][pt] = htb[o * N_ + n0 + pt];
    }
    {
        float g = g1[t], be = bb1[t], m = mm1[t], v = vv1[t];
        float s = g * rsqrtf(v + EPS_);
        sA[t] = s; tA[t] = be - m * s;
    }
    if (t < 128) {
        float g = g2[t], be = bb2[t], m = mm2[t], v = vv2[t];
        float s = g * rsqrtf(v + EPS_);
        sB[t] = s; tB[t] = be - m * s;
    }
    __syncthreads();

    int ptg = t & 15, rg = t >> 4;
    int pt4 = ptg << 2;

    for (int ib = 0; ib < 4; ++ib) {
        int r0 = (rg << 4) + (ib << 2);
        float acc[4][4] = {};
        for (int o4 = 0; o4 < 16; ++o4) {
            float hf[4][4];
            for (int c = 0; c < 4; ++c) {
                float4 q = *(const float4*)&hbuf[(o4 << 2) + c][pt4];
                hf[c][0] = q.x; hf[c][1] = q.y; hf[c][2] = q.z; hf[c][3] = q.w;
            }
            for (int j = 0; j < 4; ++j) {
                float4 wv4 = *(const float4*)(w1 + (r0 + j) * 64 + (o4 << 2));
                float wv[4] = {wv4.x, wv4.y, wv4.z, wv4.w};
                for (int c = 0; c < 4; ++c)
                    for (int pp = 0; pp < 4; ++pp)
                        acc[j][pp] += wv[c] * hf[c][pp];
            }
        }
        for (int j = 0; j < 4; ++j) {
            int r = r0 + j;
            float4 ov;
            ov.x = lrelu(sA[r] * acc[j][0] + tA[r]);
            ov.y = lrelu(sA[r] * acc[j][1] + tA[r]);
            ov.z = lrelu(sA[r] * acc[j][2] + tA[r]);
            ov.w = lrelu(sA[r] * acc[j][3] + tA[r]);
            *(float4*)&a1[r][pt4] = ov;
        }
    }
    __syncthreads();

    for (int ib = 0; ib < 2; ++ib) {
        int r0 = (rg << 3) + (ib << 2);
        float acc[4][4] = {};
        for (int p4i = 0; p4i < 64; ++p4i) {
            float af[4][4];
            for (int c = 0; c < 4; ++c) {
                float4 q = *(const float4*)&a1[(p4i << 2) + c][pt4];
                af[c][0] = q.x; af[c][1] = q.y; af[c][2] = q.z; af[c][3] = q.w;
            }
            for (int j = 0; j < 4; ++j) {
                float4 wv4 = *(const float4*)(w2 + (r0 + j) * 256 + (p4i << 2));
                float wv[4] = {wv4.x, wv4.y, wv4.z, wv4.w};
                for (int c = 0; c < 4; ++c)
                    for (int pp = 0; pp < 4; ++pp)
                        acc[j][pp] += wv[c] * af[c][pp];
            }
        }
        for (int j = 0; j < 4; ++j) {
            int r = r0 + j;
            float4 ov;
            ov.x = lrelu(sB[r] * acc[j][0] + tB[r]);
            ov.y = lrelu(sB[r] * acc[j][1] + tB[r]);
            ov.z = lrelu(sB[r] * acc[j][2] + tB[r]);
            ov.w = lrelu(sB[r] * acc[j][3] + tB[r]);
            *(float4*)&a2[r][pt4] = ov;
        }
    }
    __syncthreads();

    if (t < 64) {
        float accv = 0.f;
        for (int q = 0; q < 128; ++q) accv += w3[q] * a2[q][t];
        accv += b3[0];
        out[b * N_ + n0 + t] = accv;
    }
}

// ---------------------------------------------------------------------------
extern "C" void kernel_launch(void* const* d_in, const int* in_sizes, int n_in,
                              void* d_out, int out_size, void* d_ws, size_t ws_size,
                              hipStream_t stream) {
    (void)in_sizes; (void)n_in; (void)out_size; (void)ws_size;
    const float* x    = (const float*)d_in[0];
    const float* wk1  = (const float*)d_in[1];
    const float* gk1  = (const float*)d_in[2];
    const float* bk1  = (const float*)d_in[3];
    const float* mk1  = (const float*)d_in[4];
    const float* vk1  = (const float*)d_in[5];
    const float* wk2  = (const float*)d_in[6];
    const float* gk2  = (const float*)d_in[7];
    const float* bk2  = (const float*)d_in[8];
    const float* mk2  = (const float*)d_in[9];
    const float* vk2  = (const float*)d_in[10];
    const float* w1   = (const float*)d_in[11];
    const float* g1   = (const float*)d_in[12];
    const float* b1   = (const float*)d_in[13];
    const float* m1   = (const float*)d_in[14];
    const float* v1   = (const float*)d_in[15];
    const float* w2   = (const float*)d_in[16];
    const float* g2   = (const float*)d_in[17];
    const float* b2   = (const float*)d_in[18];
    const float* m2   = (const float*)d_in[19];
    const float* v2   = (const float*)d_in[20];
    const float* w3   = (const float*)d_in[21];
    const float* b3   = (const float*)d_in[22];

    char* ws = (char*)d_ws;
    float* yA  = (float*)(ws);                       //  8 MB
    float* dd  = (float*)(ws + 8388608);             //  8 MB
    float* xx  = (float*)(ws + 16777216);            //  128 KB
    int*   idx = (int*)  (ws + 16908288);            //  2.5 MB
    float* ht  = (float*)(ws + 19529728);            //  8 MB
    unsigned short* xps = (unsigned short*)(ws + 27918336);  // 8 MB split-bf16 images

    k_pre <<<B_ * (N_ / 64), 256, 0, stream>>>(x, wk1, yA, dd, xx, xps);
    k_topk<<<B_ * (N_ / 32), 512, 0, stream>>>(xps, xx, idx);
    k_edge<<<B_ * (N_ / 8),  256, 0, stream>>>(yA, dd, idx, wk2,
                                               gk1, bk1, mk1, vk1,
                                               gk2, bk2, mk2, vk2, ht);
    k_head<<<B_ * (N_ / 64), 256, 0, stream>>>(ht, w1, g1, b1, m1, v1,
                                               w2, g2, b2, m2, v2, w3, b3,
                                               (float*)d_out);
}

// Round 7
// 492.055 us; speedup vs baseline: 3.5019x; 1.1031x over previous
//
#include <hip/hip_runtime.h>
#include <hip/hip_bf16.h>

#define B_ 8
#define C_ 64
#define N_ 4096
#define K_ 20
#define EPS_ 1e-5f
#define SLOPE_ 0.2f

typedef __attribute__((ext_vector_type(8))) short bf16x8;
typedef __attribute__((ext_vector_type(4))) float f32x4;

__device__ __forceinline__ float lrelu(float x) { return x >= 0.f ? x : SLOPE_ * x; }
__device__ __forceinline__ float bf2f(unsigned short u) {
    return __uint_as_float(((unsigned int)u) << 16);
}
__device__ __forceinline__ unsigned short f2bf(float f) {
    unsigned int u = __float_as_uint(f);
    return (unsigned short)((u + 0x7FFFu + ((u >> 16) & 1u)) >> 16);
}

// ---------------------------------------------------------------------------
// Kernel A: yA = wA@x, dd = (wB-wA)@x, xx = |x|^2, and pre-split bf16 hi/lo
// chunk images xps[b][chunk] (swizzled, byte-identical to k_topk LDS layout).
// grid 512 (B * N/64), block 256
// ---------------------------------------------------------------------------
__global__ void __launch_bounds__(256) k_pre(const float* __restrict__ x,
                                             const float* __restrict__ wk1,
                                             float* __restrict__ yA,
                                             float* __restrict__ dd,
                                             float* __restrict__ xx,
                                             unsigned short* __restrict__ xps) {
    __shared__ float w[64][128];
    __shared__ float xs[64][64];
    int t = threadIdx.x;
    int blk = blockIdx.x;
    int b = blk >> 6;
    int n0 = (blk & 63) << 6;

    for (int i = 0; i < 8; ++i) {
        int j = i * 256 + t;
        float4 v = ((const float4*)wk1)[j];
        int o = j >> 5;
        int c4 = (j & 31) << 2;
        w[o][c4 + 0] = v.x; w[o][c4 + 1] = v.y;
        w[o][c4 + 2] = v.z; w[o][c4 + 3] = v.w;
    }
    const float* xb = x + (size_t)b * C_ * N_;
    for (int i = 0; i < 4; ++i) {
        int j = i * 256 + t;
        int c = j >> 4;
        int p4 = (j & 15) << 2;
        float4 v = *(const float4*)(xb + c * N_ + n0 + p4);
        xs[c][p4 + 0] = v.x; xs[c][p4 + 1] = v.y;
        xs[c][p4 + 2] = v.z; xs[c][p4 + 3] = v.w;
    }
    __syncthreads();

    if (t < 64) {
        float s = 0.f;
        for (int c = 0; c < 64; ++c) { float xv = xs[c][t]; s += xv * xv; }
        xx[b * N_ + n0 + t] = s;
    }

    // emit pre-split swizzled chunk image: hi[4096] | lo[4096] ushorts
    {
        unsigned short* xc = xps + ((size_t)(b * 64 + (blk & 63))) * 8192;
#pragma unroll
        for (int q = 0; q < 2; ++q) {
            int i = q * 256 + t;          // 0..511 units
            int nl = i >> 3, oct = i & 7;
            bf16x8 hv, lv8;
#pragma unroll
            for (int j = 0; j < 8; ++j) {
                float v = xs[oct * 8 + j][nl];
                unsigned short hh = f2bf(v);
                hv[j] = (short)hh;
                lv8[j] = (short)f2bf(v - bf2f(hh));
            }
            int unit = oct ^ (nl & 7);
            *(bf16x8*)&xc[nl * 64 + unit * 8] = hv;
            *(bf16x8*)&xc[4096 + nl * 64 + unit * 8] = lv8;
        }
    }

    int p = t & 63, og = t >> 6;
    for (int oi = 0; oi < 16; ++oi) {
        int o = og * 16 + oi;
        float sA = 0.f, sB = 0.f;
        for (int c = 0; c < 64; ++c) {
            float xv = xs[c][p];
            sA += w[o][c] * xv;
            sB += w[o][64 + c] * xv;
        }
        size_t base = ((size_t)(b * N_ + n0 + p)) * 64 + o;
        yA[base] = sA;
        dd[base] = sB - sA;
    }
}

// ---------------------------------------------------------------------------
// Kernel B: top-20 neighbors by score = 2*dot(x_n,x_m) - |x_m|^2
// grid 1024 (B * N/32), block 512 = 8 waves. Single-buffered xs_ (16 KB) +
// register prefetch (async-stage split): LDS 24.5 KB -> full 4-blocks/CU
// co-residency. Gram: wave (wr,wc); selection: wave w owns rows 4w..4w+3.
// ---------------------------------------------------------------------------
__global__ void __launch_bounds__(512) k_topk(const unsigned short* __restrict__ xps,
                                              const float* __restrict__ xx,
                                              int* __restrict__ idxg) {
    __shared__ unsigned short xs_[8192];      // hi 4096 | lo 4096 (16 KB)
    __shared__ float sc[32][68];              // [row][cand]
    int t = threadIdx.x;
    int lane = t & 63;
    int w = t >> 6;               // 0..7
    int wr = w >> 2;              // row group (16 rows)
    int wc = w & 3;               // cand quarter (16 cands)
    int blk = blockIdx.x;         // 0..1023
    int b = blk >> 7;
    int n0 = (blk & 127) << 5;    // 32-row block base
    int bc = b << 6;              // chunk base for this batch
    const float* xxb = xx + b * N_;

    // ---- A fragments from pre-split image of this block's home chunk
    const unsigned short* xcA = xps + ((size_t)(bc + ((blk & 127) >> 1))) * 8192;
    int anl = ((blk & 1) << 5) + (wr << 4) + (lane & 15);
    bf16x8 ah[2], al[2];
#pragma unroll
    for (int kc = 0; kc < 2; ++kc) {
        int unit = (kc * 4 + (lane >> 4)) ^ (anl & 7);
        ah[kc] = *(const bf16x8*)&xcA[anl * 64 + unit * 8];
        al[kc] = *(const bf16x8*)&xcA[4096 + anl * 64 + unit * 8];
    }

    // ---- async-stage split: issue loads early, ds_write late
    ulonglong2 pf0, pf1;
    auto prefetch = [&](int mc) {
        const ulonglong2* src = (const ulonglong2*)(xps + ((size_t)(bc + mc)) * 8192);
        pf0 = src[t];
        pf1 = src[t + 512];
    };
    auto commit = [&]() {
        ulonglong2* dst = (ulonglong2*)&xs_[0];
        dst[t] = pf0;
        dst[t + 512] = pf1;
    };

    float lv[4];
    int   li[4];
#pragma unroll
    for (int i = 0; i < 4; ++i) { lv[i] = -3.0e38f; li[i] = 0; }

    // full-width-64 sorted insert (proven machinery)
    auto ins = [&](float& lvr, int& lir, float s, int m0) {
        float mnc = __shfl(lvr, 19);
        unsigned long long mask = __ballot(s > mnc);
        while (mask) {
            int j = (int)__builtin_ctzll(mask);
            mask &= mask - 1;
            float sv = __shfl(s, j);
            if (sv > mnc) {
                unsigned long long gt = __ballot(lane < 20 && lvr > sv);
                int cpos = __popcll(gt);
                float upv = __shfl_up(lvr, 1);
                int   upi = __shfl_up(lir, 1);
                if (lane >= cpos && lane < 20) {
                    lvr = (lane == cpos) ? sv : upv;
                    lir = (lane == cpos) ? (m0 + j) : upi;
                }
                mnc = __shfl(lvr, 19);
            }
        }
    };

    prefetch(0);
    commit();
    __syncthreads();

    for (int mc = 0; mc < 64; ++mc) {
        int m0 = mc << 6;

        // ---- MFMA Gram: rows wr*16..+15 x cands wc*16..+15
        {
            f32x4 acc = {0.f, 0.f, 0.f, 0.f};
            int n_ = (wc << 4) + (lane & 15);
            float xxv = xxb[m0 + n_];
#pragma unroll
            for (int kc = 0; kc < 2; ++kc) {
                int unit = (kc * 4 + (lane >> 4)) ^ (n_ & 7);
                bf16x8 bh = *(const bf16x8*)&xs_[n_ * 64 + unit * 8];
                bf16x8 bl = *(const bf16x8*)&xs_[4096 + n_ * 64 + unit * 8];
                acc = __builtin_amdgcn_mfma_f32_16x16x32_bf16(ah[kc], bh, acc, 0, 0, 0);
                acc = __builtin_amdgcn_mfma_f32_16x16x32_bf16(ah[kc], bl, acc, 0, 0, 0);
                acc = __builtin_amdgcn_mfma_f32_16x16x32_bf16(al[kc], bh, acc, 0, 0, 0);
                acc = __builtin_amdgcn_mfma_f32_16x16x32_bf16(al[kc], bl, acc, 0, 0, 0);
            }
#pragma unroll
            for (int r = 0; r < 4; ++r)
                sc[(wr << 4) + ((lane >> 4) << 2) + r][(wc << 4) + (lane & 15)] =
                    2.f * acc[r] - xxv;
        }

        // ---- issue next chunk's global loads (land during selection)
        if (mc + 1 < 64) prefetch(mc + 1);

        __syncthreads();   // sc complete; xs_ consumed by all waves

        // ---- selection: wave w owns rows 4w..4w+3 over all 64 cands
#pragma unroll
        for (int i = 0; i < 4; ++i) {
            int lrow = (w << 2) + i;
            float s = sc[lrow][lane];
            ins(lv[i], li[i], s, m0);
        }

        // ---- write prefetched chunk into xs_ (overlaps straggler selection)
        if (mc + 1 < 64) commit();

        __syncthreads();   // xs_ ready for next Gram; sc reusable
    }

#pragma unroll
    for (int i = 0; i < 4; ++i) {
        int n = n0 + (w << 2) + i;
        if (lane < K_)
            idxg[((size_t)(b * N_ + n)) * K_ + lane] = li[i];
    }
}

// ---------------------------------------------------------------------------
// Kernel C1: gather + BN1/lrelu -> conv_k2 -> max_k -> BN2/lrelu -> ht[b][o][n]
// ---------------------------------------------------------------------------
__global__ void __launch_bounds__(256) k_edge(const float* __restrict__ yA,
                                              const float* __restrict__ dd,
                                              const int* __restrict__ idxg,
                                              const float* __restrict__ wk2,
                                              const float* __restrict__ g1,
                                              const float* __restrict__ bb1,
                                              const float* __restrict__ mm1,
                                              const float* __restrict__ vv1,
                                              const float* __restrict__ g2,
                                              const float* __restrict__ bb2,
                                              const float* __restrict__ mm2,
                                              const float* __restrict__ vv2,
                                              float* __restrict__ ht) {
    __shared__ float wt[64][68];
    __shared__ float tmf[8 * 1412];
    __shared__ float ddl[8][64];
    __shared__ float s1c[64], t1c[64], s2c[64], t2c[64];
    __shared__ int   il[8][K_];
    __shared__ float hl[8][64];
    int t = threadIdx.x;
    int blk = blockIdx.x;
    int b = blk >> 9;
    int n0 = (blk & 511) << 3;

    for (int i = 0; i < 16; ++i) {
        int j = i * 256 + t;
        int oo = j >> 6, ic = j & 63;
        wt[ic][oo] = wk2[j];
    }
    if (t < 64) {
        float g = g1[t], be = bb1[t], m = mm1[t], v = vv1[t];
        float s = g * rsqrtf(v + EPS_);
        s1c[t] = s; t1c[t] = be - m * s;
        g = g2[t]; be = bb2[t]; m = mm2[t]; v = vv2[t];
        s = g * rsqrtf(v + EPS_);
        s2c[t] = s; t2c[t] = be - m * s;
    }
    size_t pbase = (size_t)(b * N_ + n0);
    for (int i = t; i < 512; i += 256) {
        int pt = i >> 6, o = i & 63;
        ddl[pt][o] = dd[(pbase + pt) * 64 + o];
    }
    if (t < 8 * K_) {
        int pt = t / K_, k = t % K_;
        il[pt][k] = idxg[(pbase + pt) * K_ + k];
    }
    __syncthreads();

    const float* yAb = yA + (size_t)(b * N_) * 64;
    for (int i = 0; i < 10; ++i) {
        int j = i * 256 + t;
        int pt = j / 320;
        int r = j - pt * 320;
        int k = r >> 4;
        int f = r & 15;
        int m = il[pt][k];
        float4 y4 = *(const float4*)(yAb + (size_t)m * 64 + (f << 2));
        float vals[4] = {y4.x, y4.y, y4.z, y4.w};
        int o = f << 2;
        for (int cdx = 0; cdx < 4; ++cdx) {
            int oc = o + cdx;
            float v = vals[cdx] + ddl[pt][oc];
            v = lrelu(s1c[oc] * v + t1c[oc]);
            tmf[pt * 1412 + oc * 22 + k] = v;
        }
    }
    __syncthreads();

    int pt = t >> 5, u = t & 31;
    int o2_0 = (u & 7) << 3;
    int k0 = (u >> 3) * 5;
    float acc[8][5];
    for (int i = 0; i < 8; ++i)
        for (int q = 0; q < 5; ++q) acc[i][q] = 0.f;
    const float* tmp_ = &tmf[pt * 1412];
    for (int o = 0; o < 64; ++o) {
        float4 w0 = *(const float4*)&wt[o][o2_0];
        float4 w1v = *(const float4*)&wt[o][o2_0 + 4];
        float wv[8] = {w0.x, w0.y, w0.z, w0.w, w1v.x, w1v.y, w1v.z, w1v.w};
        float tvv[5];
        for (int q = 0; q < 5; ++q) tvv[q] = tmp_[o * 22 + k0 + q];
        for (int i = 0; i < 8; ++i)
            for (int q = 0; q < 5; ++q)
                acc[i][q] += wv[i] * tvv[q];
    }
    for (int i = 0; i < 8; ++i) {
        float pm = acc[i][0];
        for (int q = 1; q < 5; ++q) pm = fmaxf(pm, acc[i][q]);
        pm = fmaxf(pm, __shfl_xor(pm, 8));
        pm = fmaxf(pm, __shfl_xor(pm, 16));
        if ((u >> 3) == 0) {
            int o2 = o2_0 + i;
            hl[pt][o2] = lrelu(s2c[o2] * pm + t2c[o2]);
        }
    }
    __syncthreads();

    float* htb = ht + (size_t)b * 64 * N_;
    for (int i = t; i < 512; i += 256) {
        int o = i >> 3, pt2 = i & 7;
        htb[o * N_ + n0 + pt2] = hl[pt2][o];
    }
}

// ---------------------------------------------------------------------------
// Kernel C2: MLP head 64 -> 256 -> 128 -> 1 per point, 64 points per block
// ---------------------------------------------------------------------------
__global__ void __launch_bounds__(256) k_head(const float* __restrict__ ht,
                                              const float* __restrict__ w1,
                                              const float* __restrict__ g1,
                                              const float* __restrict__ bb1,
                                              const float* __restrict__ mm1,
                                              const float* __restrict__ vv1,
                                              const float* __restrict__ w2,
                                              const float* __restrict__ g2,
                                              const float* __restrict__ bb2,
                                              const float* __restrict__ mm2,
                                              const float* __restrict__ vv2,
                                              const float* __restrict__ w3,
                                              const float* __restrict__ b3,
                                              float* __restrict__ out) {
    __shared__ float hbuf[64][64];
    __shared__ float a1[256][64];
    __shared__ float a2[128][64];
    __shared__ float sA[256], tA[256], sB[128], tB[128];
    int t = threadIdx.x;
    int blk = blockIdx.x;
    int b = blk >> 6;
    int n0 = (blk & 63) << 6;
    const float* htb = ht + (size_t)b * 64 * N_;

    for (int i = 0; i < 16; ++i) {
        int j = i * 256 + t;
        int o = j >> 6, pt = j & 63;
        hbuf[o][pt] = htb[o * N_ + n0 + pt];
    }
    {
        float g = g1[t], be = bb1[t], m = mm1[t], v = vv1[t];
        float s = g * rsqrtf(v + EPS_);
        sA[t] = s; tA[t] = be - m * s;
    }
    if (t < 128) {
        float g = g2[t], be = bb2[t], m = mm2[t], v = vv2[t];
        float s = g * rsqrtf(v + EPS_);
        sB[t] = s; tB[t] = be - m * s;
    }
    __syncthreads();

    int ptg = t & 15, rg = t >> 4;
    int pt4 = ptg << 2;

    for (int ib = 0; ib < 4; ++ib) {
        int r0 = (rg << 4) + (ib << 2);
        float acc[4][4] = {};
        for (int o4 = 0; o4 < 16; ++o4) {
            float hf[4][4];
            for (int c = 0; c < 4; ++c) {
                float4 q = *(const float4*)&hbuf[(o4 << 2) + c][pt4];
                hf[c][0] = q.x; hf[c][1] = q.y; hf[c][2] = q.z; hf[c][3] = q.w;
            }
            for (int j = 0; j < 4; ++j) {
                float4 wv4 = *(const float4*)(w1 + (r0 + j) * 64 + (o4 << 2));
                float wv[4] = {wv4.x, wv4.y, wv4.z, wv4.w};
                for (int c = 0; c < 4; ++c)
                    for (int pp = 0; pp < 4; ++pp)
                        acc[j][pp] += wv[c] * hf[c][pp];
            }
        }
        for (int j = 0; j < 4; ++j) {
            int r = r0 + j;
            float4 ov;
            ov.x = lrelu(sA[r] * acc[j][0] + tA[r]);
            ov.y = lrelu(sA[r] * acc[j][1] + tA[r]);
            ov.z = lrelu(sA[r] * acc[j][2] + tA[r]);
            ov.w = lrelu(sA[r] * acc[j][3] + tA[r]);
            *(float4*)&a1[r][pt4] = ov;
        }
    }
    __syncthreads();

    for (int ib = 0; ib < 2; ++ib) {
        int r0 = (rg << 3) + (ib << 2);
        float acc[4][4] = {};
        for (int p4i = 0; p4i < 64; ++p4i) {
            float af[4][4];
            for (int c = 0; c < 4; ++c) {
                float4 q = *(const float4*)&a1[(p4i << 2) + c][pt4];
                af[c][0] = q.x; af[c][1] = q.y; af[c][2] = q.z; af[c][3] = q.w;
            }
            for (int j = 0; j < 4; ++j) {
                float4 wv4 = *(const float4*)(w2 + (r0 + j) * 256 + (p4i << 2));
                float wv[4] = {wv4.x, wv4.y, wv4.z, wv4.w};
                for (int c = 0; c < 4; ++c)
                    for (int pp = 0; pp < 4; ++pp)
                        acc[j][pp] += wv[c] * af[c][pp];
            }
        }
        for (int j = 0; j < 4; ++j) {
            int r = r0 + j;
            float4 ov;
            ov.x = lrelu(sB[r] * acc[j][0] + tB[r]);
            ov.y = lrelu(sB[r] * acc[j][1] + tB[r]);
            ov.z = lrelu(sB[r] * acc[j][2] + tB[r]);
            ov.w = lrelu(sB[r] * acc[j][3] + tB[r]);
            *(float4*)&a2[r][pt4] = ov;
        }
    }
    __syncthreads();

    if (t < 64) {
        float accv = 0.f;
        for (int q = 0; q < 128; ++q) accv += w3[q] * a2[q][t];
        accv += b3[0];
        out[b * N_ + n0 + t] = accv;
    }
}

// ---------------------------------------------------------------------------
extern "C" void kernel_launch(void* const* d_in, const int* in_sizes, int n_in,
                              void* d_out, int out_size, void* d_ws, size_t ws_size,
                              hipStream_t stream) {
    (void)in_sizes; (void)n_in; (void)out_size; (void)ws_size;
    const float* x    = (const float*)d_in[0];
    const float* wk1  = (const float*)d_in[1];
    const float* gk1  = (const float*)d_in[2];
    const float* bk1  = (const float*)d_in[3];
    const float* mk1  = (const float*)d_in[4];
    const float* vk1  = (const float*)d_in[5];
    const float* wk2  = (const float*)d_in[6];
    const float* gk2  = (const float*)d_in[7];
    const float* bk2  = (const float*)d_in[8];
    const float* mk2  = (const float*)d_in[9];
    const float* vk2  = (const float*)d_in[10];
    const float* w1   = (const float*)d_in[11];
    const float* g1   = (const float*)d_in[12];
    const float* b1   = (const float*)d_in[13];
    const float* m1   = (const float*)d_in[14];
    const float* v1   = (const float*)d_in[15];
    const float* w2   = (const float*)d_in[16];
    const float* g2   = (const float*)d_in[17];
    const float* b2   = (const float*)d_in[18];
    const float* m2   = (const float*)d_in[19];
    const float* v2   = (const float*)d_in[20];
    const float* w3   = (const float*)d_in[21];
    const float* b3   = (const float*)d_in[22];

    char* ws = (char*)d_ws;
    float* yA  = (float*)(ws);                       //  8 MB
    float* dd  = (float*)(ws + 8388608);             //  8 MB
    float* xx  = (float*)(ws + 16777216);            //  128 KB
    int*   idx = (int*)  (ws + 16908288);            //  2.5 MB
    float* ht  = (float*)(ws + 19529728);            //  8 MB
    unsigned short* xps = (unsigned short*)(ws + 27918336);  // 8 MB split-bf16 images

    k_pre <<<B_ * (N_ / 64), 256, 0, stream>>>(x, wk1, yA, dd, xx, xps);
    k_topk<<<B_ * (N_ / 32), 512, 0, stream>>>(xps, xx, idx);
    k_edge<<<B_ * (N_ / 8),  256, 0, stream>>>(yA, dd, idx, wk2,
                                               gk1, bk1, mk1, vk1,
                                               gk2, bk2, mk2, vk2, ht);
    k_head<<<B_ * (N_ / 64), 256, 0, stream>>>(ht, w1, g1, b1, m1, v1,
                                               w2, g2, b2, m2, v2, w3, b3,
                                               (float*)d_out);
}

// Round 8
// 470.466 us; speedup vs baseline: 3.6626x; 1.0459x over previous
//
#include <hip/hip_runtime.h>
#include <hip/hip_bf16.h>

#define B_ 8
#define C_ 64
#define N_ 4096
#define K_ 20
#define EPS_ 1e-5f
#define SLOPE_ 0.2f

typedef __attribute__((ext_vector_type(8))) short bf16x8;
typedef __attribute__((ext_vector_type(4))) float f32x4;

__device__ __forceinline__ float lrelu(float x) { return x >= 0.f ? x : SLOPE_ * x; }
__device__ __forceinline__ float bf2f(unsigned short u) {
    return __uint_as_float(((unsigned int)u) << 16);
}
__device__ __forceinline__ unsigned short f2bf(float f) {
    unsigned int u = __float_as_uint(f);
    return (unsigned short)((u + 0x7FFFu + ((u >> 16) & 1u)) >> 16);
}

// ---------------------------------------------------------------------------
// Kernel A: yA = wA@x, dd = (wB-wA)@x, xx = |x|^2, and pre-split bf16 hi/lo
// chunk images xps[b][chunk] (swizzled). grid 512, block 256
// ---------------------------------------------------------------------------
__global__ void __launch_bounds__(256) k_pre(const float* __restrict__ x,
                                             const float* __restrict__ wk1,
                                             float* __restrict__ yA,
                                             float* __restrict__ dd,
                                             float* __restrict__ xx,
                                             unsigned short* __restrict__ xps) {
    __shared__ float w[64][128];
    __shared__ float xs[64][64];
    int t = threadIdx.x;
    int blk = blockIdx.x;
    int b = blk >> 6;
    int n0 = (blk & 63) << 6;

    for (int i = 0; i < 8; ++i) {
        int j = i * 256 + t;
        float4 v = ((const float4*)wk1)[j];
        int o = j >> 5;
        int c4 = (j & 31) << 2;
        w[o][c4 + 0] = v.x; w[o][c4 + 1] = v.y;
        w[o][c4 + 2] = v.z; w[o][c4 + 3] = v.w;
    }
    const float* xb = x + (size_t)b * C_ * N_;
    for (int i = 0; i < 4; ++i) {
        int j = i * 256 + t;
        int c = j >> 4;
        int p4 = (j & 15) << 2;
        float4 v = *(const float4*)(xb + c * N_ + n0 + p4);
        xs[c][p4 + 0] = v.x; xs[c][p4 + 1] = v.y;
        xs[c][p4 + 2] = v.z; xs[c][p4 + 3] = v.w;
    }
    __syncthreads();

    if (t < 64) {
        float s = 0.f;
        for (int c = 0; c < 64; ++c) { float xv = xs[c][t]; s += xv * xv; }
        xx[b * N_ + n0 + t] = s;
    }

    {
        unsigned short* xc = xps + ((size_t)(b * 64 + (blk & 63))) * 8192;
#pragma unroll
        for (int q = 0; q < 2; ++q) {
            int i = q * 256 + t;          // 0..511 units
            int nl = i >> 3, oct = i & 7;
            bf16x8 hv, lv8;
#pragma unroll
            for (int j = 0; j < 8; ++j) {
                float v = xs[oct * 8 + j][nl];
                unsigned short hh = f2bf(v);
                hv[j] = (short)hh;
                lv8[j] = (short)f2bf(v - bf2f(hh));
            }
            int unit = oct ^ (nl & 7);
            *(bf16x8*)&xc[nl * 64 + unit * 8] = hv;
            *(bf16x8*)&xc[4096 + nl * 64 + unit * 8] = lv8;
        }
    }

    int p = t & 63, og = t >> 6;
    for (int oi = 0; oi < 16; ++oi) {
        int o = og * 16 + oi;
        float sA = 0.f, sB = 0.f;
        for (int c = 0; c < 64; ++c) {
            float xv = xs[c][p];
            sA += w[o][c] * xv;
            sB += w[o][64 + c] * xv;
        }
        size_t base = ((size_t)(b * N_ + n0 + p)) * 64 + o;
        yA[base] = sA;
        dd[base] = sB - sA;
    }
}

// ---------------------------------------------------------------------------
// Kernel B: top-20 neighbors by score = 2*dot(x_n,x_m) - |x_m|^2
// grid 1024 (B * N/32), block 512 = 8 waves. No LDS staging: B-fragments
// read directly from the L2-resident pre-split global images. LDS = only
// a double-buffered score tile (17.4 KB) -> ONE barrier per chunk.
// Pipeline: MFMA(i) | sc[i&1] write | preload frags(i+1) | select(i-1) | bar.
// ---------------------------------------------------------------------------
__global__ void __launch_bounds__(512) k_topk(const unsigned short* __restrict__ xps,
                                              const float* __restrict__ xx,
                                              int* __restrict__ idxg) {
    __shared__ float sc[2][32][68];
    int t = threadIdx.x;
    int lane = t & 63;
    int w = t >> 6;               // 0..7
    int wr = w >> 2;              // row group (16 rows)
    int wc = w & 3;               // cand quarter (16 cands)
    int blk = blockIdx.x;         // 0..1023
    int b = blk >> 7;
    int n0 = (blk & 127) << 5;    // 32-row block base
    int bc = b << 6;              // chunk base for this batch
    const float* xxb = xx + b * N_;

    // ---- A fragments from this block's home chunk image
    const unsigned short* xcA = xps + ((size_t)(bc + ((blk & 127) >> 1))) * 8192;
    int anl = ((blk & 1) << 5) + (wr << 4) + (lane & 15);
    bf16x8 ah[2], al[2];
#pragma unroll
    for (int kc = 0; kc < 2; ++kc) {
        int unit = (kc * 4 + (lane >> 4)) ^ (anl & 7);
        ah[kc] = *(const bf16x8*)&xcA[anl * 64 + unit * 8];
        al[kc] = *(const bf16x8*)&xcA[4096 + anl * 64 + unit * 8];
    }

    // ---- B fragment offsets within a chunk image (identical addressing)
    int n_ = (wc << 4) + (lane & 15);
    int off0 = n_ * 64 + (((lane >> 4)) ^ (n_ & 7)) * 8;        // kc=0
    int off1 = n_ * 64 + ((4 + (lane >> 4)) ^ (n_ & 7)) * 8;    // kc=1

    float lv[4];
    int   li[4];
#pragma unroll
    for (int i = 0; i < 4; ++i) { lv[i] = -3.0e38f; li[i] = 0; }

    // full-width-64 sorted insert (proven machinery)
    auto ins = [&](float& lvr, int& lir, float s, int m0) {
        float mnc = __shfl(lvr, 19);
        unsigned long long mask = __ballot(s > mnc);
        while (mask) {
            int j = (int)__builtin_ctzll(mask);
            mask &= mask - 1;
            float sv = __shfl(s, j);
            if (sv > mnc) {
                unsigned long long gt = __ballot(lane < 20 && lvr > sv);
                int cpos = __popcll(gt);
                float upv = __shfl_up(lvr, 1);
                int   upi = __shfl_up(lir, 1);
                if (lane >= cpos && lane < 20) {
                    lvr = (lane == cpos) ? sv : upv;
                    lir = (lane == cpos) ? (m0 + j) : upi;
                }
                mnc = __shfl(lvr, 19);
            }
        }
    };

    // ---- preload chunk 0 fragments + xx
    const unsigned short* xcB = xps + (size_t)bc * 8192;
    bf16x8 bh0 = *(const bf16x8*)&xcB[off0];
    bf16x8 bl0 = *(const bf16x8*)&xcB[4096 + off0];
    bf16x8 bh1 = *(const bf16x8*)&xcB[off1];
    bf16x8 bl1 = *(const bf16x8*)&xcB[4096 + off1];
    float xxv = xxb[n_];

    for (int mc = 0; mc < 64; ++mc) {
        // ---- Gram on preloaded fragments (same FMA order as before)
        f32x4 acc = {0.f, 0.f, 0.f, 0.f};
        acc = __builtin_amdgcn_mfma_f32_16x16x32_bf16(ah[0], bh0, acc, 0, 0, 0);
        acc = __builtin_amdgcn_mfma_f32_16x16x32_bf16(ah[0], bl0, acc, 0, 0, 0);
        acc = __builtin_amdgcn_mfma_f32_16x16x32_bf16(al[0], bh0, acc, 0, 0, 0);
        acc = __builtin_amdgcn_mfma_f32_16x16x32_bf16(al[0], bl0, acc, 0, 0, 0);
        acc = __builtin_amdgcn_mfma_f32_16x16x32_bf16(ah[1], bh1, acc, 0, 0, 0);
        acc = __builtin_amdgcn_mfma_f32_16x16x32_bf16(ah[1], bl1, acc, 0, 0, 0);
        acc = __builtin_amdgcn_mfma_f32_16x16x32_bf16(al[1], bh1, acc, 0, 0, 0);
        acc = __builtin_amdgcn_mfma_f32_16x16x32_bf16(al[1], bl1, acc, 0, 0, 0);

#pragma unroll
        for (int r = 0; r < 4; ++r)
            sc[mc & 1][(wr << 4) + ((lane >> 4) << 2) + r][n_] = 2.f * acc[r] - xxv;

        // ---- issue next chunk's global loads (L2-hot; hide under selection)
        if (mc + 1 < 64) {
            const unsigned short* xn2 = xps + (size_t)(bc + mc + 1) * 8192;
            bh0 = *(const bf16x8*)&xn2[off0];
            bl0 = *(const bf16x8*)&xn2[4096 + off0];
            bh1 = *(const bf16x8*)&xn2[off1];
            bl1 = *(const bf16x8*)&xn2[4096 + off1];
            xxv = xxb[((mc + 1) << 6) + n_];
        }

        // ---- selection of PREVIOUS chunk's scores (other buffer)
        if (mc > 0) {
            int m0p = (mc - 1) << 6;
#pragma unroll
            for (int i = 0; i < 4; ++i) {
                int lrow = (w << 2) + i;
                float s = sc[(mc - 1) & 1][lrow][lane];
                ins(lv[i], li[i], s, m0p);
            }
        }
        __syncthreads();
    }

    // ---- tail: select the last chunk (sc[1], chunk 63)
    {
        int m0p = 63 << 6;
#pragma unroll
        for (int i = 0; i < 4; ++i) {
            int lrow = (w << 2) + i;
            float s = sc[1][lrow][lane];
            ins(lv[i], li[i], s, m0p);
        }
    }

#pragma unroll
    for (int i = 0; i < 4; ++i) {
        int n = n0 + (w << 2) + i;
        if (lane < K_)
            idxg[((size_t)(b * N_ + n)) * K_ + lane] = li[i];
    }
}

// ---------------------------------------------------------------------------
// Kernel C1: gather + BN1/lrelu -> conv_k2 -> max_k -> BN2/lrelu -> ht[b][o][n]
// ---------------------------------------------------------------------------
__global__ void __launch_bounds__(256) k_edge(const float* __restrict__ yA,
                                              const float* __restrict__ dd,
                                              const int* __restrict__ idxg,
                                              const float* __restrict__ wk2,
                                              const float* __restrict__ g1,
                                              const float* __restrict__ bb1,
                                              const float* __restrict__ mm1,
                                              const float* __restrict__ vv1,
                                              const float* __restrict__ g2,
                                              const float* __restrict__ bb2,
                                              const float* __restrict__ mm2,
                                              const float* __restrict__ vv2,
                                              float* __restrict__ ht) {
    __shared__ float wt[64][68];
    __shared__ float tmf[8 * 1412];
    __shared__ float ddl[8][64];
    __shared__ float s1c[64], t1c[64], s2c[64], t2c[64];
    __shared__ int   il[8][K_];
    __shared__ float hl[8][64];
    int t = threadIdx.x;
    int blk = blockIdx.x;
    int b = blk >> 9;
    int n0 = (blk & 511) << 3;

    for (int i = 0; i < 16; ++i) {
        int j = i * 256 + t;
        int oo = j >> 6, ic = j & 63;
        wt[ic][oo] = wk2[j];
    }
    if (t < 64) {
        float g = g1[t], be = bb1[t], m = mm1[t], v = vv1[t];
        float s = g * rsqrtf(v + EPS_);
        s1c[t] = s; t1c[t] = be - m * s;
        g = g2[t]; be = bb2[t]; m = mm2[t]; v = vv2[t];
        s = g * rsqrtf(v + EPS_);
        s2c[t] = s; t2c[t] = be - m * s;
    }
    size_t pbase = (size_t)(b * N_ + n0);
    for (int i = t; i < 512; i += 256) {
        int pt = i >> 6, o = i & 63;
        ddl[pt][o] = dd[(pbase + pt) * 64 + o];
    }
    if (t < 8 * K_) {
        int pt = t / K_, k = t % K_;
        il[pt][k] = idxg[(pbase + pt) * K_ + k];
    }
    __syncthreads();

    const float* yAb = yA + (size_t)(b * N_) * 64;
    for (int i = 0; i < 10; ++i) {
        int j = i * 256 + t;
        int pt = j / 320;
        int r = j - pt * 320;
        int k = r >> 4;
        int f = r & 15;
        int m = il[pt][k];
        float4 y4 = *(const float4*)(yAb + (size_t)m * 64 + (f << 2));
        float vals[4] = {y4.x, y4.y, y4.z, y4.w};
        int o = f << 2;
        for (int cdx = 0; cdx < 4; ++cdx) {
            int oc = o + cdx;
            float v = vals[cdx] + ddl[pt][oc];
            v = lrelu(s1c[oc] * v + t1c[oc]);
            tmf[pt * 1412 + oc * 22 + k] = v;
        }
    }
    __syncthreads();

    int pt = t >> 5, u = t & 31;
    int o2_0 = (u & 7) << 3;
    int k0 = (u >> 3) * 5;
    float acc[8][5];
    for (int i = 0; i < 8; ++i)
        for (int q = 0; q < 5; ++q) acc[i][q] = 0.f;
    const float* tmp_ = &tmf[pt * 1412];
    for (int o = 0; o < 64; ++o) {
        float4 w0 = *(const float4*)&wt[o][o2_0];
        float4 w1v = *(const float4*)&wt[o][o2_0 + 4];
        float wv[8] = {w0.x, w0.y, w0.z, w0.w, w1v.x, w1v.y, w1v.z, w1v.w};
        float tvv[5];
        for (int q = 0; q < 5; ++q) tvv[q] = tmp_[o * 22 + k0 + q];
        for (int i = 0; i < 8; ++i)
            for (int q = 0; q < 5; ++q)
                acc[i][q] += wv[i] * tvv[q];
    }
    for (int i = 0; i < 8; ++i) {
        float pm = acc[i][0];
        for (int q = 1; q < 5; ++q) pm = fmaxf(pm, acc[i][q]);
        pm = fmaxf(pm, __shfl_xor(pm, 8));
        pm = fmaxf(pm, __shfl_xor(pm, 16));
        if ((u >> 3) == 0) {
            int o2 = o2_0 + i;
            hl[pt][o2] = lrelu(s2c[o2] * pm + t2c[o2]);
        }
    }
    __syncthreads();

    float* htb = ht + (size_t)b * 64 * N_;
    for (int i = t; i < 512; i += 256) {
        int o = i >> 3, pt2 = i & 7;
        htb[o * N_ + n0 + pt2] = hl[pt2][o];
    }
}

// ---------------------------------------------------------------------------
// Kernel C2: MLP head 64 -> 256 -> 128 -> 1 per point, 64 points per block
// ---------------------------------------------------------------------------
__global__ void __launch_bounds__(256) k_head(const float* __restrict__ ht,
                                              const float* __restrict__ w1,
                                              const float* __restrict__ g1,
                                              const float* __restrict__ bb1,
                                              const float* __restrict__ mm1,
                                              const float* __restrict__ vv1,
                                              const float* __restrict__ w2,
                                              const float* __restrict__ g2,
                                              const float* __restrict__ bb2,
                                              const float* __restrict__ mm2,
                                              const float* __restrict__ vv2,
                                              const float* __restrict__ w3,
                                              const float* __restrict__ b3,
                                              float* __restrict__ out) {
    __shared__ float hbuf[64][64];
    __shared__ float a1[256][64];
    __shared__ float a2[128][64];
    __shared__ float sA[256], tA[256], sB[128], tB[128];
    int t = threadIdx.x;
    int blk = blockIdx.x;
    int b = blk >> 6;
    int n0 = (blk & 63) << 6;
    const float* htb = ht + (size_t)b * 64 * N_;

    for (int i = 0; i < 16; ++i) {
        int j = i * 256 + t;
        int o = j >> 6, pt = j & 63;
        hbuf[o][pt] = htb[o * N_ + n0 + pt];
    }
    {
        float g = g1[t], be = bb1[t], m = mm1[t], v = vv1[t];
        float s = g * rsqrtf(v + EPS_);
        sA[t] = s; tA[t] = be - m * s;
    }
    if (t < 128) {
        float g = g2[t], be = bb2[t], m = mm2[t], v = vv2[t];
        float s = g * rsqrtf(v + EPS_);
        sB[t] = s; tB[t] = be - m * s;
    }
    __syncthreads();

    int ptg = t & 15, rg = t >> 4;
    int pt4 = ptg << 2;

    for (int ib = 0; ib < 4; ++ib) {
        int r0 = (rg << 4) + (ib << 2);
        float acc[4][4] = {};
        for (int o4 = 0; o4 < 16; ++o4) {
            float hf[4][4];
            for (int c = 0; c < 4; ++c) {
                float4 q = *(const float4*)&hbuf[(o4 << 2) + c][pt4];
                hf[c][0] = q.x; hf[c][1] = q.y; hf[c][2] = q.z; hf[c][3] = q.w;
            }
            for (int j = 0; j < 4; ++j) {
                float4 wv4 = *(const float4*)(w1 + (r0 + j) * 64 + (o4 << 2));
                float wv[4] = {wv4.x, wv4.y, wv4.z, wv4.w};
                for (int c = 0; c < 4; ++c)
                    for (int pp = 0; pp < 4; ++pp)
                        acc[j][pp] += wv[c] * hf[c][pp];
            }
        }
        for (int j = 0; j < 4; ++j) {
            int r = r0 + j;
            float4 ov;
            ov.x = lrelu(sA[r] * acc[j][0] + tA[r]);
            ov.y = lrelu(sA[r] * acc[j][1] + tA[r]);
            ov.z = lrelu(sA[r] * acc[j][2] + tA[r]);
            ov.w = lrelu(sA[r] * acc[j][3] + tA[r]);
            *(float4*)&a1[r][pt4] = ov;
        }
    }
    __syncthreads();

    for (int ib = 0; ib < 2; ++ib) {
        int r0 = (rg << 3) + (ib << 2);
        float acc[4][4] = {};
        for (int p4i = 0; p4i < 64; ++p4i) {
            float af[4][4];
            for (int c = 0; c < 4; ++c) {
                float4 q = *(const float4*)&a1[(p4i << 2) + c][pt4];
                af[c][0] = q.x; af[c][1] = q.y; af[c][2] = q.z; af[c][3] = q.w;
            }
            for (int j = 0; j < 4; ++j) {
                float4 wv4 = *(const float4*)(w2 + (r0 + j) * 256 + (p4i << 2));
                float wv[4] = {wv4.x, wv4.y, wv4.z, wv4.w};
                for (int c = 0; c < 4; ++c)
                    for (int pp = 0; pp < 4; ++pp)
                        acc[j][pp] += wv[c] * af[c][pp];
            }
        }
        for (int j = 0; j < 4; ++j) {
            int r = r0 + j;
            float4 ov;
            ov.x = lrelu(sB[r] * acc[j][0] + tB[r]);
            ov.y = lrelu(sB[r] * acc[j][1] + tB[r]);
            ov.z = lrelu(sB[r] * acc[j][2] + tB[r]);
            ov.w = lrelu(sB[r] * acc[j][3] + tB[r]);
            *(float4*)&a2[r][pt4] = ov;
        }
    }
    __syncthreads();

    if (t < 64) {
        float accv = 0.f;
        for (int q = 0; q < 128; ++q) accv += w3[q] * a2[q][t];
        accv += b3[0];
        out[b * N_ + n0 + t] = accv;
    }
}

// ---------------------------------------------------------------------------
extern "C" void kernel_launch(void* const* d_in, const int* in_sizes, int n_in,
                              void* d_out, int out_size, void* d_ws, size_t ws_size,
                              hipStream_t stream) {
    (void)in_sizes; (void)n_in; (void)out_size; (void)ws_size;
    const float* x    = (const float*)d_in[0];
    const float* wk1  = (const float*)d_in[1];
    const float* gk1  = (const float*)d_in[2];
    const float* bk1  = (const float*)d_in[3];
    const float* mk1  = (const float*)d_in[4];
    const float* vk1  = (const float*)d_in[5];
    const float* wk2  = (const float*)d_in[6];
    const float* gk2  = (const float*)d_in[7];
    const float* bk2  = (const float*)d_in[8];
    const float* mk2  = (const float*)d_in[9];
    const float* vk2  = (const float*)d_in[10];
    const float* w1   = (const float*)d_in[11];
    const float* g1   = (const float*)d_in[12];
    const float* b1   = (const float*)d_in[13];
    const float* m1   = (const float*)d_in[14];
    const float* v1   = (const float*)d_in[15];
    const float* w2   = (const float*)d_in[16];
    const float* g2   = (const float*)d_in[17];
    const float* b2   = (const float*)d_in[18];
    const float* m2   = (const float*)d_in[19];
    const float* v2   = (const float*)d_in[20];
    const float* w3   = (const float*)d_in[21];
    const float* b3   = (const float*)d_in[22];

    char* ws = (char*)d_ws;
    float* yA  = (float*)(ws);                       //  8 MB
    float* dd  = (float*)(ws + 8388608);             //  8 MB
    float* xx  = (float*)(ws + 16777216);            //  128 KB
    int*   idx = (int*)  (ws + 16908288);            //  2.5 MB
    float* ht  = (float*)(ws + 19529728);            //  8 MB
    unsigned short* xps = (unsigned short*)(ws + 27918336);  // 8 MB split-bf16 images

    k_pre <<<B_ * (N_ / 64), 256, 0, stream>>>(x, wk1, yA, dd, xx, xps);
    k_topk<<<B_ * (N_ / 32), 512, 0, stream>>>(xps, xx, idx);
    k_edge<<<B_ * (N_ / 8),  256, 0, stream>>>(yA, dd, idx, wk2,
                                               gk1, bk1, mk1, vk1,
                                               gk2, bk2, mk2, vk2, ht);
    k_head<<<B_ * (N_ / 64), 256, 0, stream>>>(ht, w1, g1, b1, m1, v1,
                                               w2, g2, b2, m2, v2, w3, b3,
                                               (float*)d_out);
}

// Round 10
// 444.036 us; speedup vs baseline: 3.8806x; 1.0595x over previous
//
#include <hip/hip_runtime.h>
#include <hip/hip_bf16.h>

#define B_ 8
#define C_ 64
#define N_ 4096
#define K_ 20
#define EPS_ 1e-5f
#define SLOPE_ 0.2f

typedef __attribute__((ext_vector_type(8))) short bf16x8;
typedef __attribute__((ext_vector_type(4))) float f32x4;

__device__ __forceinline__ float lrelu(float x) { return x >= 0.f ? x : SLOPE_ * x; }
__device__ __forceinline__ float bf2f(unsigned short u) {
    return __uint_as_float(((unsigned int)u) << 16);
}
__device__ __forceinline__ unsigned short f2bf(float f) {
    unsigned int u = __float_as_uint(f);
    return (unsigned short)((u + 0x7FFFu + ((u >> 16) & 1u)) >> 16);
}

// ---- VALU-only cross-lane helpers (no ds_bpermute / LDS pipe) -------------
__device__ __forceinline__ float rdlanef(float x, int l) {
    return __int_as_float(__builtin_amdgcn_readlane(__float_as_int(x), l));
}
// lane i <- lane i-1 for i in 1..19 (DPP row_shr:1; lane16 patched from
// lane15 via readlane + cndmask select — v_writelane builtin not exposed).
// Lane 0 keeps own value (never consumed: cpos==0 -> lane0 takes sv).
__device__ __forceinline__ int shup1i(int x, int lane) {
    int s = __builtin_amdgcn_update_dpp(x, x, 0x111, 0xF, 0xF, false);
    int l15 = __builtin_amdgcn_readlane(x, 15);
    return (lane == 16) ? l15 : s;
}
__device__ __forceinline__ float shup1f(float x, int lane) {
    return __int_as_float(shup1i(__float_as_int(x), lane));
}

// ---------------------------------------------------------------------------
// Kernel A: yA = wA@x, dd = (wB-wA)@x, xx = |x|^2, and pre-split bf16 hi/lo
// chunk images xps[b][chunk] (swizzled). grid 512, block 256
// ---------------------------------------------------------------------------
__global__ void __launch_bounds__(256) k_pre(const float* __restrict__ x,
                                             const float* __restrict__ wk1,
                                             float* __restrict__ yA,
                                             float* __restrict__ dd,
                                             float* __restrict__ xx,
                                             unsigned short* __restrict__ xps) {
    __shared__ float w[64][128];
    __shared__ float xs[64][64];
    int t = threadIdx.x;
    int blk = blockIdx.x;
    int b = blk >> 6;
    int n0 = (blk & 63) << 6;

    for (int i = 0; i < 8; ++i) {
        int j = i * 256 + t;
        float4 v = ((const float4*)wk1)[j];
        int o = j >> 5;
        int c4 = (j & 31) << 2;
        w[o][c4 + 0] = v.x; w[o][c4 + 1] = v.y;
        w[o][c4 + 2] = v.z; w[o][c4 + 3] = v.w;
    }
    const float* xb = x + (size_t)b * C_ * N_;
    for (int i = 0; i < 4; ++i) {
        int j = i * 256 + t;
        int c = j >> 4;
        int p4 = (j & 15) << 2;
        float4 v = *(const float4*)(xb + c * N_ + n0 + p4);
        xs[c][p4 + 0] = v.x; xs[c][p4 + 1] = v.y;
        xs[c][p4 + 2] = v.z; xs[c][p4 + 3] = v.w;
    }
    __syncthreads();

    if (t < 64) {
        float s = 0.f;
        for (int c = 0; c < 64; ++c) { float xv = xs[c][t]; s += xv * xv; }
        xx[b * N_ + n0 + t] = s;
    }

    {
        unsigned short* xc = xps + ((size_t)(b * 64 + (blk & 63))) * 8192;
#pragma unroll
        for (int q = 0; q < 2; ++q) {
            int i = q * 256 + t;          // 0..511 units
            int nl = i >> 3, oct = i & 7;
            bf16x8 hv, lv8;
#pragma unroll
            for (int j = 0; j < 8; ++j) {
                float v = xs[oct * 8 + j][nl];
                unsigned short hh = f2bf(v);
                hv[j] = (short)hh;
                lv8[j] = (short)f2bf(v - bf2f(hh));
            }
            int unit = oct ^ (nl & 7);
            *(bf16x8*)&xc[nl * 64 + unit * 8] = hv;
            *(bf16x8*)&xc[4096 + nl * 64 + unit * 8] = lv8;
        }
    }

    int p = t & 63, og = t >> 6;
    for (int oi = 0; oi < 16; ++oi) {
        int o = og * 16 + oi;
        float sA = 0.f, sB = 0.f;
        for (int c = 0; c < 64; ++c) {
            float xv = xs[c][p];
            sA += w[o][c] * xv;
            sB += w[o][64 + c] * xv;
        }
        size_t base = ((size_t)(b * N_ + n0 + p)) * 64 + o;
        yA[base] = sA;
        dd[base] = sB - sA;
    }
}

// ---------------------------------------------------------------------------
// Kernel B: top-20 neighbors by score = 2*dot(x_n,x_m) - |x_m|^2
// grid 1024 (B * N/32), block 512 = 8 waves. B-fragments direct from the
// L2-resident pre-split global images; double-buffered score tile in LDS;
// ONE barrier per chunk. Selection cross-lane ops are VALU-only (DPP +
// readlane) to unload the per-CU LDS pipe.
// ---------------------------------------------------------------------------
__global__ void __launch_bounds__(512) k_topk(const unsigned short* __restrict__ xps,
                                              const float* __restrict__ xx,
                                              int* __restrict__ idxg) {
    __shared__ float sc[2][32][68];
    int t = threadIdx.x;
    int lane = t & 63;
    int w = t >> 6;               // 0..7
    int wr = w >> 2;              // row group (16 rows)
    int wc = w & 3;               // cand quarter (16 cands)
    int blk = blockIdx.x;         // 0..1023
    int b = blk >> 7;
    int n0 = (blk & 127) << 5;    // 32-row block base
    int bc = b << 6;              // chunk base for this batch
    const float* xxb = xx + b * N_;

    // ---- A fragments from this block's home chunk image
    const unsigned short* xcA = xps + ((size_t)(bc + ((blk & 127) >> 1))) * 8192;
    int anl = ((blk & 1) << 5) + (wr << 4) + (lane & 15);
    bf16x8 ah[2], al[2];
#pragma unroll
    for (int kc = 0; kc < 2; ++kc) {
        int unit = (kc * 4 + (lane >> 4)) ^ (anl & 7);
        ah[kc] = *(const bf16x8*)&xcA[anl * 64 + unit * 8];
        al[kc] = *(const bf16x8*)&xcA[4096 + anl * 64 + unit * 8];
    }

    // ---- B fragment offsets within a chunk image
    int n_ = (wc << 4) + (lane & 15);
    int off0 = n_ * 64 + (((lane >> 4)) ^ (n_ & 7)) * 8;        // kc=0
    int off1 = n_ * 64 + ((4 + (lane >> 4)) ^ (n_ & 7)) * 8;    // kc=1

    float lv[4];
    int   li[4];
#pragma unroll
    for (int i = 0; i < 4; ++i) { lv[i] = -3.0e38f; li[i] = 0; }

    // full-width-64 sorted insert; cross-lane via VALU only.
    auto ins = [&](float& lvr, int& lir, float s, int m0) {
        float mnc = rdlanef(lvr, 19);
        unsigned long long mask = __ballot(s > mnc);
        while (mask) {
            int j = (int)__builtin_ctzll(mask);
            mask &= mask - 1;
            float sv = rdlanef(s, j);
            if (sv > mnc) {
                unsigned long long gt = __ballot(lane < 20 && lvr > sv);
                int cpos = __popcll(gt);
                float upv = shup1f(lvr, lane);
                int   upi = shup1i(lir, lane);
                if (lane >= cpos && lane < 20) {
                    lvr = (lane == cpos) ? sv : upv;
                    lir = (lane == cpos) ? (m0 + j) : upi;
                }
                mnc = rdlanef(lvr, 19);
            }
        }
    };

    // ---- preload chunk 0 fragments + xx
    const unsigned short* xcB = xps + (size_t)bc * 8192;
    bf16x8 bh0 = *(const bf16x8*)&xcB[off0];
    bf16x8 bl0 = *(const bf16x8*)&xcB[4096 + off0];
    bf16x8 bh1 = *(const bf16x8*)&xcB[off1];
    bf16x8 bl1 = *(const bf16x8*)&xcB[4096 + off1];
    float xxv = xxb[n_];

    for (int mc = 0; mc < 64; ++mc) {
        // ---- Gram on preloaded fragments (same FMA order as before)
        f32x4 acc = {0.f, 0.f, 0.f, 0.f};
        acc = __builtin_amdgcn_mfma_f32_16x16x32_bf16(ah[0], bh0, acc, 0, 0, 0);
        acc = __builtin_amdgcn_mfma_f32_16x16x32_bf16(ah[0], bl0, acc, 0, 0, 0);
        acc = __builtin_amdgcn_mfma_f32_16x16x32_bf16(al[0], bh0, acc, 0, 0, 0);
        acc = __builtin_amdgcn_mfma_f32_16x16x32_bf16(al[0], bl0, acc, 0, 0, 0);
        acc = __builtin_amdgcn_mfma_f32_16x16x32_bf16(ah[1], bh1, acc, 0, 0, 0);
        acc = __builtin_amdgcn_mfma_f32_16x16x32_bf16(ah[1], bl1, acc, 0, 0, 0);
        acc = __builtin_amdgcn_mfma_f32_16x16x32_bf16(al[1], bh1, acc, 0, 0, 0);
        acc = __builtin_amdgcn_mfma_f32_16x16x32_bf16(al[1], bl1, acc, 0, 0, 0);

#pragma unroll
        for (int r = 0; r < 4; ++r)
            sc[mc & 1][(wr << 4) + ((lane >> 4) << 2) + r][n_] = 2.f * acc[r] - xxv;

        // ---- issue next chunk's global loads (L2-hot; hide under selection)
        if (mc + 1 < 64) {
            const unsigned short* xn2 = xps + (size_t)(bc + mc + 1) * 8192;
            bh0 = *(const bf16x8*)&xn2[off0];
            bl0 = *(const bf16x8*)&xn2[4096 + off0];
            bh1 = *(const bf16x8*)&xn2[off1];
            bl1 = *(const bf16x8*)&xn2[4096 + off1];
            xxv = xxb[((mc + 1) << 6) + n_];
        }

        // ---- selection of PREVIOUS chunk's scores (other buffer)
        if (mc > 0) {
            int m0p = (mc - 1) << 6;
#pragma unroll
            for (int i = 0; i < 4; ++i) {
                int lrow = (w << 2) + i;
                float s = sc[(mc - 1) & 1][lrow][lane];
                ins(lv[i], li[i], s, m0p);
            }
        }
        __syncthreads();
    }

    // ---- tail: select the last chunk (sc[1], chunk 63)
    {
        int m0p = 63 << 6;
#pragma unroll
        for (int i = 0; i < 4; ++i) {
            int lrow = (w << 2) + i;
            float s = sc[1][lrow][lane];
            ins(lv[i], li[i], s, m0p);
        }
    }

#pragma unroll
    for (int i = 0; i < 4; ++i) {
        int n = n0 + (w << 2) + i;
        if (lane < K_)
            idxg[((size_t)(b * N_ + n)) * K_ + lane] = li[i];
    }
}

// ---------------------------------------------------------------------------
// Kernel C1: gather + BN1/lrelu -> conv_k2 -> max_k -> BN2/lrelu -> ht[b][o][n]
// ---------------------------------------------------------------------------
__global__ void __launch_bounds__(256) k_edge(const float* __restrict__ yA,
                                              const float* __restrict__ dd,
                                              const int* __restrict__ idxg,
                                              const float* __restrict__ wk2,
                                              const float* __restrict__ g1,
                                              const float* __restrict__ bb1,
                                              const float* __restrict__ mm1,
                                              const float* __restrict__ vv1,
                                              const float* __restrict__ g2,
                                              const float* __restrict__ bb2,
                                              const float* __restrict__ mm2,
                                              const float* __restrict__ vv2,
                                              float* __restrict__ ht) {
    __shared__ float wt[64][68];
    __shared__ float tmf[8 * 1412];
    __shared__ float ddl[8][64];
    __shared__ float s1c[64], t1c[64], s2c[64], t2c[64];
    __shared__ int   il[8][K_];
    __shared__ float hl[8][64];
    int t = threadIdx.x;
    int blk = blockIdx.x;
    int b = blk >> 9;
    int n0 = (blk & 511) << 3;

    for (int i = 0; i < 16; ++i) {
        int j = i * 256 + t;
        int oo = j >> 6, ic = j & 63;
        wt[ic][oo] = wk2[j];
    }
    if (t < 64) {
        float g = g1[t], be = bb1[t], m = mm1[t], v = vv1[t];
        float s = g * rsqrtf(v + EPS_);
        s1c[t] = s; t1c[t] = be - m * s;
        g = g2[t]; be = bb2[t]; m = mm2[t]; v = vv2[t];
        s = g * rsqrtf(v + EPS_);
        s2c[t] = s; t2c[t] = be - m * s;
    }
    size_t pbase = (size_t)(b * N_ + n0);
    for (int i = t; i < 512; i += 256) {
        int pt = i >> 6, o = i & 63;
        ddl[pt][o] = dd[(pbase + pt) * 64 + o];
    }
    if (t < 8 * K_) {
        int pt = t / K_, k = t % K_;
        il[pt][k] = idxg[(pbase + pt) * K_ + k];
    }
    __syncthreads();

    const float* yAb = yA + (size_t)(b * N_) * 64;
    for (int i = 0; i < 10; ++i) {
        int j = i * 256 + t;
        int pt = j / 320;
        int r = j - pt * 320;
        int k = r >> 4;
        int f = r & 15;
        int m = il[pt][k];
        float4 y4 = *(const float4*)(yAb + (size_t)m * 64 + (f << 2));
        float vals[4] = {y4.x, y4.y, y4.z, y4.w};
        int o = f << 2;
        for (int cdx = 0; cdx < 4; ++cdx) {
            int oc = o + cdx;
            float v = vals[cdx] + ddl[pt][oc];
            v = lrelu(s1c[oc] * v + t1c[oc]);
            tmf[pt * 1412 + oc * 22 + k] = v;
        }
    }
    __syncthreads();

    int pt = t >> 5, u = t & 31;
    int o2_0 = (u & 7) << 3;
    int k0 = (u >> 3) * 5;
    float acc[8][5];
    for (int i = 0; i < 8; ++i)
        for (int q = 0; q < 5; ++q) acc[i][q] = 0.f;
    const float* tmp_ = &tmf[pt * 1412];
    for (int o = 0; o < 64; ++o) {
        float4 w0 = *(const float4*)&wt[o][o2_0];
        float4 w1v = *(const float4*)&wt[o][o2_0 + 4];
        float wv[8] = {w0.x, w0.y, w0.z, w0.w, w1v.x, w1v.y, w1v.z, w1v.w};
        float tvv[5];
        for (int q = 0; q < 5; ++q) tvv[q] = tmp_[o * 22 + k0 + q];
        for (int i = 0; i < 8; ++i)
            for (int q = 0; q < 5; ++q)
                acc[i][q] += wv[i] * tvv[q];
    }
    for (int i = 0; i < 8; ++i) {
        float pm = acc[i][0];
        for (int q = 1; q < 5; ++q) pm = fmaxf(pm, acc[i][q]);
        pm = fmaxf(pm, __shfl_xor(pm, 8));
        pm = fmaxf(pm, __shfl_xor(pm, 16));
        if ((u >> 3) == 0) {
            int o2 = o2_0 + i;
            hl[pt][o2] = lrelu(s2c[o2] * pm + t2c[o2]);
        }
    }
    __syncthreads();

    float* htb = ht + (size_t)b * 64 * N_;
    for (int i = t; i < 512; i += 256) {
        int o = i >> 3, pt2 = i & 7;
        htb[o * N_ + n0 + pt2] = hl[pt2][o];
    }
}

// ---------------------------------------------------------------------------
// Kernel C2: MLP head 64 -> 256 -> 128 -> 1 per point, 64 points per block
// ---------------------------------------------------------------------------
__global__ void __launch_bounds__(256) k_head(const float* __restrict__ ht,
                                              const float* __restrict__ w1,
                                              const float* __restrict__ g1,
                                              const float* __restrict__ bb1,
                                              const float* __restrict__ mm1,
                                              const float* __restrict__ vv1,
                                              const float* __restrict__ w2,
                                              const float* __restrict__ g2,
                                              const float* __restrict__ bb2,
                                              const float* __restrict__ mm2,
                                              const float* __restrict__ vv2,
                                              const float* __restrict__ w3,
                                              const float* __restrict__ b3,
                                              float* __restrict__ out) {
    __shared__ float hbuf[64][64];
    __shared__ float a1[256][64];
    __shared__ float a2[128][64];
    __shared__ float sA[256], tA[256], sB[128], tB[128];
    int t = threadIdx.x;
    int blk = blockIdx.x;
    int b = blk >> 6;
    int n0 = (blk & 63) << 6;
    const float* htb = ht + (size_t)b * 64 * N_;

    for (int i = 0; i < 16; ++i) {
        int j = i * 256 + t;
        int o = j >> 6, pt = j & 63;
        hbuf[o][pt] = htb[o * N_ + n0 + pt];
    }
    {
        float g = g1[t], be = bb1[t], m = mm1[t], v = vv1[t];
        float s = g * rsqrtf(v + EPS_);
        sA[t] = s; tA[t] = be - m * s;
    }
    if (t < 128) {
        float g = g2[t], be = bb2[t], m = mm2[t], v = vv2[t];
        float s = g * rsqrtf(v + EPS_);
        sB[t] = s; tB[t] = be - m * s;
    }
    __syncthreads();

    int ptg = t & 15, rg = t >> 4;
    int pt4 = ptg << 2;

    for (int ib = 0; ib < 4; ++ib) {
        int r0 = (rg << 4) + (ib << 2);
        float acc[4][4] = {};
        for (int o4 = 0; o4 < 16; ++o4) {
            float hf[4][4];
            for (int c = 0; c < 4; ++c) {
                float4 q = *(const float4*)&hbuf[(o4 << 2) + c][pt4];
                hf[c][0] = q.x; hf[c][1] = q.y; hf[c][2] = q.z; hf[c][3] = q.w;
            }
            for (int j = 0; j < 4; ++j) {
                float4 wv4 = *(const float4*)(w1 + (r0 + j) * 64 + (o4 << 2));
                float wv[4] = {wv4.x, wv4.y, wv4.z, wv4.w};
                for (int c = 0; c < 4; ++c)
                    for (int pp = 0; pp < 4; ++pp)
                        acc[j][pp] += wv[c] * hf[c][pp];
            }
        }
        for (int j = 0; j < 4; ++j) {
            int r = r0 + j;
            float4 ov;
            ov.x = lrelu(sA[r] * acc[j][0] + tA[r]);
            ov.y = lrelu(sA[r] * acc[j][1] + tA[r]);
            ov.z = lrelu(sA[r] * acc[j][2] + tA[r]);
            ov.w = lrelu(sA[r] * acc[j][3] + tA[r]);
            *(float4*)&a1[r][pt4] = ov;
        }
    }
    __syncthreads();

    for (int ib = 0; ib < 2; ++ib) {
        int r0 = (rg << 3) + (ib << 2);
        float acc[4][4] = {};
        for (int p4i = 0; p4i < 64; ++p4i) {
            float af[4][4];
            for (int c = 0; c < 4; ++c) {
                float4 q = *(const float4*)&a1[(p4i << 2) + c][pt4];
                af[c][0] = q.x; af[c][1] = q.y; af[c][2] = q.z; af[c][3] = q.w;
            }
            for (int j = 0; j < 4; ++j) {
                float4 wv4 = *(const float4*)(w2 + (r0 + j) * 256 + (p4i << 2));
                float wv[4] = {wv4.x, wv4.y, wv4.z, wv4.w};
                for (int c = 0; c < 4; ++c)
                    for (int pp = 0; pp < 4; ++pp)
                        acc[j][pp] += wv[c] * af[c][pp];
            }
        }
        for (int j = 0; j < 4; ++j) {
            int r = r0 + j;
            float4 ov;
            ov.x = lrelu(sB[r] * acc[j][0] + tB[r]);
            ov.y = lrelu(sB[r] * acc[j][1] + tB[r]);
            ov.z = lrelu(sB[r] * acc[j][2] + tB[r]);
            ov.w = lrelu(sB[r] * acc[j][3] + tB[r]);
            *(float4*)&a2[r][pt4] = ov;
        }
    }
    __syncthreads();

    if (t < 64) {
        float accv = 0.f;
        for (int q = 0; q < 128; ++q) accv += w3[q] * a2[q][t];
        accv += b3[0];
        out[b * N_ + n0 + t] = accv;
    }
}

// ---------------------------------------------------------------------------
extern "C" void kernel_launch(void* const* d_in, const int* in_sizes, int n_in,
                              void* d_out, int out_size, void* d_ws, size_t ws_size,
                              hipStream_t stream) {
    (void)in_sizes; (void)n_in; (void)out_size; (void)ws_size;
    const float* x    = (const float*)d_in[0];
    const float* wk1  = (const float*)d_in[1];
    const float* gk1  = (const float*)d_in[2];
    const float* bk1  = (const float*)d_in[3];
    const float* mk1  = (const float*)d_in[4];
    const float* vk1  = (const float*)d_in[5];
    const float* wk2  = (const float*)d_in[6];
    const float* gk2  = (const float*)d_in[7];
    const float* bk2  = (const float*)d_in[8];
    const float* mk2  = (const float*)d_in[9];
    const float* vk2  = (const float*)d_in[10];
    const float* w1   = (const float*)d_in[11];
    const float* g1   = (const float*)d_in[12];
    const float* b1   = (const float*)d_in[13];
    const float* m1   = (const float*)d_in[14];
    const float* v1   = (const float*)d_in[15];
    const float* w2   = (const float*)d_in[16];
    const float* g2   = (const float*)d_in[17];
    const float* b2   = (const float*)d_in[18];
    const float* m2   = (const float*)d_in[19];
    const float* v2   = (const float*)d_in[20];
    const float* w3   = (const float*)d_in[21];
    const float* b3   = (const float*)d_in[22];

    char* ws = (char*)d_ws;
    float* yA  = (float*)(ws);                       //  8 MB
    float* dd  = (float*)(ws + 8388608);             //  8 MB
    float* xx  = (float*)(ws + 16777216);            //  128 KB
    int*   idx = (int*)  (ws + 16908288);            //  2.5 MB
    float* ht  = (float*)(ws + 19529728);            //  8 MB
    unsigned short* xps = (unsigned short*)(ws + 27918336);  // 8 MB split-bf16 images

    k_pre <<<B_ * (N_ / 64), 256, 0, stream>>>(x, wk1, yA, dd, xx, xps);
    k_topk<<<B_ * (N_ / 32), 512, 0, stream>>>(xps, xx, idx);
    k_edge<<<B_ * (N_ / 8),  256, 0, stream>>>(yA, dd, idx, wk2,
                                               gk1, bk1, mk1, vk1,
                                               gk2, bk2, mk2, vk2, ht);
    k_head<<<B_ * (N_ / 64), 256, 0, stream>>>(ht, w1, g1, b1, m1, v1,
                                               w2, g2, b2, m2, v2, w3, b3,
                                               (float*)d_out);
}

// Round 11
// 398.104 us; speedup vs baseline: 4.3283x; 1.1154x over previous
//
#include <hip/hip_runtime.h>
#include <hip/hip_bf16.h>

#define B_ 8
#define C_ 64
#define N_ 4096
#define K_ 20
#define EPS_ 1e-5f
#define SLOPE_ 0.2f

typedef __attribute__((ext_vector_type(8))) short bf16x8;
typedef __attribute__((ext_vector_type(4))) float f32x4;

__device__ __forceinline__ float lrelu(float x) { return x >= 0.f ? x : SLOPE_ * x; }
__device__ __forceinline__ float bf2f(unsigned short u) {
    return __uint_as_float(((unsigned int)u) << 16);
}
__device__ __forceinline__ unsigned short f2bf(float f) {
    unsigned int u = __float_as_uint(f);
    return (unsigned short)((u + 0x7FFFu + ((u >> 16) & 1u)) >> 16);
}

__device__ __forceinline__ float rdlanef(float x, int l) {
    return __int_as_float(__builtin_amdgcn_readlane(__float_as_int(x), l));
}

// ---------------------------------------------------------------------------
// Kernel A: yA = wA@x, dd = (wB-wA)@x, xx = |x|^2, and pre-split bf16 hi/lo
// chunk images xps[b][chunk] (swizzled). grid 512, block 256
// ---------------------------------------------------------------------------
__global__ void __launch_bounds__(256) k_pre(const float* __restrict__ x,
                                             const float* __restrict__ wk1,
                                             float* __restrict__ yA,
                                             float* __restrict__ dd,
                                             float* __restrict__ xx,
                                             unsigned short* __restrict__ xps) {
    __shared__ float w[64][128];
    __shared__ float xs[64][64];
    int t = threadIdx.x;
    int blk = blockIdx.x;
    int b = blk >> 6;
    int n0 = (blk & 63) << 6;

    for (int i = 0; i < 8; ++i) {
        int j = i * 256 + t;
        float4 v = ((const float4*)wk1)[j];
        int o = j >> 5;
        int c4 = (j & 31) << 2;
        w[o][c4 + 0] = v.x; w[o][c4 + 1] = v.y;
        w[o][c4 + 2] = v.z; w[o][c4 + 3] = v.w;
    }
    const float* xb = x + (size_t)b * C_ * N_;
    for (int i = 0; i < 4; ++i) {
        int j = i * 256 + t;
        int c = j >> 4;
        int p4 = (j & 15) << 2;
        float4 v = *(const float4*)(xb + c * N_ + n0 + p4);
        xs[c][p4 + 0] = v.x; xs[c][p4 + 1] = v.y;
        xs[c][p4 + 2] = v.z; xs[c][p4 + 3] = v.w;
    }
    __syncthreads();

    if (t < 64) {
        float s = 0.f;
        for (int c = 0; c < 64; ++c) { float xv = xs[c][t]; s += xv * xv; }
        xx[b * N_ + n0 + t] = s;
    }

    {
        unsigned short* xc = xps + ((size_t)(b * 64 + (blk & 63))) * 8192;
#pragma unroll
        for (int q = 0; q < 2; ++q) {
            int i = q * 256 + t;          // 0..511 units
            int nl = i >> 3, oct = i & 7;
            bf16x8 hv, lv8;
#pragma unroll
            for (int j = 0; j < 8; ++j) {
                float v = xs[oct * 8 + j][nl];
                unsigned short hh = f2bf(v);
                hv[j] = (short)hh;
                lv8[j] = (short)f2bf(v - bf2f(hh));
            }
            int unit = oct ^ (nl & 7);
            *(bf16x8*)&xc[nl * 64 + unit * 8] = hv;
            *(bf16x8*)&xc[4096 + nl * 64 + unit * 8] = lv8;
        }
    }

    int p = t & 63, og = t >> 6;
    for (int oi = 0; oi < 16; ++oi) {
        int o = og * 16 + oi;
        float sA = 0.f, sB = 0.f;
        for (int c = 0; c < 64; ++c) {
            float xv = xs[c][p];
            sA += w[o][c] * xv;
            sB += w[o][64 + c] * xv;
        }
        size_t base = ((size_t)(b * N_ + n0 + p)) * 64 + o;
        yA[base] = sA;
        dd[base] = sB - sA;
    }
}

// ---------------------------------------------------------------------------
// Kernel B: top-20 neighbors by score = 2*dot(x_n,x_m) - |x_m|^2
// grid 1024 (B * N/32), block 512 = 8 waves. B-fragments direct from the
// L2-resident pre-split global images; double-buffered score tile in LDS;
// ONE barrier per chunk. Insert shift-up via ds_permute (idle LDS pipe);
// compares/selects on VALU; readlane broadcasts uniform values.
// ---------------------------------------------------------------------------
__global__ void __launch_bounds__(512) k_topk(const unsigned short* __restrict__ xps,
                                              const float* __restrict__ xx,
                                              int* __restrict__ idxg) {
    __shared__ float sc[2][32][68];
    int t = threadIdx.x;
    int lane = t & 63;
    int w = t >> 6;               // 0..7
    int wr = w >> 2;              // row group (16 rows)
    int wc = w & 3;               // cand quarter (16 cands)
    int blk = blockIdx.x;         // 0..1023
    int b = blk >> 7;
    int n0 = (blk & 127) << 5;    // 32-row block base
    int bc = b << 6;              // chunk base for this batch
    const float* xxb = xx + b * N_;
    int pa = ((lane + 1) & 63) << 2;   // ds_permute push addr: lane i -> lane i+1

    // ---- A fragments from this block's home chunk image
    const unsigned short* xcA = xps + ((size_t)(bc + ((blk & 127) >> 1))) * 8192;
    int anl = ((blk & 1) << 5) + (wr << 4) + (lane & 15);
    bf16x8 ah[2], al[2];
#pragma unroll
    for (int kc = 0; kc < 2; ++kc) {
        int unit = (kc * 4 + (lane >> 4)) ^ (anl & 7);
        ah[kc] = *(const bf16x8*)&xcA[anl * 64 + unit * 8];
        al[kc] = *(const bf16x8*)&xcA[4096 + anl * 64 + unit * 8];
    }

    // ---- B fragment offsets within a chunk image
    int n_ = (wc << 4) + (lane & 15);
    int off0 = n_ * 64 + (((lane >> 4)) ^ (n_ & 7)) * 8;        // kc=0
    int off1 = n_ * 64 + ((4 + (lane >> 4)) ^ (n_ & 7)) * 8;    // kc=1

    float lv[4];
    int   li[4];
#pragma unroll
    for (int i = 0; i < 4; ++i) { lv[i] = -3.0e38f; li[i] = 0; }

    // full-width-64 sorted insert; shift via ds_permute (full-wave active
    // at every call site — divergence here is wave-uniform only).
    auto ins = [&](float& lvr, int& lir, float s, int m0) {
        float mnc = rdlanef(lvr, 19);
        unsigned long long mask = __ballot(s > mnc);
        while (mask) {
            int j = (int)__builtin_ctzll(mask);
            mask &= mask - 1;
            float sv = rdlanef(s, j);
            if (sv > mnc) {
                unsigned long long gt = __ballot(lane < 20 && lvr > sv);
                int cpos = __popcll(gt);
                float upv = __int_as_float(
                    __builtin_amdgcn_ds_permute(pa, __float_as_int(lvr)));
                int   upi = __builtin_amdgcn_ds_permute(pa, lir);
                if (lane >= cpos && lane < 20) {
                    lvr = (lane == cpos) ? sv : upv;
                    lir = (lane == cpos) ? (m0 + j) : upi;
                }
                mnc = rdlanef(lvr, 19);
            }
        }
    };

    // ---- preload chunk 0 fragments + xx
    const unsigned short* xcB = xps + (size_t)bc * 8192;
    bf16x8 bh0 = *(const bf16x8*)&xcB[off0];
    bf16x8 bl0 = *(const bf16x8*)&xcB[4096 + off0];
    bf16x8 bh1 = *(const bf16x8*)&xcB[off1];
    bf16x8 bl1 = *(const bf16x8*)&xcB[4096 + off1];
    float xxv = xxb[n_];

    for (int mc = 0; mc < 64; ++mc) {
        // ---- Gram on preloaded fragments (same FMA order as before)
        f32x4 acc = {0.f, 0.f, 0.f, 0.f};
        acc = __builtin_amdgcn_mfma_f32_16x16x32_bf16(ah[0], bh0, acc, 0, 0, 0);
        acc = __builtin_amdgcn_mfma_f32_16x16x32_bf16(ah[0], bl0, acc, 0, 0, 0);
        acc = __builtin_amdgcn_mfma_f32_16x16x32_bf16(al[0], bh0, acc, 0, 0, 0);
        acc = __builtin_amdgcn_mfma_f32_16x16x32_bf16(al[0], bl0, acc, 0, 0, 0);
        acc = __builtin_amdgcn_mfma_f32_16x16x32_bf16(ah[1], bh1, acc, 0, 0, 0);
        acc = __builtin_amdgcn_mfma_f32_16x16x32_bf16(ah[1], bl1, acc, 0, 0, 0);
        acc = __builtin_amdgcn_mfma_f32_16x16x32_bf16(al[1], bh1, acc, 0, 0, 0);
        acc = __builtin_amdgcn_mfma_f32_16x16x32_bf16(al[1], bl1, acc, 0, 0, 0);

#pragma unroll
        for (int r = 0; r < 4; ++r)
            sc[mc & 1][(wr << 4) + ((lane >> 4) << 2) + r][n_] = 2.f * acc[r] - xxv;

        // ---- issue next chunk's global loads (L2-hot; hide under selection)
        if (mc + 1 < 64) {
            const unsigned short* xn2 = xps + (size_t)(bc + mc + 1) * 8192;
            bh0 = *(const bf16x8*)&xn2[off0];
            bl0 = *(const bf16x8*)&xn2[4096 + off0];
            bh1 = *(const bf16x8*)&xn2[off1];
            bl1 = *(const bf16x8*)&xn2[4096 + off1];
            xxv = xxb[((mc + 1) << 6) + n_];
        }

        // ---- selection of PREVIOUS chunk's scores (other buffer)
        if (mc > 0) {
            int m0p = (mc - 1) << 6;
#pragma unroll
            for (int i = 0; i < 4; ++i) {
                int lrow = (w << 2) + i;
                float s = sc[(mc - 1) & 1][lrow][lane];
                ins(lv[i], li[i], s, m0p);
            }
        }
        __syncthreads();
    }

    // ---- tail: select the last chunk (sc[1], chunk 63)
    {
        int m0p = 63 << 6;
#pragma unroll
        for (int i = 0; i < 4; ++i) {
            int lrow = (w << 2) + i;
            float s = sc[1][lrow][lane];
            ins(lv[i], li[i], s, m0p);
        }
    }

#pragma unroll
    for (int i = 0; i < 4; ++i) {
        int n = n0 + (w << 2) + i;
        if (lane < K_)
            idxg[((size_t)(b * N_ + n)) * K_ + lane] = li[i];
    }
}

// ---------------------------------------------------------------------------
// Kernel C1: gather + BN1/lrelu -> conv_k2 -> max_k -> BN2/lrelu -> ht[b][o][n]
// ---------------------------------------------------------------------------
__global__ void __launch_bounds__(256) k_edge(const float* __restrict__ yA,
                                              const float* __restrict__ dd,
                                              const int* __restrict__ idxg,
                                              const float* __restrict__ wk2,
                                              const float* __restrict__ g1,
                                              const float* __restrict__ bb1,
                                              const float* __restrict__ mm1,
                                              const float* __restrict__ vv1,
                                              const float* __restrict__ g2,
                                              const float* __restrict__ bb2,
                                              const float* __restrict__ mm2,
                                              const float* __restrict__ vv2,
                                              float* __restrict__ ht) {
    __shared__ float wt[64][68];
    __shared__ float tmf[8 * 1412];
    __shared__ float ddl[8][64];
    __shared__ float s1c[64], t1c[64], s2c[64], t2c[64];
    __shared__ int   il[8][K_];
    __shared__ float hl[8][64];
    int t = threadIdx.x;
    int blk = blockIdx.x;
    int b = blk >> 9;
    int n0 = (blk & 511) << 3;

    for (int i = 0; i < 16; ++i) {
        int j = i * 256 + t;
        int oo = j >> 6, ic = j & 63;
        wt[ic][oo] = wk2[j];
    }
    if (t < 64) {
        float g = g1[t], be = bb1[t], m = mm1[t], v = vv1[t];
        float s = g * rsqrtf(v + EPS_);
        s1c[t] = s; t1c[t] = be - m * s;
        g = g2[t]; be = bb2[t]; m = mm2[t]; v = vv2[t];
        s = g * rsqrtf(v + EPS_);
        s2c[t] = s; t2c[t] = be - m * s;
    }
    size_t pbase = (size_t)(b * N_ + n0);
    for (int i = t; i < 512; i += 256) {
        int pt = i >> 6, o = i & 63;
        ddl[pt][o] = dd[(pbase + pt) * 64 + o];
    }
    if (t < 8 * K_) {
        int pt = t / K_, k = t % K_;
        il[pt][k] = idxg[(pbase + pt) * K_ + k];
    }
    __syncthreads();

    const float* yAb = yA + (size_t)(b * N_) * 64;
    for (int i = 0; i < 10; ++i) {
        int j = i * 256 + t;
        int pt = j / 320;
        int r = j - pt * 320;
        int k = r >> 4;
        int f = r & 15;
        int m = il[pt][k];
        float4 y4 = *(const float4*)(yAb + (size_t)m * 64 + (f << 2));
        float vals[4] = {y4.x, y4.y, y4.z, y4.w};
        int o = f << 2;
        for (int cdx = 0; cdx < 4; ++cdx) {
            int oc = o + cdx;
            float v = vals[cdx] + ddl[pt][oc];
            v = lrelu(s1c[oc] * v + t1c[oc]);
            tmf[pt * 1412 + oc * 22 + k] = v;
        }
    }
    __syncthreads();

    int pt = t >> 5, u = t & 31;
    int o2_0 = (u & 7) << 3;
    int k0 = (u >> 3) * 5;
    float acc[8][5];
    for (int i = 0; i < 8; ++i)
        for (int q = 0; q < 5; ++q) acc[i][q] = 0.f;
    const float* tmp_ = &tmf[pt * 1412];
    for (int o = 0; o < 64; ++o) {
        float4 w0 = *(const float4*)&wt[o][o2_0];
        float4 w1v = *(const float4*)&wt[o][o2_0 + 4];
        float wv[8] = {w0.x, w0.y, w0.z, w0.w, w1v.x, w1v.y, w1v.z, w1v.w};
        float tvv[5];
        for (int q = 0; q < 5; ++q) tvv[q] = tmp_[o * 22 + k0 + q];
        for (int i = 0; i < 8; ++i)
            for (int q = 0; q < 5; ++q)
                acc[i][q] += wv[i] * tvv[q];
    }
    for (int i = 0; i < 8; ++i) {
        float pm = acc[i][0];
        for (int q = 1; q < 5; ++q) pm = fmaxf(pm, acc[i][q]);
        pm = fmaxf(pm, __shfl_xor(pm, 8));
        pm = fmaxf(pm, __shfl_xor(pm, 16));
        if ((u >> 3) == 0) {
            int o2 = o2_0 + i;
            hl[pt][o2] = lrelu(s2c[o2] * pm + t2c[o2]);
        }
    }
    __syncthreads();

    float* htb = ht + (size_t)b * 64 * N_;
    for (int i = t; i < 512; i += 256) {
        int o = i >> 3, pt2 = i & 7;
        htb[o * N_ + n0 + pt2] = hl[pt2][o];
    }
}

// ---------------------------------------------------------------------------
// Kernel C2: MLP head 64 -> 256 -> 128 -> 1 per point, 64 points per block
// ---------------------------------------------------------------------------
__global__ void __launch_bounds__(256) k_head(const float* __restrict__ ht,
                                              const float* __restrict__ w1,
                                              const float* __restrict__ g1,
                                              const float* __restrict__ bb1,
                                              const float* __restrict__ mm1,
                                              const float* __restrict__ vv1,
                                              const float* __restrict__ w2,
                                              const float* __restrict__ g2,
                                              const float* __restrict__ bb2,
                                              const float* __restrict__ mm2,
                                              const float* __restrict__ vv2,
                                              const float* __restrict__ w3,
                                              const float* __restrict__ b3,
                                              float* __restrict__ out) {
    __shared__ float hbuf[64][64];
    __shared__ float a1[256][64];
    __shared__ float a2[128][64];
    __shared__ float sA[256], tA[256], sB[128], tB[128];
    int t = threadIdx.x;
    int blk = blockIdx.x;
    int b = blk >> 6;
    int n0 = (blk & 63) << 6;
    const float* htb = ht + (size_t)b * 64 * N_;

    for (int i = 0; i < 16; ++i) {
        int j = i * 256 + t;
        int o = j >> 6, pt = j & 63;
        hbuf[o][pt] = htb[o * N_ + n0 + pt];
    }
    {
        float g = g1[t], be = bb1[t], m = mm1[t], v = vv1[t];
        float s = g * rsqrtf(v + EPS_);
        sA[t] = s; tA[t] = be - m * s;
    }
    if (t < 128) {
        float g = g2[t], be = bb2[t], m = mm2[t], v = vv2[t];
        float s = g * rsqrtf(v + EPS_);
        sB[t] = s; tB[t] = be - m * s;
    }
    __syncthreads();

    int ptg = t & 15, rg = t >> 4;
    int pt4 = ptg << 2;

    for (int ib = 0; ib < 4; ++ib) {
        int r0 = (rg << 4) + (ib << 2);
        float acc[4][4] = {};
        for (int o4 = 0; o4 < 16; ++o4) {
            float hf[4][4];
            for (int c = 0; c < 4; ++c) {
                float4 q = *(const float4*)&hbuf[(o4 << 2) + c][pt4];
                hf[c][0] = q.x; hf[c][1] = q.y; hf[c][2] = q.z; hf[c][3] = q.w;
            }
            for (int j = 0; j < 4; ++j) {
                float4 wv4 = *(const float4*)(w1 + (r0 + j) * 64 + (o4 << 2));
                float wv[4] = {wv4.x, wv4.y, wv4.z, wv4.w};
                for (int c = 0; c < 4; ++c)
                    for (int pp = 0; pp < 4; ++pp)
                        acc[j][pp] += wv[c] * hf[c][pp];
            }
        }
        for (int j = 0; j < 4; ++j) {
            int r = r0 + j;
            float4 ov;
            ov.x = lrelu(sA[r] * acc[j][0] + tA[r]);
            ov.y = lrelu(sA[r] * acc[j][1] + tA[r]);
            ov.z = lrelu(sA[r] * acc[j][2] + tA[r]);
            ov.w = lrelu(sA[r] * acc[j][3] + tA[r]);
            *(float4*)&a1[r][pt4] = ov;
        }
    }
    __syncthreads();

    for (int ib = 0; ib < 2; ++ib) {
        int r0 = (rg << 3) + (ib << 2);
        float acc[4][4] = {};
        for (int p4i = 0; p4i < 64; ++p4i) {
            float af[4][4];
            for (int c = 0; c < 4; ++c) {
                float4 q = *(const float4*)&a1[(p4i << 2) + c][pt4];
                af[c][0] = q.x; af[c][1] = q.y; af[c][2] = q.z; af[c][3] = q.w;
            }
            for (int j = 0; j < 4; ++j) {
                float4 wv4 = *(const float4*)(w2 + (r0 + j) * 256 + (p4i << 2));
                float wv[4] = {wv4.x, wv4.y, wv4.z, wv4.w};
                for (int c = 0; c < 4; ++c)
                    for (int pp = 0; pp < 4; ++pp)
                        acc[j][pp] += wv[c] * af[c][pp];
            }
        }
        for (int j = 0; j < 4; ++j) {
            int r = r0 + j;
            float4 ov;
            ov.x = lrelu(sB[r] * acc[j][0] + tB[r]);
            ov.y = lrelu(sB[r] * acc[j][1] + tB[r]);
            ov.z = lrelu(sB[r] * acc[j][2] + tB[r]);
            ov.w = lrelu(sB[r] * acc[j][3] + tB[r]);
            *(float4*)&a2[r][pt4] = ov;
        }
    }
    __syncthreads();

    if (t < 64) {
        float accv = 0.f;
        for (int q = 0; q < 128; ++q) accv += w3[q] * a2[q][t];
        accv += b3[0];
        out[b * N_ + n0 + t] = accv;
    }
}

// ---------------------------------------------------------------------------
extern "C" void kernel_launch(void* const* d_in, const int* in_sizes, int n_in,
                              void* d_out, int out_size, void* d_ws, size_t ws_size,
                              hipStream_t stream) {
    (void)in_sizes; (void)n_in; (void)out_size; (void)ws_size;
    const float* x    = (const float*)d_in[0];
    const float* wk1  = (const float*)d_in[1];
    const float* gk1  = (const float*)d_in[2];
    const float* bk1  = (const float*)d_in[3];
    const float* mk1  = (const float*)d_in[4];
    const float* vk1  = (const float*)d_in[5];
    const float* wk2  = (const float*)d_in[6];
    const float* gk2  = (const float*)d_in[7];
    const float* bk2  = (const float*)d_in[8];
    const float* mk2  = (const float*)d_in[9];
    const float* vk2  = (const float*)d_in[10];
    const float* w1   = (const float*)d_in[11];
    const float* g1   = (const float*)d_in[12];
    const float* b1   = (const float*)d_in[13];
    const float* m1   = (const float*)d_in[14];
    const float* v1   = (const float*)d_in[15];
    const float* w2   = (const float*)d_in[16];
    const float* g2   = (const float*)d_in[17];
    const float* b2   = (const float*)d_in[18];
    const float* m2   = (const float*)d_in[19];
    const float* v2   = (const float*)d_in[20];
    const float* w3   = (const float*)d_in[21];
    const float* b3   = (const float*)d_in[22];

    char* ws = (char*)d_ws;
    float* yA  = (float*)(ws);                       //  8 MB
    float* dd  = (float*)(ws + 8388608);             //  8 MB
    float* xx  = (float*)(ws + 16777216);            //  128 KB
    int*   idx = (int*)  (ws + 16908288);            //  2.5 MB
    float* ht  = (float*)(ws + 19529728);            //  8 MB
    unsigned short* xps = (unsigned short*)(ws + 27918336);  // 8 MB split-bf16 images

    k_pre <<<B_ * (N_ / 64), 256, 0, stream>>>(x, wk1, yA, dd, xx, xps);
    k_topk<<<B_ * (N_ / 32), 512, 0, stream>>>(xps, xx, idx);
    k_edge<<<B_ * (N_ / 8),  256, 0, stream>>>(yA, dd, idx, wk2,
                                               gk1, bk1, mk1, vk1,
                                               gk2, bk2, mk2, vk2, ht);
    k_head<<<B_ * (N_ / 64), 256, 0, stream>>>(ht, w1, g1, b1, m1, v1,
                                               w2, g2, b2, m2, v2, w3, b3,
                                               (float*)d_out);
}

// Round 12
// 357.714 us; speedup vs baseline: 4.8170x; 1.1129x over previous
//
#include <hip/hip_runtime.h>
#include <hip/hip_bf16.h>

#define B_ 8
#define C_ 64
#define N_ 4096
#define K_ 20
#define EPS_ 1e-5f
#define SLOPE_ 0.2f

typedef __attribute__((ext_vector_type(8))) short bf16x8;
typedef __attribute__((ext_vector_type(4))) float f32x4;

__device__ __forceinline__ float lrelu(float x) { return x >= 0.f ? x : SLOPE_ * x; }
__device__ __forceinline__ float bf2f(unsigned short u) {
    return __uint_as_float(((unsigned int)u) << 16);
}
__device__ __forceinline__ unsigned short f2bf(float f) {
    unsigned int u = __float_as_uint(f);
    return (unsigned short)((u + 0x7FFFu + ((u >> 16) & 1u)) >> 16);
}

__device__ __forceinline__ float rdlanef(float x, int l) {
    return __int_as_float(__builtin_amdgcn_readlane(__float_as_int(x), l));
}

// ---------------------------------------------------------------------------
// Kernel A: yA = wA@x, dd = (wB-wA)@x, xx = |x|^2, and pre-split bf16 hi/lo
// chunk images xps[b][chunk] (swizzled). grid 512, block 256
// ---------------------------------------------------------------------------
__global__ void __launch_bounds__(256) k_pre(const float* __restrict__ x,
                                             const float* __restrict__ wk1,
                                             float* __restrict__ yA,
                                             float* __restrict__ dd,
                                             float* __restrict__ xx,
                                             unsigned short* __restrict__ xps) {
    __shared__ float w[64][128];
    __shared__ float xs[64][64];
    int t = threadIdx.x;
    int blk = blockIdx.x;
    int b = blk >> 6;
    int n0 = (blk & 63) << 6;

    for (int i = 0; i < 8; ++i) {
        int j = i * 256 + t;
        float4 v = ((const float4*)wk1)[j];
        int o = j >> 5;
        int c4 = (j & 31) << 2;
        w[o][c4 + 0] = v.x; w[o][c4 + 1] = v.y;
        w[o][c4 + 2] = v.z; w[o][c4 + 3] = v.w;
    }
    const float* xb = x + (size_t)b * C_ * N_;
    for (int i = 0; i < 4; ++i) {
        int j = i * 256 + t;
        int c = j >> 4;
        int p4 = (j & 15) << 2;
        float4 v = *(const float4*)(xb + c * N_ + n0 + p4);
        xs[c][p4 + 0] = v.x; xs[c][p4 + 1] = v.y;
        xs[c][p4 + 2] = v.z; xs[c][p4 + 3] = v.w;
    }
    __syncthreads();

    if (t < 64) {
        float s = 0.f;
        for (int c = 0; c < 64; ++c) { float xv = xs[c][t]; s += xv * xv; }
        xx[b * N_ + n0 + t] = s;
    }

    {
        unsigned short* xc = xps + ((size_t)(b * 64 + (blk & 63))) * 8192;
#pragma unroll
        for (int q = 0; q < 2; ++q) {
            int i = q * 256 + t;          // 0..511 units
            int nl = i >> 3, oct = i & 7;
            bf16x8 hv, lv8;
#pragma unroll
            for (int j = 0; j < 8; ++j) {
                float v = xs[oct * 8 + j][nl];
                unsigned short hh = f2bf(v);
                hv[j] = (short)hh;
                lv8[j] = (short)f2bf(v - bf2f(hh));
            }
            int unit = oct ^ (nl & 7);
            *(bf16x8*)&xc[nl * 64 + unit * 8] = hv;
            *(bf16x8*)&xc[4096 + nl * 64 + unit * 8] = lv8;
        }
    }

    int p = t & 63, og = t >> 6;
    for (int oi = 0; oi < 16; ++oi) {
        int o = og * 16 + oi;
        float sA = 0.f, sB = 0.f;
        for (int c = 0; c < 64; ++c) {
            float xv = xs[c][p];
            sA += w[o][c] * xv;
            sB += w[o][64 + c] * xv;
        }
        size_t base = ((size_t)(b * N_ + n0 + p)) * 64 + o;
        yA[base] = sA;
        dd[base] = sB - sA;
    }
}

// ---------------------------------------------------------------------------
// Kernel B: top-20 neighbors (unchanged from round 11 — proven)
// ---------------------------------------------------------------------------
__global__ void __launch_bounds__(512) k_topk(const unsigned short* __restrict__ xps,
                                              const float* __restrict__ xx,
                                              int* __restrict__ idxg) {
    __shared__ float sc[2][32][68];
    int t = threadIdx.x;
    int lane = t & 63;
    int w = t >> 6;               // 0..7
    int wr = w >> 2;              // row group (16 rows)
    int wc = w & 3;               // cand quarter (16 cands)
    int blk = blockIdx.x;         // 0..1023
    int b = blk >> 7;
    int n0 = (blk & 127) << 5;    // 32-row block base
    int bc = b << 6;              // chunk base for this batch
    const float* xxb = xx + b * N_;
    int pa = ((lane + 1) & 63) << 2;   // ds_permute push addr: lane i -> lane i+1

    const unsigned short* xcA = xps + ((size_t)(bc + ((blk & 127) >> 1))) * 8192;
    int anl = ((blk & 1) << 5) + (wr << 4) + (lane & 15);
    bf16x8 ah[2], al[2];
#pragma unroll
    for (int kc = 0; kc < 2; ++kc) {
        int unit = (kc * 4 + (lane >> 4)) ^ (anl & 7);
        ah[kc] = *(const bf16x8*)&xcA[anl * 64 + unit * 8];
        al[kc] = *(const bf16x8*)&xcA[4096 + anl * 64 + unit * 8];
    }

    int n_ = (wc << 4) + (lane & 15);
    int off0 = n_ * 64 + (((lane >> 4)) ^ (n_ & 7)) * 8;        // kc=0
    int off1 = n_ * 64 + ((4 + (lane >> 4)) ^ (n_ & 7)) * 8;    // kc=1

    float lv[4];
    int   li[4];
#pragma unroll
    for (int i = 0; i < 4; ++i) { lv[i] = -3.0e38f; li[i] = 0; }

    auto ins = [&](float& lvr, int& lir, float s, int m0) {
        float mnc = rdlanef(lvr, 19);
        unsigned long long mask = __ballot(s > mnc);
        while (mask) {
            int j = (int)__builtin_ctzll(mask);
            mask &= mask - 1;
            float sv = rdlanef(s, j);
            if (sv > mnc) {
                unsigned long long gt = __ballot(lane < 20 && lvr > sv);
                int cpos = __popcll(gt);
                float upv = __int_as_float(
                    __builtin_amdgcn_ds_permute(pa, __float_as_int(lvr)));
                int   upi = __builtin_amdgcn_ds_permute(pa, lir);
                if (lane >= cpos && lane < 20) {
                    lvr = (lane == cpos) ? sv : upv;
                    lir = (lane == cpos) ? (m0 + j) : upi;
                }
                mnc = rdlanef(lvr, 19);
            }
        }
    };

    const unsigned short* xcB = xps + (size_t)bc * 8192;
    bf16x8 bh0 = *(const bf16x8*)&xcB[off0];
    bf16x8 bl0 = *(const bf16x8*)&xcB[4096 + off0];
    bf16x8 bh1 = *(const bf16x8*)&xcB[off1];
    bf16x8 bl1 = *(const bf16x8*)&xcB[4096 + off1];
    float xxv = xxb[n_];

    for (int mc = 0; mc < 64; ++mc) {
        f32x4 acc = {0.f, 0.f, 0.f, 0.f};
        acc = __builtin_amdgcn_mfma_f32_16x16x32_bf16(ah[0], bh0, acc, 0, 0, 0);
        acc = __builtin_amdgcn_mfma_f32_16x16x32_bf16(ah[0], bl0, acc, 0, 0, 0);
        acc = __builtin_amdgcn_mfma_f32_16x16x32_bf16(al[0], bh0, acc, 0, 0, 0);
        acc = __builtin_amdgcn_mfma_f32_16x16x32_bf16(al[0], bl0, acc, 0, 0, 0);
        acc = __builtin_amdgcn_mfma_f32_16x16x32_bf16(ah[1], bh1, acc, 0, 0, 0);
        acc = __builtin_amdgcn_mfma_f32_16x16x32_bf16(ah[1], bl1, acc, 0, 0, 0);
        acc = __builtin_amdgcn_mfma_f32_16x16x32_bf16(al[1], bh1, acc, 0, 0, 0);
        acc = __builtin_amdgcn_mfma_f32_16x16x32_bf16(al[1], bl1, acc, 0, 0, 0);

#pragma unroll
        for (int r = 0; r < 4; ++r)
            sc[mc & 1][(wr << 4) + ((lane >> 4) << 2) + r][n_] = 2.f * acc[r] - xxv;

        if (mc + 1 < 64) {
            const unsigned short* xn2 = xps + (size_t)(bc + mc + 1) * 8192;
            bh0 = *(const bf16x8*)&xn2[off0];
            bl0 = *(const bf16x8*)&xn2[4096 + off0];
            bh1 = *(const bf16x8*)&xn2[off1];
            bl1 = *(const bf16x8*)&xn2[4096 + off1];
            xxv = xxb[((mc + 1) << 6) + n_];
        }

        if (mc > 0) {
            int m0p = (mc - 1) << 6;
#pragma unroll
            for (int i = 0; i < 4; ++i) {
                int lrow = (w << 2) + i;
                float s = sc[(mc - 1) & 1][lrow][lane];
                ins(lv[i], li[i], s, m0p);
            }
        }
        __syncthreads();
    }

    {
        int m0p = 63 << 6;
#pragma unroll
        for (int i = 0; i < 4; ++i) {
            int lrow = (w << 2) + i;
            float s = sc[1][lrow][lane];
            ins(lv[i], li[i], s, m0p);
        }
    }

#pragma unroll
    for (int i = 0; i < 4; ++i) {
        int n = n0 + (w << 2) + i;
        if (lane < K_)
            idxg[((size_t)(b * N_ + n)) * K_ + lane] = li[i];
    }
}

// ---------------------------------------------------------------------------
// Kernel C1 (MFMA rewrite): gather+BN1 -> split-bf16 images -> MFMA GEMM
// C[o2][col=(pt,k)] = W @ T -> ct in LDS -> max_k -> BN2/lrelu -> ht[b][o][n]
// grid 4096 (B * N/8), block 256 (4 waves; wave w = M-tile o2 range w*16..+15)
// ---------------------------------------------------------------------------
__global__ void __launch_bounds__(256) k_edge(const float* __restrict__ yA,
                                              const float* __restrict__ dd,
                                              const int* __restrict__ idxg,
                                              const float* __restrict__ wk2,
                                              const float* __restrict__ g1,
                                              const float* __restrict__ bb1,
                                              const float* __restrict__ mm1,
                                              const float* __restrict__ vv1,
                                              const float* __restrict__ g2,
                                              const float* __restrict__ bb2,
                                              const float* __restrict__ mm2,
                                              const float* __restrict__ vv2,
                                              float* __restrict__ ht) {
    __shared__ unsigned short wimg[8192];   // W hi[4096] | lo[4096] swizzled image
    __shared__ float ubuf[64 * 164];        // union: T hi/lo images, then ct[64][164]
    __shared__ float s1c[64], t1c[64], s2c[64], t2c[64];
    __shared__ float ddl[8][64];
    __shared__ int   il[8][K_];
    __shared__ float hl[8][64];
    unsigned short* timgH = (unsigned short*)ubuf;          // [col][64] cols 0..159
    unsigned short* timgL = timgH + 160 * 64;
    float* ct = ubuf;                                       // [64][164] after MFMA

    int t = threadIdx.x;
    int lane = t & 63;
    int w = t >> 6;               // wave 0..3 = M-tile
    int blk = blockIdx.x;
    int b = blk >> 9;
    int n0 = (blk & 511) << 3;

    // ---- preload: W hi/lo image (verified k_pre staging pattern), BN consts
    for (int rep = 0; rep < 2; ++rep) {
        int i = rep * 256 + t;            // 512 items of 8 elems
        int row = i >> 3, oct = i & 7;
        float4 wa = *(const float4*)(wk2 + row * 64 + oct * 8);
        float4 wb = *(const float4*)(wk2 + row * 64 + oct * 8 + 4);
        float wv[8] = {wa.x, wa.y, wa.z, wa.w, wb.x, wb.y, wb.z, wb.w};
        bf16x8 hv, lv8;
#pragma unroll
        for (int j = 0; j < 8; ++j) {
            unsigned short hh = f2bf(wv[j]);
            hv[j] = (short)hh;
            lv8[j] = (short)f2bf(wv[j] - bf2f(hh));
        }
        int unit = oct ^ (row & 7);
        *(bf16x8*)&wimg[row * 64 + unit * 8] = hv;
        *(bf16x8*)&wimg[4096 + row * 64 + unit * 8] = lv8;
    }
    if (t < 64) {
        float g = g1[t], be = bb1[t], m = mm1[t], v = vv1[t];
        float s = g * rsqrtf(v + EPS_);
        s1c[t] = s; t1c[t] = be - m * s;
        g = g2[t]; be = bb2[t]; m = mm2[t]; v = vv2[t];
        s = g * rsqrtf(v + EPS_);
        s2c[t] = s; t2c[t] = be - m * s;
    }
    size_t pbase = (size_t)(b * N_ + n0);
    for (int i = t; i < 512; i += 256) {
        int pt = i >> 6, o = i & 63;
        ddl[pt][o] = dd[(pbase + pt) * 64 + o];
    }
    if (t < 8 * K_) {
        int pt = t / K_, k = t % K_;
        il[pt][k] = idxg[(pbase + pt) * K_ + k];
    }
    __syncthreads();

    // ---- gather: T[o][col] = lrelu(BN1(yA[m][o] + dd[n][o])) -> hi/lo image
    // 1280 8-elem items; 5/thread; batch global loads first (latency overlap)
    const float* yAb = yA + (size_t)(b * N_) * 64;
    float4 ga[5][2];
    int gcol[5], goct[5], gpt[5];
#pragma unroll
    for (int rep = 0; rep < 5; ++rep) {
        int j = rep * 256 + t;
        int pt = j / 160;
        int r = j - pt * 160;
        int k = r >> 3, oct = r & 7;
        int m = il[pt][k];
        const float* src = yAb + (size_t)m * 64 + oct * 8;
        ga[rep][0] = *(const float4*)src;
        ga[rep][1] = *(const float4*)(src + 4);
        gcol[rep] = pt * 20 + k; goct[rep] = oct; gpt[rep] = pt;
    }
#pragma unroll
    for (int rep = 0; rep < 5; ++rep) {
        int oct = goct[rep], pt = gpt[rep], col = gcol[rep];
        float yv[8] = {ga[rep][0].x, ga[rep][0].y, ga[rep][0].z, ga[rep][0].w,
                       ga[rep][1].x, ga[rep][1].y, ga[rep][1].z, ga[rep][1].w};
        bf16x8 hv, lv8;
#pragma unroll
        for (int jj = 0; jj < 8; ++jj) {
            int oc = oct * 8 + jj;
            float v = lrelu(s1c[oc] * (yv[jj] + ddl[pt][oc]) + t1c[oc]);
            unsigned short hh = f2bf(v);
            hv[jj] = (short)hh;
            lv8[jj] = (short)f2bf(v - bf2f(hh));
        }
        int unit = oct ^ (col & 7);
        *(bf16x8*)&timgH[col * 64 + unit * 8] = hv;
        *(bf16x8*)&timgL[col * 64 + unit * 8] = lv8;
    }
    __syncthreads();

    // ---- MFMA: wave w handles o2-tile w (rows w*16..+15), 10 N-tiles
    int anl = (w << 4) + (lane & 15);
    bf16x8 ah[2], al[2];
#pragma unroll
    for (int kc = 0; kc < 2; ++kc) {
        int unit = (kc * 4 + (lane >> 4)) ^ (anl & 7);
        ah[kc] = *(const bf16x8*)&wimg[anl * 64 + unit * 8];
        al[kc] = *(const bf16x8*)&wimg[4096 + anl * 64 + unit * 8];
    }
    f32x4 acc[10];
#pragma unroll
    for (int nt = 0; nt < 10; ++nt) {
        int col = nt * 16 + (lane & 15);
        int u0 = ((lane >> 4)) ^ (col & 7);
        int u1 = (4 + (lane >> 4)) ^ (col & 7);
        bf16x8 bh0 = *(const bf16x8*)&timgH[col * 64 + u0 * 8];
        bf16x8 bl0 = *(const bf16x8*)&timgL[col * 64 + u0 * 8];
        bf16x8 bh1 = *(const bf16x8*)&timgH[col * 64 + u1 * 8];
        bf16x8 bl1 = *(const bf16x8*)&timgL[col * 64 + u1 * 8];
        f32x4 a = {0.f, 0.f, 0.f, 0.f};
        a = __builtin_amdgcn_mfma_f32_16x16x32_bf16(ah[0], bh0, a, 0, 0, 0);
        a = __builtin_amdgcn_mfma_f32_16x16x32_bf16(ah[0], bl0, a, 0, 0, 0);
        a = __builtin_amdgcn_mfma_f32_16x16x32_bf16(al[0], bh0, a, 0, 0, 0);
        a = __builtin_amdgcn_mfma_f32_16x16x32_bf16(al[0], bl0, a, 0, 0, 0);
        a = __builtin_amdgcn_mfma_f32_16x16x32_bf16(ah[1], bh1, a, 0, 0, 0);
        a = __builtin_amdgcn_mfma_f32_16x16x32_bf16(ah[1], bl1, a, 0, 0, 0);
        a = __builtin_amdgcn_mfma_f32_16x16x32_bf16(al[1], bh1, a, 0, 0, 0);
        a = __builtin_amdgcn_mfma_f32_16x16x32_bf16(al[1], bl1, a, 0, 0, 0);
        acc[nt] = a;
    }
    __syncthreads();   // all T-image reads complete before ct overwrite

    // ---- write C to ct[o2][col] (D-layout: col=lane&15, row=(lane>>4)*4+r)
#pragma unroll
    for (int nt = 0; nt < 10; ++nt) {
#pragma unroll
        for (int r = 0; r < 4; ++r)
            ct[((w << 4) + ((lane >> 4) << 2) + r) * 164 + nt * 16 + (lane & 15)] =
                acc[nt][r];
    }
    __syncthreads();

    // ---- max over k (20 cols per point) + BN2/lrelu
#pragma unroll
    for (int rep = 0; rep < 2; ++rep) {
        int pair = rep * 256 + t;          // 512 (o2,pt) pairs
        int o2 = pair >> 3, pt = pair & 7;
        const float* row = &ct[o2 * 164 + pt * 20];
        float4 c0 = *(const float4*)(row + 0);
        float4 c1 = *(const float4*)(row + 4);
        float4 c2 = *(const float4*)(row + 8);
        float4 c3 = *(const float4*)(row + 12);
        float4 c4 = *(const float4*)(row + 16);
        float mx = fmaxf(fmaxf(fmaxf(c0.x, c0.y), fmaxf(c0.z, c0.w)),
                   fmaxf(fmaxf(fmaxf(c1.x, c1.y), fmaxf(c1.z, c1.w)),
                   fmaxf(fmaxf(fmaxf(c2.x, c2.y), fmaxf(c2.z, c2.w)),
                   fmaxf(fmaxf(fmaxf(c3.x, c3.y), fmaxf(c3.z, c3.w)),
                         fmaxf(fmaxf(c4.x, c4.y), fmaxf(c4.z, c4.w))))));
        hl[pt][o2] = lrelu(s2c[o2] * mx + t2c[o2]);
    }
    __syncthreads();

    // ---- write ht transposed [b][o][n]
    float* htb = ht + (size_t)b * 64 * N_;
    for (int i = t; i < 512; i += 256) {
        int o = i >> 3, pt2 = i & 7;
        htb[o * N_ + n0 + pt2] = hl[pt2][o];
    }
}

// ---------------------------------------------------------------------------
// Kernel C2: MLP head 64 -> 256 -> 128 -> 1 per point, 64 points per block
// ---------------------------------------------------------------------------
__global__ void __launch_bounds__(256) k_head(const float* __restrict__ ht,
                                              const float* __restrict__ w1,
                                              const float* __restrict__ g1,
                                              const float* __restrict__ bb1,
                                              const float* __restrict__ mm1,
                                              const float* __restrict__ vv1,
                                              const float* __restrict__ w2,
                                              const float* __restrict__ g2,
                                              const float* __restrict__ bb2,
                                              const float* __restrict__ mm2,
                                              const float* __restrict__ vv2,
                                              const float* __restrict__ w3,
                                              const float* __restrict__ b3,
                                              float* __restrict__ out) {
    __shared__ float hbuf[64][64];
    __shared__ float a1[256][64];
    __shared__ float a2[128][64];
    __shared__ float sA[256], tA[256], sB[128], tB[128];
    int t = threadIdx.x;
    int blk = blockIdx.x;
    int b = blk >> 6;
    int n0 = (blk & 63) << 6;
    const float* htb = ht + (size_t)b * 64 * N_;

    for (int i = 0; i < 16; ++i) {
        int j = i * 256 + t;
        int o = j >> 6, pt = j & 63;
        hbuf[o][pt] = htb[o * N_ + n0 + pt];
    }
    {
        float g = g1[t], be = bb1[t], m = mm1[t], v = vv1[t];
        float s = g * rsqrtf(v + EPS_);
        sA[t] = s; tA[t] = be - m * s;
    }
    if (t < 128) {
        float g = g2[t], be = bb2[t], m = mm2[t], v = vv2[t];
        float s = g * rsqrtf(v + EPS_);
        sB[t] = s; tB[t] = be - m * s;
    }
    __syncthreads();

    int ptg = t & 15, rg = t >> 4;
    int pt4 = ptg << 2;

    for (int ib = 0; ib < 4; ++ib) {
        int r0 = (rg << 4) + (ib << 2);
        float acc[4][4] = {};
        for (int o4 = 0; o4 < 16; ++o4) {
            float hf[4][4];
            for (int c = 0; c < 4; ++c) {
                float4 q = *(const float4*)&hbuf[(o4 << 2) + c][pt4];
                hf[c][0] = q.x; hf[c][1] = q.y; hf[c][2] = q.z; hf[c][3] = q.w;
            }
            for (int j = 0; j < 4; ++j) {
                float4 wv4 = *(const float4*)(w1 + (r0 + j) * 64 + (o4 << 2));
                float wv[4] = {wv4.x, wv4.y, wv4.z, wv4.w};
                for (int c = 0; c < 4; ++c)
                    for (int pp = 0; pp < 4; ++pp)
                        acc[j][pp] += wv[c] * hf[c][pp];
            }
        }
        for (int j = 0; j < 4; ++j) {
            int r = r0 + j;
            float4 ov;
            ov.x = lrelu(sA[r] * acc[j][0] + tA[r]);
            ov.y = lrelu(sA[r] * acc[j][1] + tA[r]);
            ov.z = lrelu(sA[r] * acc[j][2] + tA[r]);
            ov.w = lrelu(sA[r] * acc[j][3] + tA[r]);
            *(float4*)&a1[r][pt4] = ov;
        }
    }
    __syncthreads();

    for (int ib = 0; ib < 2; ++ib) {
        int r0 = (rg << 3) + (ib << 2);
        float acc[4][4] = {};
        for (int p4i = 0; p4i < 64; ++p4i) {
            float af[4][4];
            for (int c = 0; c < 4; ++c) {
                float4 q = *(const float4*)&a1[(p4i << 2) + c][pt4];
                af[c][0] = q.x; af[c][1] = q.y; af[c][2] = q.z; af[c][3] = q.w;
            }
            for (int j = 0; j < 4; ++j) {
                float4 wv4 = *(const float4*)(w2 + (r0 + j) * 256 + (p4i << 2));
                float wv[4] = {wv4.x, wv4.y, wv4.z, wv4.w};
                for (int c = 0; c < 4; ++c)
                    for (int pp = 0; pp < 4; ++pp)
                        acc[j][pp] += wv[c] * af[c][pp];
            }
        }
        for (int j = 0; j < 4; ++j) {
            int r = r0 + j;
            float4 ov;
            ov.x = lrelu(sB[r] * acc[j][0] + tB[r]);
            ov.y = lrelu(sB[r] * acc[j][1] + tB[r]);
            ov.z = lrelu(sB[r] * acc[j][2] + tB[r]);
            ov.w = lrelu(sB[r] * acc[j][3] + tB[r]);
            *(float4*)&a2[r][pt4] = ov;
        }
    }
    __syncthreads();

    if (t < 64) {
        float accv = 0.f;
        for (int q = 0; q < 128; ++q) accv += w3[q] * a2[q][t];
        accv += b3[0];
        out[b * N_ + n0 + t] = accv;
    }
}

// ---------------------------------------------------------------------------
extern "C" void kernel_launch(void* const* d_in, const int* in_sizes, int n_in,
                              void* d_out, int out_size, void* d_ws, size_t ws_size,
                              hipStream_t stream) {
    (void)in_sizes; (void)n_in; (void)out_size; (void)ws_size;
    const float* x    = (const float*)d_in[0];
    const float* wk1  = (const float*)d_in[1];
    const float* gk1  = (const float*)d_in[2];
    const float* bk1  = (const float*)d_in[3];
    const float* mk1  = (const float*)d_in[4];
    const float* vk1  = (const float*)d_in[5];
    const float* wk2  = (const float*)d_in[6];
    const float* gk2  = (const float*)d_in[7];
    const float* bk2  = (const float*)d_in[8];
    const float* mk2  = (const float*)d_in[9];
    const float* vk2  = (const float*)d_in[10];
    const float* w1   = (const float*)d_in[11];
    const float* g1   = (const float*)d_in[12];
    const float* b1   = (const float*)d_in[13];
    const float* m1   = (const float*)d_in[14];
    const float* v1   = (const float*)d_in[15];
    const float* w2   = (const float*)d_in[16];
    const float* g2   = (const float*)d_in[17];
    const float* b2   = (const float*)d_in[18];
    const float* m2   = (const float*)d_in[19];
    const float* v2   = (const float*)d_in[20];
    const float* w3   = (const float*)d_in[21];
    const float* b3   = (const float*)d_in[22];

    char* ws = (char*)d_ws;
    float* yA  = (float*)(ws);                       //  8 MB
    float* dd  = (float*)(ws + 8388608);             //  8 MB
    float* xx  = (float*)(ws + 16777216);            //  128 KB
    int*   idx = (int*)  (ws + 16908288);            //  2.5 MB
    float* ht  = (float*)(ws + 19529728);            //  8 MB
    unsigned short* xps = (unsigned short*)(ws + 27918336);  // 8 MB split-bf16 images

    k_pre <<<B_ * (N_ / 64), 256, 0, stream>>>(x, wk1, yA, dd, xx, xps);
    k_topk<<<B_ * (N_ / 32), 512, 0, stream>>>(xps, xx, idx);
    k_edge<<<B_ * (N_ / 8),  256, 0, stream>>>(yA, dd, idx, wk2,
                                               gk1, bk1, mk1, vk1,
                                               gk2, bk2, mk2, vk2, ht);
    k_head<<<B_ * (N_ / 64), 256, 0, stream>>>(ht, w1, g1, b1, m1, v1,
                                               w2, g2, b2, m2, v2, w3, b3,
                                               (float*)d_out);
}

// Round 13
// 341.412 us; speedup vs baseline: 5.0470x; 1.0477x over previous
//
#include <hip/hip_runtime.h>
#include <hip/hip_bf16.h>

#define B_ 8
#define C_ 64
#define N_ 4096
#define K_ 20
#define EPS_ 1e-5f
#define SLOPE_ 0.2f

typedef __attribute__((ext_vector_type(8))) short bf16x8;
typedef __attribute__((ext_vector_type(4))) float f32x4;

__device__ __forceinline__ float lrelu(float x) { return x >= 0.f ? x : SLOPE_ * x; }
__device__ __forceinline__ float bf2f(unsigned short u) {
    return __uint_as_float(((unsigned int)u) << 16);
}
__device__ __forceinline__ unsigned short f2bf(float f) {
    unsigned int u = __float_as_uint(f);
    return (unsigned short)((u + 0x7FFFu + ((u >> 16) & 1u)) >> 16);
}

__device__ __forceinline__ float rdlanef(float x, int l) {
    return __int_as_float(__builtin_amdgcn_readlane(__float_as_int(x), l));
}

// ---------------------------------------------------------------------------
// Kernel A (MFMA rewrite): Y[128x64] = [wA;wB] @ xs via split-bf16 MFMA.
// yA = rows 0..63; dd = rows 64..127 - rows 0..63. Also xx and xps images.
// grid 512 (B * N/64), block 256 (4 waves; wave w = M-tiles {w, w+4})
// ---------------------------------------------------------------------------
__global__ void __launch_bounds__(256) k_pre(const float* __restrict__ x,
                                             const float* __restrict__ wk1,
                                             float* __restrict__ yA,
                                             float* __restrict__ dd,
                                             float* __restrict__ xx,
                                             unsigned short* __restrict__ xps) {
    __shared__ float xs[64][64];              // 16 KB [c][p]
    __shared__ unsigned short wimg[16384];    // 32 KB: hi[8192] | lo[8192], m=0..127
    __shared__ unsigned short ximg[8192];     // 16 KB: hi[4096] | lo[4096], p=0..63
    int t = threadIdx.x;
    int lane = t & 63;
    int w = t >> 6;
    int blk = blockIdx.x;
    int b = blk >> 6;
    int n0 = (blk & 63) << 6;

    // ---- stage xs (coalesced)
    const float* xb = x + (size_t)b * C_ * N_;
    for (int i = 0; i < 4; ++i) {
        int j = i * 256 + t;
        int c = j >> 4;
        int p4 = (j & 15) << 2;
        float4 v = *(const float4*)(xb + c * N_ + n0 + p4);
        xs[c][p4 + 0] = v.x; xs[c][p4 + 1] = v.y;
        xs[c][p4 + 2] = v.z; xs[c][p4 + 3] = v.w;
    }
    // ---- build stacked-W image: S[m][c] = m<64 ? wA[m][c] : wB[m-64][c]
    for (int rep = 0; rep < 4; ++rep) {
        int i = rep * 256 + t;                // 1024 units (128 m x 8 oct)
        int m = i >> 3, oct = i & 7;
        const float* src = wk1 + (m & 63) * 128 + ((m >> 6) << 6) + oct * 8;
        float4 a4 = *(const float4*)src;
        float4 b4 = *(const float4*)(src + 4);
        float wv[8] = {a4.x, a4.y, a4.z, a4.w, b4.x, b4.y, b4.z, b4.w};
        bf16x8 hv, lv8;
#pragma unroll
        for (int j = 0; j < 8; ++j) {
            unsigned short hh = f2bf(wv[j]);
            hv[j] = (short)hh;
            lv8[j] = (short)f2bf(wv[j] - bf2f(hh));
        }
        int unit = oct ^ (m & 7);
        *(bf16x8*)&wimg[m * 64 + unit * 8] = hv;
        *(bf16x8*)&wimg[8192 + m * 64 + unit * 8] = lv8;
    }
    __syncthreads();

    if (t < 64) {
        float s = 0.f;
        for (int c = 0; c < 64; ++c) { float xv = xs[c][t]; s += xv * xv; }
        xx[b * N_ + n0 + t] = s;
    }

    // ---- build x image (LDS + global xps, identical bytes to before)
    unsigned short* xc = xps + ((size_t)(b * 64 + (blk & 63))) * 8192;
#pragma unroll
    for (int q = 0; q < 2; ++q) {
        int i = q * 256 + t;
        int nl = i >> 3, oct = i & 7;
        bf16x8 hv, lv8;
#pragma unroll
        for (int j = 0; j < 8; ++j) {
            float v = xs[oct * 8 + j][nl];
            unsigned short hh = f2bf(v);
            hv[j] = (short)hh;
            lv8[j] = (short)f2bf(v - bf2f(hh));
        }
        int unit = oct ^ (nl & 7);
        *(bf16x8*)&ximg[nl * 64 + unit * 8] = hv;
        *(bf16x8*)&ximg[4096 + nl * 64 + unit * 8] = lv8;
        *(bf16x8*)&xc[nl * 64 + unit * 8] = hv;
        *(bf16x8*)&xc[4096 + nl * 64 + unit * 8] = lv8;
    }
    __syncthreads();

    // ---- MFMA: wave w owns M-tiles {w (yA-part), w+4 (wB-part)}
    int mA = (w << 4) + (lane & 15);
    int mB = ((w + 4) << 4) + (lane & 15);
    bf16x8 ahA[2], alA[2], ahB[2], alB[2];
#pragma unroll
    for (int kc = 0; kc < 2; ++kc) {
        int uA = (kc * 4 + (lane >> 4)) ^ (mA & 7);
        int uB = (kc * 4 + (lane >> 4)) ^ (mB & 7);
        ahA[kc] = *(const bf16x8*)&wimg[mA * 64 + uA * 8];
        alA[kc] = *(const bf16x8*)&wimg[8192 + mA * 64 + uA * 8];
        ahB[kc] = *(const bf16x8*)&wimg[mB * 64 + uB * 8];
        alB[kc] = *(const bf16x8*)&wimg[8192 + mB * 64 + uB * 8];
    }
    size_t pbase = (size_t)(b * N_ + n0);
#pragma unroll
    for (int nt = 0; nt < 4; ++nt) {
        int p = nt * 16 + (lane & 15);
        int u0 = ((lane >> 4)) ^ (p & 7);
        int u1 = (4 + (lane >> 4)) ^ (p & 7);
        bf16x8 bh0 = *(const bf16x8*)&ximg[p * 64 + u0 * 8];
        bf16x8 bl0 = *(const bf16x8*)&ximg[4096 + p * 64 + u0 * 8];
        bf16x8 bh1 = *(const bf16x8*)&ximg[p * 64 + u1 * 8];
        bf16x8 bl1 = *(const bf16x8*)&ximg[4096 + p * 64 + u1 * 8];
        f32x4 aA = {0.f, 0.f, 0.f, 0.f};
        aA = __builtin_amdgcn_mfma_f32_16x16x32_bf16(ahA[0], bh0, aA, 0, 0, 0);
        aA = __builtin_amdgcn_mfma_f32_16x16x32_bf16(ahA[0], bl0, aA, 0, 0, 0);
        aA = __builtin_amdgcn_mfma_f32_16x16x32_bf16(alA[0], bh0, aA, 0, 0, 0);
        aA = __builtin_amdgcn_mfma_f32_16x16x32_bf16(alA[0], bl0, aA, 0, 0, 0);
        aA = __builtin_amdgcn_mfma_f32_16x16x32_bf16(ahA[1], bh1, aA, 0, 0, 0);
        aA = __builtin_amdgcn_mfma_f32_16x16x32_bf16(ahA[1], bl1, aA, 0, 0, 0);
        aA = __builtin_amdgcn_mfma_f32_16x16x32_bf16(alA[1], bh1, aA, 0, 0, 0);
        aA = __builtin_amdgcn_mfma_f32_16x16x32_bf16(alA[1], bl1, aA, 0, 0, 0);
        f32x4 aB = {0.f, 0.f, 0.f, 0.f};
        aB = __builtin_amdgcn_mfma_f32_16x16x32_bf16(ahB[0], bh0, aB, 0, 0, 0);
        aB = __builtin_amdgcn_mfma_f32_16x16x32_bf16(ahB[0], bl0, aB, 0, 0, 0);
        aB = __builtin_amdgcn_mfma_f32_16x16x32_bf16(alB[0], bh0, aB, 0, 0, 0);
        aB = __builtin_amdgcn_mfma_f32_16x16x32_bf16(alB[0], bl0, aB, 0, 0, 0);
        aB = __builtin_amdgcn_mfma_f32_16x16x32_bf16(ahB[1], bh1, aB, 0, 0, 0);
        aB = __builtin_amdgcn_mfma_f32_16x16x32_bf16(ahB[1], bl1, aB, 0, 0, 0);
        aB = __builtin_amdgcn_mfma_f32_16x16x32_bf16(alB[1], bh1, aB, 0, 0, 0);
        aB = __builtin_amdgcn_mfma_f32_16x16x32_bf16(alB[1], bl1, aB, 0, 0, 0);

        // D layout: col p = lane&15 (this nt), rows o = w*16 + (lane>>4)*4 + r
        int obase = (w << 4) + ((lane >> 4) << 2);
        float4 ya4 = {aA[0], aA[1], aA[2], aA[3]};
        float4 dd4 = {aB[0] - aA[0], aB[1] - aA[1], aB[2] - aA[2], aB[3] - aA[3]};
        *(float4*)(yA + (pbase + p) * 64 + obase) = ya4;
        *(float4*)(dd + (pbase + p) * 64 + obase) = dd4;
    }
}

// ---------------------------------------------------------------------------
// Kernel B: top-20 neighbors. Same as round 11/12 except the insert loop
// drops the in-loop threshold recheck (below-min inserts are exact no-ops),
// shortening the serial chain per candidate ~3x.
// ---------------------------------------------------------------------------
__global__ void __launch_bounds__(512) k_topk(const unsigned short* __restrict__ xps,
                                              const float* __restrict__ xx,
                                              int* __restrict__ idxg) {
    __shared__ float sc[2][32][68];
    int t = threadIdx.x;
    int lane = t & 63;
    int w = t >> 6;               // 0..7
    int wr = w >> 2;              // row group (16 rows)
    int wc = w & 3;               // cand quarter (16 cands)
    int blk = blockIdx.x;         // 0..1023
    int b = blk >> 7;
    int n0 = (blk & 127) << 5;    // 32-row block base
    int bc = b << 6;              // chunk base for this batch
    const float* xxb = xx + b * N_;
    int pa = ((lane + 1) & 63) << 2;   // ds_permute push addr: lane i -> lane i+1

    const unsigned short* xcA = xps + ((size_t)(bc + ((blk & 127) >> 1))) * 8192;
    int anl = ((blk & 1) << 5) + (wr << 4) + (lane & 15);
    bf16x8 ah[2], al[2];
#pragma unroll
    for (int kc = 0; kc < 2; ++kc) {
        int unit = (kc * 4 + (lane >> 4)) ^ (anl & 7);
        ah[kc] = *(const bf16x8*)&xcA[anl * 64 + unit * 8];
        al[kc] = *(const bf16x8*)&xcA[4096 + anl * 64 + unit * 8];
    }

    int n_ = (wc << 4) + (lane & 15);
    int off0 = n_ * 64 + (((lane >> 4)) ^ (n_ & 7)) * 8;        // kc=0
    int off1 = n_ * 64 + ((4 + (lane >> 4)) ^ (n_ & 7)) * 8;    // kc=1

    float lv[4];
    int   li[4];
#pragma unroll
    for (int i = 0; i < 4; ++i) { lv[i] = -3.0e38f; li[i] = 0; }

    // sorted insert; no in-loop threshold recheck (no-op inserts are exact)
    auto ins = [&](float& lvr, int& lir, float s, int m0) {
        float mnc = rdlanef(lvr, 19);
        unsigned long long mask = __ballot(s > mnc);
        while (mask) {
            int j = (int)__builtin_ctzll(mask);
            mask &= mask - 1;
            float sv = rdlanef(s, j);
            unsigned long long gt = __ballot(lane < 20 && lvr > sv);
            int cpos = __popcll(gt);
            float upv = __int_as_float(
                __builtin_amdgcn_ds_permute(pa, __float_as_int(lvr)));
            int   upi = __builtin_amdgcn_ds_permute(pa, lir);
            if (lane >= cpos && lane < 20) {
                lvr = (lane == cpos) ? sv : upv;
                lir = (lane == cpos) ? (m0 + j) : upi;
            }
        }
    };

    const unsigned short* xcB = xps + (size_t)bc * 8192;
    bf16x8 bh0 = *(const bf16x8*)&xcB[off0];
    bf16x8 bl0 = *(const bf16x8*)&xcB[4096 + off0];
    bf16x8 bh1 = *(const bf16x8*)&xcB[off1];
    bf16x8 bl1 = *(const bf16x8*)&xcB[4096 + off1];
    float xxv = xxb[n_];

    for (int mc = 0; mc < 64; ++mc) {
        f32x4 acc = {0.f, 0.f, 0.f, 0.f};
        acc = __builtin_amdgcn_mfma_f32_16x16x32_bf16(ah[0], bh0, acc, 0, 0, 0);
        acc = __builtin_amdgcn_mfma_f32_16x16x32_bf16(ah[0], bl0, acc, 0, 0, 0);
        acc = __builtin_amdgcn_mfma_f32_16x16x32_bf16(al[0], bh0, acc, 0, 0, 0);
        acc = __builtin_amdgcn_mfma_f32_16x16x32_bf16(al[0], bl0, acc, 0, 0, 0);
        acc = __builtin_amdgcn_mfma_f32_16x16x32_bf16(ah[1], bh1, acc, 0, 0, 0);
        acc = __builtin_amdgcn_mfma_f32_16x16x32_bf16(ah[1], bl1, acc, 0, 0, 0);
        acc = __builtin_amdgcn_mfma_f32_16x16x32_bf16(al[1], bh1, acc, 0, 0, 0);
        acc = __builtin_amdgcn_mfma_f32_16x16x32_bf16(al[1], bl1, acc, 0, 0, 0);

#pragma unroll
        for (int r = 0; r < 4; ++r)
            sc[mc & 1][(wr << 4) + ((lane >> 4) << 2) + r][n_] = 2.f * acc[r] - xxv;

        if (mc + 1 < 64) {
            const unsigned short* xn2 = xps + (size_t)(bc + mc + 1) * 8192;
            bh0 = *(const bf16x8*)&xn2[off0];
            bl0 = *(const bf16x8*)&xn2[4096 + off0];
            bh1 = *(const bf16x8*)&xn2[off1];
            bl1 = *(const bf16x8*)&xn2[4096 + off1];
            xxv = xxb[((mc + 1) << 6) + n_];
        }

        if (mc > 0) {
            int m0p = (mc - 1) << 6;
#pragma unroll
            for (int i = 0; i < 4; ++i) {
                int lrow = (w << 2) + i;
                float s = sc[(mc - 1) & 1][lrow][lane];
                ins(lv[i], li[i], s, m0p);
            }
        }
        __syncthreads();
    }

    {
        int m0p = 63 << 6;
#pragma unroll
        for (int i = 0; i < 4; ++i) {
            int lrow = (w << 2) + i;
            float s = sc[1][lrow][lane];
            ins(lv[i], li[i], s, m0p);
        }
    }

#pragma unroll
    for (int i = 0; i < 4; ++i) {
        int n = n0 + (w << 2) + i;
        if (lane < K_)
            idxg[((size_t)(b * N_ + n)) * K_ + lane] = li[i];
    }
}

// ---------------------------------------------------------------------------
// Kernel C1 (MFMA): gather+BN1 -> split-bf16 images -> MFMA GEMM
// C[o2][col=(pt,k)] = W @ T -> ct in LDS -> max_k -> BN2/lrelu -> ht[b][o][n]
// grid 4096 (B * N/8), block 256 (4 waves; wave w = M-tile o2 range w*16..+15)
// ---------------------------------------------------------------------------
__global__ void __launch_bounds__(256) k_edge(const float* __restrict__ yA,
                                              const float* __restrict__ dd,
                                              const int* __restrict__ idxg,
                                              const float* __restrict__ wk2,
                                              const float* __restrict__ g1,
                                              const float* __restrict__ bb1,
                                              const float* __restrict__ mm1,
                                              const float* __restrict__ vv1,
                                              const float* __restrict__ g2,
                                              const float* __restrict__ bb2,
                                              const float* __restrict__ mm2,
                                              const float* __restrict__ vv2,
                                              float* __restrict__ ht) {
    __shared__ unsigned short wimg[8192];   // W hi[4096] | lo[4096] swizzled image
    __shared__ float ubuf[64 * 164];        // union: T hi/lo images, then ct[64][164]
    __shared__ float s1c[64], t1c[64], s2c[64], t2c[64];
    __shared__ float ddl[8][64];
    __shared__ int   il[8][K_];
    __shared__ float hl[8][64];
    unsigned short* timgH = (unsigned short*)ubuf;          // [col][64] cols 0..159
    unsigned short* timgL = timgH + 160 * 64;
    float* ct = ubuf;                                       // [64][164] after MFMA

    int t = threadIdx.x;
    int lane = t & 63;
    int w = t >> 6;               // wave 0..3 = M-tile
    int blk = blockIdx.x;
    int b = blk >> 9;
    int n0 = (blk & 511) << 3;

    for (int rep = 0; rep < 2; ++rep) {
        int i = rep * 256 + t;            // 512 items of 8 elems
        int row = i >> 3, oct = i & 7;
        float4 wa = *(const float4*)(wk2 + row * 64 + oct * 8);
        float4 wb = *(const float4*)(wk2 + row * 64 + oct * 8 + 4);
        float wv[8] = {wa.x, wa.y, wa.z, wa.w, wb.x, wb.y, wb.z, wb.w};
        bf16x8 hv, lv8;
#pragma unroll
        for (int j = 0; j < 8; ++j) {
            unsigned short hh = f2bf(wv[j]);
            hv[j] = (short)hh;
            lv8[j] = (short)f2bf(wv[j] - bf2f(hh));
        }
        int unit = oct ^ (row & 7);
        *(bf16x8*)&wimg[row * 64 + unit * 8] = hv;
        *(bf16x8*)&wimg[4096 + row * 64 + unit * 8] = lv8;
    }
    if (t < 64) {
        float g = g1[t], be = bb1[t], m = mm1[t], v = vv1[t];
        float s = g * rsqrtf(v + EPS_);
        s1c[t] = s; t1c[t] = be - m * s;
        g = g2[t]; be = bb2[t]; m = mm2[t]; v = vv2[t];
        s = g * rsqrtf(v + EPS_);
        s2c[t] = s; t2c[t] = be - m * s;
    }
    size_t pbase = (size_t)(b * N_ + n0);
    for (int i = t; i < 512; i += 256) {
        int pt = i >> 6, o = i & 63;
        ddl[pt][o] = dd[(pbase + pt) * 64 + o];
    }
    if (t < 8 * K_) {
        int pt = t / K_, k = t % K_;
        il[pt][k] = idxg[(pbase + pt) * K_ + k];
    }
    __syncthreads();

    const float* yAb = yA + (size_t)(b * N_) * 64;
    float4 ga[5][2];
    int gcol[5], goct[5], gpt[5];
#pragma unroll
    for (int rep = 0; rep < 5; ++rep) {
        int j = rep * 256 + t;
        int pt = j / 160;
        int r = j - pt * 160;
        int k = r >> 3, oct = r & 7;
        int m = il[pt][k];
        const float* src = yAb + (size_t)m * 64 + oct * 8;
        ga[rep][0] = *(const float4*)src;
        ga[rep][1] = *(const float4*)(src + 4);
        gcol[rep] = pt * 20 + k; goct[rep] = oct; gpt[rep] = pt;
    }
#pragma unroll
    for (int rep = 0; rep < 5; ++rep) {
        int oct = goct[rep], pt = gpt[rep], col = gcol[rep];
        float yv[8] = {ga[rep][0].x, ga[rep][0].y, ga[rep][0].z, ga[rep][0].w,
                       ga[rep][1].x, ga[rep][1].y, ga[rep][1].z, ga[rep][1].w};
        bf16x8 hv, lv8;
#pragma unroll
        for (int jj = 0; jj < 8; ++jj) {
            int oc = oct * 8 + jj;
            float v = lrelu(s1c[oc] * (yv[jj] + ddl[pt][oc]) + t1c[oc]);
            unsigned short hh = f2bf(v);
            hv[jj] = (short)hh;
            lv8[jj] = (short)f2bf(v - bf2f(hh));
        }
        int unit = oct ^ (col & 7);
        *(bf16x8*)&timgH[col * 64 + unit * 8] = hv;
        *(bf16x8*)&timgL[col * 64 + unit * 8] = lv8;
    }
    __syncthreads();

    int anl = (w << 4) + (lane & 15);
    bf16x8 ah[2], al[2];
#pragma unroll
    for (int kc = 0; kc < 2; ++kc) {
        int unit = (kc * 4 + (lane >> 4)) ^ (anl & 7);
        ah[kc] = *(const bf16x8*)&wimg[anl * 64 + unit * 8];
        al[kc] = *(const bf16x8*)&wimg[4096 + anl * 64 + unit * 8];
    }
    f32x4 acc[10];
#pragma unroll
    for (int nt = 0; nt < 10; ++nt) {
        int col = nt * 16 + (lane & 15);
        int u0 = ((lane >> 4)) ^ (col & 7);
        int u1 = (4 + (lane >> 4)) ^ (col & 7);
        bf16x8 bh0 = *(const bf16x8*)&timgH[col * 64 + u0 * 8];
        bf16x8 bl0 = *(const bf16x8*)&timgL[col * 64 + u0 * 8];
        bf16x8 bh1 = *(const bf16x8*)&timgH[col * 64 + u1 * 8];
        bf16x8 bl1 = *(const bf16x8*)&timgL[col * 64 + u1 * 8];
        f32x4 a = {0.f, 0.f, 0.f, 0.f};
        a = __builtin_amdgcn_mfma_f32_16x16x32_bf16(ah[0], bh0, a, 0, 0, 0);
        a = __builtin_amdgcn_mfma_f32_16x16x32_bf16(ah[0], bl0, a, 0, 0, 0);
        a = __builtin_amdgcn_mfma_f32_16x16x32_bf16(al[0], bh0, a, 0, 0, 0);
        a = __builtin_amdgcn_mfma_f32_16x16x32_bf16(al[0], bl0, a, 0, 0, 0);
        a = __builtin_amdgcn_mfma_f32_16x16x32_bf16(ah[1], bh1, a, 0, 0, 0);
        a = __builtin_amdgcn_mfma_f32_16x16x32_bf16(ah[1], bl1, a, 0, 0, 0);
        a = __builtin_amdgcn_mfma_f32_16x16x32_bf16(al[1], bh1, a, 0, 0, 0);
        a = __builtin_amdgcn_mfma_f32_16x16x32_bf16(al[1], bl1, a, 0, 0, 0);
        acc[nt] = a;
    }
    __syncthreads();

#pragma unroll
    for (int nt = 0; nt < 10; ++nt) {
#pragma unroll
        for (int r = 0; r < 4; ++r)
            ct[((w << 4) + ((lane >> 4) << 2) + r) * 164 + nt * 16 + (lane & 15)] =
                acc[nt][r];
    }
    __syncthreads();

#pragma unroll
    for (int rep = 0; rep < 2; ++rep) {
        int pair = rep * 256 + t;          // 512 (o2,pt) pairs
        int o2 = pair >> 3, pt = pair & 7;
        const float* row = &ct[o2 * 164 + pt * 20];
        float4 c0 = *(const float4*)(row + 0);
        float4 c1 = *(const float4*)(row + 4);
        float4 c2 = *(const float4*)(row + 8);
        float4 c3 = *(const float4*)(row + 12);
        float4 c4 = *(const float4*)(row + 16);
        float mx = fmaxf(fmaxf(fmaxf(c0.x, c0.y), fmaxf(c0.z, c0.w)),
                   fmaxf(fmaxf(fmaxf(c1.x, c1.y), fmaxf(c1.z, c1.w)),
                   fmaxf(fmaxf(fmaxf(c2.x, c2.y), fmaxf(c2.z, c2.w)),
                   fmaxf(fmaxf(fmaxf(c3.x, c3.y), fmaxf(c3.z, c3.w)),
                         fmaxf(fmaxf(c4.x, c4.y), fmaxf(c4.z, c4.w))))));
        hl[pt][o2] = lrelu(s2c[o2] * mx + t2c[o2]);
    }
    __syncthreads();

    float* htb = ht + (size_t)b * 64 * N_;
    for (int i = t; i < 512; i += 256) {
        int o = i >> 3, pt2 = i & 7;
        htb[o * N_ + n0 + pt2] = hl[pt2][o];
    }
}

// ---------------------------------------------------------------------------
// Kernel C2: MLP head 64 -> 256 -> 128 -> 1 per point, 64 points per block
// ---------------------------------------------------------------------------
__global__ void __launch_bounds__(256) k_head(const float* __restrict__ ht,
                                              const float* __restrict__ w1,
                                              const float* __restrict__ g1,
                                              const float* __restrict__ bb1,
                                              const float* __restrict__ mm1,
                                              const float* __restrict__ vv1,
                                              const float* __restrict__ w2,
                                              const float* __restrict__ g2,
                                              const float* __restrict__ bb2,
                                              const float* __restrict__ mm2,
                                              const float* __restrict__ vv2,
                                              const float* __restrict__ w3,
                                              const float* __restrict__ b3,
                                              float* __restrict__ out) {
    __shared__ float hbuf[64][64];
    __shared__ float a1[256][64];
    __shared__ float a2[128][64];
    __shared__ float sA[256], tA[256], sB[128], tB[128];
    int t = threadIdx.x;
    int blk = blockIdx.x;
    int b = blk >> 6;
    int n0 = (blk & 63) << 6;
    const float* htb = ht + (size_t)b * 64 * N_;

    for (int i = 0; i < 16; ++i) {
        int j = i * 256 + t;
        int o = j >> 6, pt = j & 63;
        hbuf[o][pt] = htb[o * N_ + n0 + pt];
    }
    {
        float g = g1[t], be = bb1[t], m = mm1[t], v = vv1[t];
        float s = g * rsqrtf(v + EPS_);
        sA[t] = s; tA[t] = be - m * s;
    }
    if (t < 128) {
        float g = g2[t], be = bb2[t], m = mm2[t], v = vv2[t];
        float s = g * rsqrtf(v + EPS_);
        sB[t] = s; tB[t] = be - m * s;
    }
    __syncthreads();

    int ptg = t & 15, rg = t >> 4;
    int pt4 = ptg << 2;

    for (int ib = 0; ib < 4; ++ib) {
        int r0 = (rg << 4) + (ib << 2);
        float acc[4][4] = {};
        for (int o4 = 0; o4 < 16; ++o4) {
            float hf[4][4];
            for (int c = 0; c < 4; ++c) {
                float4 q = *(const float4*)&hbuf[(o4 << 2) + c][pt4];
                hf[c][0] = q.x; hf[c][1] = q.y; hf[c][2] = q.z; hf[c][3] = q.w;
            }
            for (int j = 0; j < 4; ++j) {
                float4 wv4 = *(const float4*)(w1 + (r0 + j) * 64 + (o4 << 2));
                float wv[4] = {wv4.x, wv4.y, wv4.z, wv4.w};
                for (int c = 0; c < 4; ++c)
                    for (int pp = 0; pp < 4; ++pp)
                        acc[j][pp] += wv[c] * hf[c][pp];
            }
        }
        for (int j = 0; j < 4; ++j) {
            int r = r0 + j;
            float4 ov;
            ov.x = lrelu(sA[r] * acc[j][0] + tA[r]);
            ov.y = lrelu(sA[r] * acc[j][1] + tA[r]);
            ov.z = lrelu(sA[r] * acc[j][2] + tA[r]);
            ov.w = lrelu(sA[r] * acc[j][3] + tA[r]);
            *(float4*)&a1[r][pt4] = ov;
        }
    }
    __syncthreads();

    for (int ib = 0; ib < 2; ++ib) {
        int r0 = (rg << 3) + (ib << 2);
        float acc[4][4] = {};
        for (int p4i = 0; p4i < 64; ++p4i) {
            float af[4][4];
            for (int c = 0; c < 4; ++c) {
                float4 q = *(const float4*)&a1[(p4i << 2) + c][pt4];
                af[c][0] = q.x; af[c][1] = q.y; af[c][2] = q.z; af[c][3] = q.w;
            }
            for (int j = 0; j < 4; ++j) {
                float4 wv4 = *(const float4*)(w2 + (r0 + j) * 256 + (p4i << 2));
                float wv[4] = {wv4.x, wv4.y, wv4.z, wv4.w};
                for (int c = 0; c < 4; ++c)
                    for (int pp = 0; pp < 4; ++pp)
                        acc[j][pp] += wv[c] * af[c][pp];
            }
        }
        for (int j = 0; j < 4; ++j) {
            int r = r0 + j;
            float4 ov;
            ov.x = lrelu(sB[r] * acc[j][0] + tB[r]);
            ov.y = lrelu(sB[r] * acc[j][1] + tB[r]);
            ov.z = lrelu(sB[r] * acc[j][2] + tB[r]);
            ov.w = lrelu(sB[r] * acc[j][3] + tB[r]);
            *(float4*)&a2[r][pt4] = ov;
        }
    }
    __syncthreads();

    if (t < 64) {
        float accv = 0.f;
        for (int q = 0; q < 128; ++q) accv += w3[q] * a2[q][t];
        accv += b3[0];
        out[b * N_ + n0 + t] = accv;
    }
}

// ---------------------------------------------------------------------------
extern "C" void kernel_launch(void* const* d_in, const int* in_sizes, int n_in,
                              void* d_out, int out_size, void* d_ws, size_t ws_size,
                              hipStream_t stream) {
    (void)in_sizes; (void)n_in; (void)out_size; (void)ws_size;
    const float* x    = (const float*)d_in[0];
    const float* wk1  = (const float*)d_in[1];
    const float* gk1  = (const float*)d_in[2];
    const float* bk1  = (const float*)d_in[3];
    const float* mk1  = (const float*)d_in[4];
    const float* vk1  = (const float*)d_in[5];
    const float* wk2  = (const float*)d_in[6];
    const float* gk2  = (const float*)d_in[7];
    const float* bk2  = (const float*)d_in[8];
    const float* mk2  = (const float*)d_in[9];
    const float* vk2  = (const float*)d_in[10];
    const float* w1   = (const float*)d_in[11];
    const float* g1   = (const float*)d_in[12];
    const float* b1   = (const float*)d_in[13];
    const float* m1   = (const float*)d_in[14];
    const float* v1   = (const float*)d_in[15];
    const float* w2   = (const float*)d_in[16];
    const float* g2   = (const float*)d_in[17];
    const float* b2   = (const float*)d_in[18];
    const float* m2   = (const float*)d_in[19];
    const float* v2   = (const float*)d_in[20];
    const float* w3   = (const float*)d_in[21];
    const float* b3   = (const float*)d_in[22];

    char* ws = (char*)d_ws;
    float* yA  = (float*)(ws);                       //  8 MB
    float* dd  = (float*)(ws + 8388608);             //  8 MB
    float* xx  = (float*)(ws + 16777216);            //  128 KB
    int*   idx = (int*)  (ws + 16908288);            //  2.5 MB
    float* ht  = (float*)(ws + 19529728);            //  8 MB
    unsigned short* xps = (unsigned short*)(ws + 27918336);  // 8 MB split-bf16 images

    k_pre <<<B_ * (N_ / 64), 256, 0, stream>>>(x, wk1, yA, dd, xx, xps);
    k_topk<<<B_ * (N_ / 32), 512, 0, stream>>>(xps, xx, idx);
    k_edge<<<B_ * (N_ / 8),  256, 0, stream>>>(yA, dd, idx, wk2,
                                               gk1, bk1, mk1, vk1,
                                               gk2, bk2, mk2, vk2, ht);
    k_head<<<B_ * (N_ / 64), 256, 0, stream>>>(ht, w1, g1, b1, m1, v1,
                                               w2, g2, b2, m2, v2, w3, b3,
                                               (float*)d_out);
}

// Round 14
// 301.329 us; speedup vs baseline: 5.7184x; 1.1330x over previous
//
#include <hip/hip_runtime.h>
#include <hip/hip_bf16.h>

#define B_ 8
#define C_ 64
#define N_ 4096
#define K_ 20
#define EPS_ 1e-5f
#define SLOPE_ 0.2f

typedef __attribute__((ext_vector_type(8))) short bf16x8;
typedef __attribute__((ext_vector_type(4))) float f32x4;

__device__ __forceinline__ float lrelu(float x) { return x >= 0.f ? x : SLOPE_ * x; }
__device__ __forceinline__ float bf2f(unsigned short u) {
    return __uint_as_float(((unsigned int)u) << 16);
}
__device__ __forceinline__ unsigned short f2bf(float f) {
    unsigned int u = __float_as_uint(f);
    return (unsigned short)((u + 0x7FFFu + ((u >> 16) & 1u)) >> 16);
}

__device__ __forceinline__ float rdlanef(float x, int l) {
    return __int_as_float(__builtin_amdgcn_readlane(__float_as_int(x), l));
}

// split 8 floats into hi/lo bf16x8
__device__ __forceinline__ void split8(const float* v, bf16x8& h, bf16x8& l) {
#pragma unroll
    for (int j = 0; j < 8; ++j) {
        unsigned short hh = f2bf(v[j]);
        h[j] = (short)hh;
        l[j] = (short)f2bf(v[j] - bf2f(hh));
    }
}

// ---------------------------------------------------------------------------
// Kernel A (MFMA): Y[128x64] = [wA;wB] @ xs via split-bf16 MFMA.
// yA = rows 0..63; dd = rows 64..127 - rows 0..63. Also xx and xps images.
// grid 512 (B * N/64), block 256
// ---------------------------------------------------------------------------
__global__ void __launch_bounds__(256) k_pre(const float* __restrict__ x,
                                             const float* __restrict__ wk1,
                                             float* __restrict__ yA,
                                             float* __restrict__ dd,
                                             float* __restrict__ xx,
                                             unsigned short* __restrict__ xps) {
    __shared__ float xs[64][64];
    __shared__ unsigned short wimg[16384];
    __shared__ unsigned short ximg[8192];
    int t = threadIdx.x;
    int lane = t & 63;
    int w = t >> 6;
    int blk = blockIdx.x;
    int b = blk >> 6;
    int n0 = (blk & 63) << 6;

    const float* xb = x + (size_t)b * C_ * N_;
    for (int i = 0; i < 4; ++i) {
        int j = i * 256 + t;
        int c = j >> 4;
        int p4 = (j & 15) << 2;
        float4 v = *(const float4*)(xb + c * N_ + n0 + p4);
        xs[c][p4 + 0] = v.x; xs[c][p4 + 1] = v.y;
        xs[c][p4 + 2] = v.z; xs[c][p4 + 3] = v.w;
    }
    for (int rep = 0; rep < 4; ++rep) {
        int i = rep * 256 + t;
        int m = i >> 3, oct = i & 7;
        const float* src = wk1 + (m & 63) * 128 + ((m >> 6) << 6) + oct * 8;
        float4 a4 = *(const float4*)src;
        float4 b4 = *(const float4*)(src + 4);
        float wv[8] = {a4.x, a4.y, a4.z, a4.w, b4.x, b4.y, b4.z, b4.w};
        bf16x8 hv, lv8;
        split8(wv, hv, lv8);
        int unit = oct ^ (m & 7);
        *(bf16x8*)&wimg[m * 64 + unit * 8] = hv;
        *(bf16x8*)&wimg[8192 + m * 64 + unit * 8] = lv8;
    }
    __syncthreads();

    if (t < 64) {
        float s = 0.f;
        for (int c = 0; c < 64; ++c) { float xv = xs[c][t]; s += xv * xv; }
        xx[b * N_ + n0 + t] = s;
    }

    unsigned short* xc = xps + ((size_t)(b * 64 + (blk & 63))) * 8192;
#pragma unroll
    for (int q = 0; q < 2; ++q) {
        int i = q * 256 + t;
        int nl = i >> 3, oct = i & 7;
        float wv[8];
#pragma unroll
        for (int j = 0; j < 8; ++j) wv[j] = xs[oct * 8 + j][nl];
        bf16x8 hv, lv8;
        split8(wv, hv, lv8);
        int unit = oct ^ (nl & 7);
        *(bf16x8*)&ximg[nl * 64 + unit * 8] = hv;
        *(bf16x8*)&ximg[4096 + nl * 64 + unit * 8] = lv8;
        *(bf16x8*)&xc[nl * 64 + unit * 8] = hv;
        *(bf16x8*)&xc[4096 + nl * 64 + unit * 8] = lv8;
    }
    __syncthreads();

    int mA = (w << 4) + (lane & 15);
    int mB = ((w + 4) << 4) + (lane & 15);
    bf16x8 ahA[2], alA[2], ahB[2], alB[2];
#pragma unroll
    for (int kc = 0; kc < 2; ++kc) {
        int uA = (kc * 4 + (lane >> 4)) ^ (mA & 7);
        int uB = (kc * 4 + (lane >> 4)) ^ (mB & 7);
        ahA[kc] = *(const bf16x8*)&wimg[mA * 64 + uA * 8];
        alA[kc] = *(const bf16x8*)&wimg[8192 + mA * 64 + uA * 8];
        ahB[kc] = *(const bf16x8*)&wimg[mB * 64 + uB * 8];
        alB[kc] = *(const bf16x8*)&wimg[8192 + mB * 64 + uB * 8];
    }
    size_t pbase = (size_t)(b * N_ + n0);
#pragma unroll
    for (int nt = 0; nt < 4; ++nt) {
        int p = nt * 16 + (lane & 15);
        int u0 = ((lane >> 4)) ^ (p & 7);
        int u1 = (4 + (lane >> 4)) ^ (p & 7);
        bf16x8 bh0 = *(const bf16x8*)&ximg[p * 64 + u0 * 8];
        bf16x8 bl0 = *(const bf16x8*)&ximg[4096 + p * 64 + u0 * 8];
        bf16x8 bh1 = *(const bf16x8*)&ximg[p * 64 + u1 * 8];
        bf16x8 bl1 = *(const bf16x8*)&ximg[4096 + p * 64 + u1 * 8];
        f32x4 aA = {0.f, 0.f, 0.f, 0.f};
        aA = __builtin_amdgcn_mfma_f32_16x16x32_bf16(ahA[0], bh0, aA, 0, 0, 0);
        aA = __builtin_amdgcn_mfma_f32_16x16x32_bf16(ahA[0], bl0, aA, 0, 0, 0);
        aA = __builtin_amdgcn_mfma_f32_16x16x32_bf16(alA[0], bh0, aA, 0, 0, 0);
        aA = __builtin_amdgcn_mfma_f32_16x16x32_bf16(alA[0], bl0, aA, 0, 0, 0);
        aA = __builtin_amdgcn_mfma_f32_16x16x32_bf16(ahA[1], bh1, aA, 0, 0, 0);
        aA = __builtin_amdgcn_mfma_f32_16x16x32_bf16(ahA[1], bl1, aA, 0, 0, 0);
        aA = __builtin_amdgcn_mfma_f32_16x16x32_bf16(alA[1], bh1, aA, 0, 0, 0);
        aA = __builtin_amdgcn_mfma_f32_16x16x32_bf16(alA[1], bl1, aA, 0, 0, 0);
        f32x4 aB = {0.f, 0.f, 0.f, 0.f};
        aB = __builtin_amdgcn_mfma_f32_16x16x32_bf16(ahB[0], bh0, aB, 0, 0, 0);
        aB = __builtin_amdgcn_mfma_f32_16x16x32_bf16(ahB[0], bl0, aB, 0, 0, 0);
        aB = __builtin_amdgcn_mfma_f32_16x16x32_bf16(alB[0], bh0, aB, 0, 0, 0);
        aB = __builtin_amdgcn_mfma_f32_16x16x32_bf16(alB[0], bl0, aB, 0, 0, 0);
        aB = __builtin_amdgcn_mfma_f32_16x16x32_bf16(ahB[1], bh1, aB, 0, 0, 0);
        aB = __builtin_amdgcn_mfma_f32_16x16x32_bf16(ahB[1], bl1, aB, 0, 0, 0);
        aB = __builtin_amdgcn_mfma_f32_16x16x32_bf16(alB[1], bh1, aB, 0, 0, 0);
        aB = __builtin_amdgcn_mfma_f32_16x16x32_bf16(alB[1], bl1, aB, 0, 0, 0);

        int obase = (w << 4) + ((lane >> 4) << 2);
        float4 ya4 = {aA[0], aA[1], aA[2], aA[3]};
        float4 dd4 = {aB[0] - aA[0], aB[1] - aA[1], aB[2] - aA[2], aB[3] - aA[3]};
        *(float4*)(yA + (pbase + p) * 64 + obase) = ya4;
        *(float4*)(dd + (pbase + p) * 64 + obase) = dd4;
    }
}

// ---------------------------------------------------------------------------
// Kernel B: top-20 neighbors (unchanged from round 13 — proven)
// ---------------------------------------------------------------------------
__global__ void __launch_bounds__(512) k_topk(const unsigned short* __restrict__ xps,
                                              const float* __restrict__ xx,
                                              int* __restrict__ idxg) {
    __shared__ float sc[2][32][68];
    int t = threadIdx.x;
    int lane = t & 63;
    int w = t >> 6;
    int wr = w >> 2;
    int wc = w & 3;
    int blk = blockIdx.x;
    int b = blk >> 7;
    int n0 = (blk & 127) << 5;
    int bc = b << 6;
    const float* xxb = xx + b * N_;
    int pa = ((lane + 1) & 63) << 2;

    const unsigned short* xcA = xps + ((size_t)(bc + ((blk & 127) >> 1))) * 8192;
    int anl = ((blk & 1) << 5) + (wr << 4) + (lane & 15);
    bf16x8 ah[2], al[2];
#pragma unroll
    for (int kc = 0; kc < 2; ++kc) {
        int unit = (kc * 4 + (lane >> 4)) ^ (anl & 7);
        ah[kc] = *(const bf16x8*)&xcA[anl * 64 + unit * 8];
        al[kc] = *(const bf16x8*)&xcA[4096 + anl * 64 + unit * 8];
    }

    int n_ = (wc << 4) + (lane & 15);
    int off0 = n_ * 64 + (((lane >> 4)) ^ (n_ & 7)) * 8;
    int off1 = n_ * 64 + ((4 + (lane >> 4)) ^ (n_ & 7)) * 8;

    float lv[4];
    int   li[4];
#pragma unroll
    for (int i = 0; i < 4; ++i) { lv[i] = -3.0e38f; li[i] = 0; }

    auto ins = [&](float& lvr, int& lir, float s, int m0) {
        float mnc = rdlanef(lvr, 19);
        unsigned long long mask = __ballot(s > mnc);
        while (mask) {
            int j = (int)__builtin_ctzll(mask);
            mask &= mask - 1;
            float sv = rdlanef(s, j);
            unsigned long long gt = __ballot(lane < 20 && lvr > sv);
            int cpos = __popcll(gt);
            float upv = __int_as_float(
                __builtin_amdgcn_ds_permute(pa, __float_as_int(lvr)));
            int   upi = __builtin_amdgcn_ds_permute(pa, lir);
            if (lane >= cpos && lane < 20) {
                lvr = (lane == cpos) ? sv : upv;
                lir = (lane == cpos) ? (m0 + j) : upi;
            }
        }
    };

    const unsigned short* xcB = xps + (size_t)bc * 8192;
    bf16x8 bh0 = *(const bf16x8*)&xcB[off0];
    bf16x8 bl0 = *(const bf16x8*)&xcB[4096 + off0];
    bf16x8 bh1 = *(const bf16x8*)&xcB[off1];
    bf16x8 bl1 = *(const bf16x8*)&xcB[4096 + off1];
    float xxv = xxb[n_];

    for (int mc = 0; mc < 64; ++mc) {
        f32x4 acc = {0.f, 0.f, 0.f, 0.f};
        acc = __builtin_amdgcn_mfma_f32_16x16x32_bf16(ah[0], bh0, acc, 0, 0, 0);
        acc = __builtin_amdgcn_mfma_f32_16x16x32_bf16(ah[0], bl0, acc, 0, 0, 0);
        acc = __builtin_amdgcn_mfma_f32_16x16x32_bf16(al[0], bh0, acc, 0, 0, 0);
        acc = __builtin_amdgcn_mfma_f32_16x16x32_bf16(al[0], bl0, acc, 0, 0, 0);
        acc = __builtin_amdgcn_mfma_f32_16x16x32_bf16(ah[1], bh1, acc, 0, 0, 0);
        acc = __builtin_amdgcn_mfma_f32_16x16x32_bf16(ah[1], bl1, acc, 0, 0, 0);
        acc = __builtin_amdgcn_mfma_f32_16x16x32_bf16(al[1], bh1, acc, 0, 0, 0);
        acc = __builtin_amdgcn_mfma_f32_16x16x32_bf16(al[1], bl1, acc, 0, 0, 0);

#pragma unroll
        for (int r = 0; r < 4; ++r)
            sc[mc & 1][(wr << 4) + ((lane >> 4) << 2) + r][n_] = 2.f * acc[r] - xxv;

        if (mc + 1 < 64) {
            const unsigned short* xn2 = xps + (size_t)(bc + mc + 1) * 8192;
            bh0 = *(const bf16x8*)&xn2[off0];
            bl0 = *(const bf16x8*)&xn2[4096 + off0];
            bh1 = *(const bf16x8*)&xn2[off1];
            bl1 = *(const bf16x8*)&xn2[4096 + off1];
            xxv = xxb[((mc + 1) << 6) + n_];
        }

        if (mc > 0) {
            int m0p = (mc - 1) << 6;
#pragma unroll
            for (int i = 0; i < 4; ++i) {
                int lrow = (w << 2) + i;
                float s = sc[(mc - 1) & 1][lrow][lane];
                ins(lv[i], li[i], s, m0p);
            }
        }
        __syncthreads();
    }

    {
        int m0p = 63 << 6;
#pragma unroll
        for (int i = 0; i < 4; ++i) {
            int lrow = (w << 2) + i;
            float s = sc[1][lrow][lane];
            ins(lv[i], li[i], s, m0p);
        }
    }

#pragma unroll
    for (int i = 0; i < 4; ++i) {
        int n = n0 + (w << 2) + i;
        if (lane < K_)
            idxg[((size_t)(b * N_ + n)) * K_ + lane] = li[i];
    }
}

// ---------------------------------------------------------------------------
// Kernel C1 (MFMA): gather+BN1 -> split-bf16 images -> MFMA GEMM
// (unchanged from round 12/13 — proven)
// ---------------------------------------------------------------------------
__global__ void __launch_bounds__(256) k_edge(const float* __restrict__ yA,
                                              const float* __restrict__ dd,
                                              const int* __restrict__ idxg,
                                              const float* __restrict__ wk2,
                                              const float* __restrict__ g1,
                                              const float* __restrict__ bb1,
                                              const float* __restrict__ mm1,
                                              const float* __restrict__ vv1,
                                              const float* __restrict__ g2,
                                              const float* __restrict__ bb2,
                                              const float* __restrict__ mm2,
                                              const float* __restrict__ vv2,
                                              float* __restrict__ ht) {
    __shared__ unsigned short wimg[8192];
    __shared__ float ubuf[64 * 164];
    __shared__ float s1c[64], t1c[64], s2c[64], t2c[64];
    __shared__ float ddl[8][64];
    __shared__ int   il[8][K_];
    __shared__ float hl[8][64];
    unsigned short* timgH = (unsigned short*)ubuf;
    unsigned short* timgL = timgH + 160 * 64;
    float* ct = ubuf;

    int t = threadIdx.x;
    int lane = t & 63;
    int w = t >> 6;
    int blk = blockIdx.x;
    int b = blk >> 9;
    int n0 = (blk & 511) << 3;

    for (int rep = 0; rep < 2; ++rep) {
        int i = rep * 256 + t;
        int row = i >> 3, oct = i & 7;
        float4 wa = *(const float4*)(wk2 + row * 64 + oct * 8);
        float4 wb = *(const float4*)(wk2 + row * 64 + oct * 8 + 4);
        float wv[8] = {wa.x, wa.y, wa.z, wa.w, wb.x, wb.y, wb.z, wb.w};
        bf16x8 hv, lv8;
        split8(wv, hv, lv8);
        int unit = oct ^ (row & 7);
        *(bf16x8*)&wimg[row * 64 + unit * 8] = hv;
        *(bf16x8*)&wimg[4096 + row * 64 + unit * 8] = lv8;
    }
    if (t < 64) {
        float g = g1[t], be = bb1[t], m = mm1[t], v = vv1[t];
        float s = g * rsqrtf(v + EPS_);
        s1c[t] = s; t1c[t] = be - m * s;
        g = g2[t]; be = bb2[t]; m = mm2[t]; v = vv2[t];
        s = g * rsqrtf(v + EPS_);
        s2c[t] = s; t2c[t] = be - m * s;
    }
    size_t pbase = (size_t)(b * N_ + n0);
    for (int i = t; i < 512; i += 256) {
        int pt = i >> 6, o = i & 63;
        ddl[pt][o] = dd[(pbase + pt) * 64 + o];
    }
    if (t < 8 * K_) {
        int pt = t / K_, k = t % K_;
        il[pt][k] = idxg[(pbase + pt) * K_ + k];
    }
    __syncthreads();

    const float* yAb = yA + (size_t)(b * N_) * 64;
    float4 ga[5][2];
    int gcol[5], goct[5], gpt[5];
#pragma unroll
    for (int rep = 0; rep < 5; ++rep) {
        int j = rep * 256 + t;
        int pt = j / 160;
        int r = j - pt * 160;
        int k = r >> 3, oct = r & 7;
        int m = il[pt][k];
        const float* src = yAb + (size_t)m * 64 + oct * 8;
        ga[rep][0] = *(const float4*)src;
        ga[rep][1] = *(const float4*)(src + 4);
        gcol[rep] = pt * 20 + k; goct[rep] = oct; gpt[rep] = pt;
    }
#pragma unroll
    for (int rep = 0; rep < 5; ++rep) {
        int oct = goct[rep], pt = gpt[rep], col = gcol[rep];
        float yv[8] = {ga[rep][0].x, ga[rep][0].y, ga[rep][0].z, ga[rep][0].w,
                       ga[rep][1].x, ga[rep][1].y, ga[rep][1].z, ga[rep][1].w};
        float tv[8];
#pragma unroll
        for (int jj = 0; jj < 8; ++jj) {
            int oc = oct * 8 + jj;
            tv[jj] = lrelu(s1c[oc] * (yv[jj] + ddl[pt][oc]) + t1c[oc]);
        }
        bf16x8 hv, lv8;
        split8(tv, hv, lv8);
        int unit = oct ^ (col & 7);
        *(bf16x8*)&timgH[col * 64 + unit * 8] = hv;
        *(bf16x8*)&timgL[col * 64 + unit * 8] = lv8;
    }
    __syncthreads();

    int anl = (w << 4) + (lane & 15);
    bf16x8 ah[2], al[2];
#pragma unroll
    for (int kc = 0; kc < 2; ++kc) {
        int unit = (kc * 4 + (lane >> 4)) ^ (anl & 7);
        ah[kc] = *(const bf16x8*)&wimg[anl * 64 + unit * 8];
        al[kc] = *(const bf16x8*)&wimg[4096 + anl * 64 + unit * 8];
    }
    f32x4 acc[10];
#pragma unroll
    for (int nt = 0; nt < 10; ++nt) {
        int col = nt * 16 + (lane & 15);
        int u0 = ((lane >> 4)) ^ (col & 7);
        int u1 = (4 + (lane >> 4)) ^ (col & 7);
        bf16x8 bh0 = *(const bf16x8*)&timgH[col * 64 + u0 * 8];
        bf16x8 bl0 = *(const bf16x8*)&timgL[col * 64 + u0 * 8];
        bf16x8 bh1 = *(const bf16x8*)&timgH[col * 64 + u1 * 8];
        bf16x8 bl1 = *(const bf16x8*)&timgL[col * 64 + u1 * 8];
        f32x4 a = {0.f, 0.f, 0.f, 0.f};
        a = __builtin_amdgcn_mfma_f32_16x16x32_bf16(ah[0], bh0, a, 0, 0, 0);
        a = __builtin_amdgcn_mfma_f32_16x16x32_bf16(ah[0], bl0, a, 0, 0, 0);
        a = __builtin_amdgcn_mfma_f32_16x16x32_bf16(al[0], bh0, a, 0, 0, 0);
        a = __builtin_amdgcn_mfma_f32_16x16x32_bf16(al[0], bl0, a, 0, 0, 0);
        a = __builtin_amdgcn_mfma_f32_16x16x32_bf16(ah[1], bh1, a, 0, 0, 0);
        a = __builtin_amdgcn_mfma_f32_16x16x32_bf16(ah[1], bl1, a, 0, 0, 0);
        a = __builtin_amdgcn_mfma_f32_16x16x32_bf16(al[1], bh1, a, 0, 0, 0);
        a = __builtin_amdgcn_mfma_f32_16x16x32_bf16(al[1], bl1, a, 0, 0, 0);
        acc[nt] = a;
    }
    __syncthreads();

#pragma unroll
    for (int nt = 0; nt < 10; ++nt) {
#pragma unroll
        for (int r = 0; r < 4; ++r)
            ct[((w << 4) + ((lane >> 4) << 2) + r) * 164 + nt * 16 + (lane & 15)] =
                acc[nt][r];
    }
    __syncthreads();

#pragma unroll
    for (int rep = 0; rep < 2; ++rep) {
        int pair = rep * 256 + t;
        int o2 = pair >> 3, pt = pair & 7;
        const float* row = &ct[o2 * 164 + pt * 20];
        float4 c0 = *(const float4*)(row + 0);
        float4 c1 = *(const float4*)(row + 4);
        float4 c2 = *(const float4*)(row + 8);
        float4 c3 = *(const float4*)(row + 12);
        float4 c4 = *(const float4*)(row + 16);
        float mx = fmaxf(fmaxf(fmaxf(c0.x, c0.y), fmaxf(c0.z, c0.w)),
                   fmaxf(fmaxf(fmaxf(c1.x, c1.y), fmaxf(c1.z, c1.w)),
                   fmaxf(fmaxf(fmaxf(c2.x, c2.y), fmaxf(c2.z, c2.w)),
                   fmaxf(fmaxf(fmaxf(c3.x, c3.y), fmaxf(c3.z, c3.w)),
                         fmaxf(fmaxf(c4.x, c4.y), fmaxf(c4.z, c4.w))))));
        hl[pt][o2] = lrelu(s2c[o2] * mx + t2c[o2]);
    }
    __syncthreads();

    float* htb = ht + (size_t)b * 64 * N_;
    for (int i = t; i < 512; i += 256) {
        int o = i >> 3, pt2 = i & 7;
        htb[o * N_ + n0 + pt2] = hl[pt2][o];
    }
}

// ---------------------------------------------------------------------------
// Kernel C2 (MFMA rewrite): head 64 -> 256 -> 128 -> 1 per point.
// Stage A (W1@h) and B (W2@a1) as split-bf16 MFMA; h as hi/lo bf16 image
// [pt][72]; a1 fp32 in LDS [pt][132], computed in 2 K-halves (ka);
// stage C (w3 . a2) from registers via shfl_xor. grid 512, block 256.
// ---------------------------------------------------------------------------
__global__ void __launch_bounds__(256) k_head(const float* __restrict__ ht,
                                              const float* __restrict__ w1,
                                              const float* __restrict__ g1,
                                              const float* __restrict__ bb1,
                                              const float* __restrict__ mm1,
                                              const float* __restrict__ vv1,
                                              const float* __restrict__ w2,
                                              const float* __restrict__ g2,
                                              const float* __restrict__ bb2,
                                              const float* __restrict__ mm2,
                                              const float* __restrict__ vv2,
                                              const float* __restrict__ w3,
                                              const float* __restrict__ b3,
                                              float* __restrict__ out) {
    __shared__ unsigned int himgH[64 * 36];   // [pt][36 u32] = 72 bf16 ch (pad 8)
    __shared__ unsigned int himgL[64 * 36];
    __shared__ float a1f[64 * 132];           // [pt][132] fp32, current 128-row half
    __shared__ float sA[256], tA[256], sB[128], tB[128], w3s[128];
    __shared__ float outp[4][64];
    int t = threadIdx.x;
    int lane = t & 63;
    int w = t >> 6;
    int blk = blockIdx.x;
    int b = blk >> 6;
    int n0 = (blk & 63) << 6;
    const float* htb = ht + (size_t)b * 64 * N_;

    // ---- load h (coalesced) -> hi/lo bf16 image [pt][ch]
#pragma unroll
    for (int rep = 0; rep < 8; ++rep) {
        int i = rep * 256 + t;                // 2048 ch-pairs
        int pt = i & 63, op = i >> 6;         // op = ch pair 0..31
        float v0 = htb[(2 * op) * N_ + n0 + pt];
        float v1 = htb[(2 * op + 1) * N_ + n0 + pt];
        unsigned short h0 = f2bf(v0), h1 = f2bf(v1);
        unsigned short l0 = f2bf(v0 - bf2f(h0)), l1 = f2bf(v1 - bf2f(h1));
        himgH[pt * 36 + op] = (unsigned int)h0 | ((unsigned int)h1 << 16);
        himgL[pt * 36 + op] = (unsigned int)l0 | ((unsigned int)l1 << 16);
    }
    {
        float g = g1[t], be = bb1[t], m = mm1[t], v = vv1[t];
        float s = g * rsqrtf(v + EPS_);
        sA[t] = s; tA[t] = be - m * s;
    }
    if (t < 128) {
        float g = g2[t], be = bb2[t], m = mm2[t], v = vv2[t];
        float s = g * rsqrtf(v + EPS_);
        sB[t] = s; tB[t] = be - m * s;
        w3s[t] = w3[t];
    }
    __syncthreads();

    f32x4 acc2[2][4];                          // [mt2][nt] persists across ka
#pragma unroll
    for (int i = 0; i < 2; ++i)
#pragma unroll
        for (int j = 0; j < 4; ++j) acc2[i][j] = (f32x4){0.f, 0.f, 0.f, 0.f};

    for (int ka = 0; ka < 2; ++ka) {
        // ======== stage A half: a1 rows 128*ka .. +127 ========
        // A-frags: W1 rows (global fp32 -> split)
        bf16x8 wh[2][2], wl[2][2];             // [mtl2][kc]
#pragma unroll
        for (int mtl2 = 0; mtl2 < 2; ++mtl2) {
            int mabs = 128 * ka + ((2 * w + mtl2) << 4) + (lane & 15);
#pragma unroll
            for (int kc = 0; kc < 2; ++kc) {
                const float* p = w1 + mabs * 64 + kc * 32 + ((lane >> 4) << 3);
                float4 q0 = *(const float4*)p;
                float4 q1 = *(const float4*)(p + 4);
                float vv8[8] = {q0.x, q0.y, q0.z, q0.w, q1.x, q1.y, q1.z, q1.w};
                split8(vv8, wh[mtl2][kc], wl[mtl2][kc]);
            }
        }
#pragma unroll
        for (int nt = 0; nt < 4; ++nt) {
            int pt = (nt << 4) + (lane & 15);
            f32x4 aAcc[2] = {{0.f, 0.f, 0.f, 0.f}, {0.f, 0.f, 0.f, 0.f}};
#pragma unroll
            for (int kc = 0; kc < 2; ++kc) {
                int chb = kc * 32 + ((lane >> 4) << 3);   // multiple of 8
                bf16x8 bh = *(const bf16x8*)((const unsigned short*)himgH + pt * 72 + chb);
                bf16x8 bl = *(const bf16x8*)((const unsigned short*)himgL + pt * 72 + chb);
#pragma unroll
                for (int mtl2 = 0; mtl2 < 2; ++mtl2) {
                    aAcc[mtl2] = __builtin_amdgcn_mfma_f32_16x16x32_bf16(wh[mtl2][kc], bh, aAcc[mtl2], 0, 0, 0);
                    aAcc[mtl2] = __builtin_amdgcn_mfma_f32_16x16x32_bf16(wh[mtl2][kc], bl, aAcc[mtl2], 0, 0, 0);
                    aAcc[mtl2] = __builtin_amdgcn_mfma_f32_16x16x32_bf16(wl[mtl2][kc], bh, aAcc[mtl2], 0, 0, 0);
                    aAcc[mtl2] = __builtin_amdgcn_mfma_f32_16x16x32_bf16(wl[mtl2][kc], bl, aAcc[mtl2], 0, 0, 0);
                }
            }
            // epilogue: BN1h + lrelu -> a1f[pt][klocal]
#pragma unroll
            for (int mtl2 = 0; mtl2 < 2; ++mtl2) {
                int klocal = ((2 * w + mtl2) << 4) + ((lane >> 4) << 2);
                int rabs = 128 * ka + klocal;
                float4 ov;
                ov.x = lrelu(sA[rabs + 0] * aAcc[mtl2][0] + tA[rabs + 0]);
                ov.y = lrelu(sA[rabs + 1] * aAcc[mtl2][1] + tA[rabs + 1]);
                ov.z = lrelu(sA[rabs + 2] * aAcc[mtl2][2] + tA[rabs + 2]);
                ov.w = lrelu(sA[rabs + 3] * aAcc[mtl2][3] + tA[rabs + 3]);
                *(float4*)&a1f[pt * 132 + klocal] = ov;
            }
        }
        __syncthreads();   // a1f half complete

        // ======== stage B partial: Y2 += W2[:, half] @ a1f ========
#pragma unroll
        for (int kc2 = 0; kc2 < 4; ++kc2) {
            // A-frags: W2 (global fp32 -> split)
            bf16x8 ah2[2], al2[2];
#pragma unroll
            for (int mt2 = 0; mt2 < 2; ++mt2) {
                int oabs = (w << 5) + (mt2 << 4) + (lane & 15);
                const float* p = w2 + oabs * 256 + 128 * ka + kc2 * 32 + ((lane >> 4) << 3);
                float4 q0 = *(const float4*)p;
                float4 q1 = *(const float4*)(p + 4);
                float vv8[8] = {q0.x, q0.y, q0.z, q0.w, q1.x, q1.y, q1.z, q1.w};
                split8(vv8, ah2[mt2], al2[mt2]);
            }
#pragma unroll
            for (int nt = 0; nt < 4; ++nt) {
                int pt = (nt << 4) + (lane & 15);
                int kl = kc2 * 32 + ((lane >> 4) << 3);
                float4 q0 = *(const float4*)&a1f[pt * 132 + kl];
                float4 q1 = *(const float4*)&a1f[pt * 132 + kl + 4];
                float vv8[8] = {q0.x, q0.y, q0.z, q0.w, q1.x, q1.y, q1.z, q1.w};
                bf16x8 bh, bl;
                split8(vv8, bh, bl);
#pragma unroll
                for (int mt2 = 0; mt2 < 2; ++mt2) {
                    acc2[mt2][nt] = __builtin_amdgcn_mfma_f32_16x16x32_bf16(ah2[mt2], bh, acc2[mt2][nt], 0, 0, 0);
                    acc2[mt2][nt] = __builtin_amdgcn_mfma_f32_16x16x32_bf16(ah2[mt2], bl, acc2[mt2][nt], 0, 0, 0);
                    acc2[mt2][nt] = __builtin_amdgcn_mfma_f32_16x16x32_bf16(al2[mt2], bh, acc2[mt2][nt], 0, 0, 0);
                    acc2[mt2][nt] = __builtin_amdgcn_mfma_f32_16x16x32_bf16(al2[mt2], bl, acc2[mt2][nt], 0, 0, 0);
                }
            }
        }
        __syncthreads();   // a1f consumed; safe to overwrite next ka
    }

    // ======== stage C: out = w3 . lrelu(BN2h(Y2)) + b3 ========
    float part[4] = {0.f, 0.f, 0.f, 0.f};
#pragma unroll
    for (int mt2 = 0; mt2 < 2; ++mt2) {
        int ob = (w << 5) + (mt2 << 4) + ((lane >> 4) << 2);
#pragma unroll
        for (int nt = 0; nt < 4; ++nt) {
#pragma unroll
            for (int r = 0; r < 4; ++r) {
                int o = ob + r;
                float a2v = lrelu(sB[o] * acc2[mt2][nt][r] + tB[o]);
                part[nt] += w3s[o] * a2v;
            }
        }
    }
#pragma unroll
    for (int nt = 0; nt < 4; ++nt) {
        part[nt] += __shfl_xor(part[nt], 16);
        part[nt] += __shfl_xor(part[nt], 32);
    }
    if (lane < 16) {
#pragma unroll
        for (int nt = 0; nt < 4; ++nt)
            outp[w][(nt << 4) + lane] = part[nt];
    }
    __syncthreads();
    if (t < 64)
        out[b * N_ + n0 + t] = outp[0][t] + outp[1][t] + outp[2][t] + outp[3][t] + b3[0];
}

// ---------------------------------------------------------------------------
extern "C" void kernel_launch(void* const* d_in, const int* in_sizes, int n_in,
                              void* d_out, int out_size, void* d_ws, size_t ws_size,
                              hipStream_t stream) {
    (void)in_sizes; (void)n_in; (void)out_size; (void)ws_size;
    const float* x    = (const float*)d_in[0];
    const float* wk1  = (const float*)d_in[1];
    const float* gk1  = (const float*)d_in[2];
    const float* bk1  = (const float*)d_in[3];
    const float* mk1  = (const float*)d_in[4];
    const float* vk1  = (const float*)d_in[5];
    const float* wk2  = (const float*)d_in[6];
    const float* gk2  = (const float*)d_in[7];
    const float* bk2  = (const float*)d_in[8];
    const float* mk2  = (const float*)d_in[9];
    const float* vk2  = (const float*)d_in[10];
    const float* w1   = (const float*)d_in[11];
    const float* g1   = (const float*)d_in[12];
    const float* b1   = (const float*)d_in[13];
    const float* m1   = (const float*)d_in[14];
    const float* v1   = (const float*)d_in[15];
    const float* w2   = (const float*)d_in[16];
    const float* g2   = (const float*)d_in[17];
    const float* b2   = (const float*)d_in[18];
    const float* m2   = (const float*)d_in[19];
    const float* v2   = (const float*)d_in[20];
    const float* w3   = (const float*)d_in[21];
    const float* b3   = (const float*)d_in[22];

    char* ws = (char*)d_ws;
    float* yA  = (float*)(ws);                       //  8 MB
    float* dd  = (float*)(ws + 8388608);             //  8 MB
    float* xx  = (float*)(ws + 16777216);            //  128 KB
    int*   idx = (int*)  (ws + 16908288);            //  2.5 MB
    float* ht  = (float*)(ws + 19529728);            //  8 MB
    unsigned short* xps = (unsigned short*)(ws + 27918336);  // 8 MB split-bf16 images

    k_pre <<<B_ * (N_ / 64), 256, 0, stream>>>(x, wk1, yA, dd, xx, xps);
    k_topk<<<B_ * (N_ / 32), 512, 0, stream>>>(xps, xx, idx);
    k_edge<<<B_ * (N_ / 8),  256, 0, stream>>>(yA, dd, idx, wk2,
                                               gk1, bk1, mk1, vk1,
                                               gk2, bk2, mk2, vk2, ht);
    k_head<<<B_ * (N_ / 64), 256, 0, stream>>>(ht, w1, g1, b1, m1, v1,
                                               w2, g2, b2, m2, v2, w3, b3,
                                               (float*)d_out);
}